// Round 3
// baseline (1575.144 us; speedup 1.0000x reference)
//
#include <hip/hip_runtime.h>

typedef __attribute__((ext_vector_type(4))) float f4;

#define NN 50000
#define NE 600000
#define HEADS 4
#define DH 32
#define HIDU 128
#define NC 10
#define GR 32   // gemm rows per block

// ---------------- CSR build ----------------
__global__ void k_zero(int* p, int n) {
    int i = blockIdx.x * blockDim.x + threadIdx.x;
    if (i < n) p[i] = 0;
}

__global__ void k_hist(const int* __restrict__ dst, int* __restrict__ deg) {
    int i = blockIdx.x * blockDim.x + threadIdx.x;
    if (i < NE) atomicAdd(&deg[dst[i]], 1);
}

__global__ __launch_bounds__(1024) void k_scan(const int* __restrict__ deg,
                                               int* __restrict__ row_ptr,
                                               int* __restrict__ cursor) {
    __shared__ int sums[1024];
    int t = threadIdx.x;
    const int CH = (NN + 1023) / 1024;  // 49
    int base = t * CH;
    int s = 0;
    for (int i = 0; i < CH; i++) { int idx = base + i; if (idx < NN) s += deg[idx]; }
    sums[t] = s;
    __syncthreads();
    for (int off = 1; off < 1024; off <<= 1) {
        int v = 0;
        if (t >= off) v = sums[t - off];
        __syncthreads();
        sums[t] += v;
        __syncthreads();
    }
    int run = sums[t] - s;  // exclusive prefix of this chunk
    for (int i = 0; i < CH; i++) {
        int idx = base + i;
        if (idx < NN) { row_ptr[idx] = run; cursor[idx] = run; run += deg[idx]; }
    }
    if (t == 1023) row_ptr[NN] = run;   // == NE
}

__global__ void k_scatter(const int* __restrict__ ei, int* __restrict__ cursor,
                          int2* __restrict__ csr_se) {
    int i = blockIdx.x * blockDim.x + threadIdx.x;
    if (i < NE) {
        int s = ei[i];
        int d = ei[NE + i];
        int pos = atomicAdd(&cursor[d], 1);
        csr_se[pos] = make_int2(s, i);
    }
}

// ---------------- fused q/k/v/s GEMM (fp32 VALU, X staged in LDS once) ----------------
// tile: GR(32) rows x 128 cols x 4 mats. block 256 = 8 rowgroups(4 rows) x 32 lanes(4 cols).
__global__ __launch_bounds__(256) void gemm_qkvs(
    const float* __restrict__ X,
    const float* __restrict__ W0, const float* __restrict__ W1,
    const float* __restrict__ W2, const float* __restrict__ W3,
    const float* __restrict__ b0, const float* __restrict__ b1,
    const float* __restrict__ b2, const float* __restrict__ b3,
    float* __restrict__ outq, float* __restrict__ outk, float* __restrict__ outv,
    float* __restrict__ outs, int nrows)
{
    __shared__ float Xs[GR * HIDU];   // 16 KB
    const int t = threadIdx.x;
    const int row0 = blockIdx.x * GR;

    #pragma unroll
    for (int i = 0; i < 4; i++) {                 // stage X tile (32x128) as f4
        int idx = t + i * 256;                    // f4 index; 32 f4 per row
        int r = idx >> 5;
        int c = (idx & 31) << 2;
        int gr = row0 + r; if (gr > nrows - 1) gr = nrows - 1;
        *(f4*)(&Xs[r * HIDU + c]) = *(const f4*)(X + (size_t)gr * HIDU + c);
    }
    __syncthreads();

    const int rg = t >> 5;            // rowgroup 0..7
    const int c0 = (t & 31) << 2;     // col group

    float acc[4][4][4];               // [mat][row][col]
    #pragma unroll
    for (int m = 0; m < 4; m++)
        #pragma unroll
        for (int i = 0; i < 4; i++)
            #pragma unroll
            for (int c = 0; c < 4; c++) acc[m][i][c] = 0.f;

    const float* Wm0 = W0 + c0;
    const float* Wm1 = W1 + c0;
    const float* Wm2 = W2 + c0;
    const float* Wm3 = W3 + c0;

    #pragma unroll 4
    for (int k4 = 0; k4 < 32; k4++) {
        f4 xr[4];
        #pragma unroll
        for (int i = 0; i < 4; i++)
            xr[i] = *(const f4*)(&Xs[(rg * 4 + i) * HIDU + k4 * 4]);

        const float* wm[4] = {Wm0, Wm1, Wm2, Wm3};
        #pragma unroll
        for (int m = 0; m < 4; m++) {
            f4 w[4];
            #pragma unroll
            for (int j = 0; j < 4; j++)
                w[j] = *(const f4*)(wm[m] + (size_t)(k4 * 4 + j) * HIDU);
            #pragma unroll
            for (int i = 0; i < 4; i++)
                #pragma unroll
                for (int j = 0; j < 4; j++)
                    #pragma unroll
                    for (int c = 0; c < 4; c++)
                        acc[m][i][c] += xr[i][j] * w[j][c];
        }
    }

    float* om[4] = {outq, outk, outv, outs};
    const float* bm[4] = {b0, b1, b2, b3};
    #pragma unroll
    for (int m = 0; m < 4; m++) {
        f4 bv = *(const f4*)(bm[m] + c0);
        #pragma unroll
        for (int i = 0; i < 4; i++) {
            int rr = row0 + rg * 4 + i;
            if (rr < nrows) {
                f4 v;
                #pragma unroll
                for (int c = 0; c < 4; c++) v[c] = acc[m][i][c] + bv[c];
                *(f4*)(om[m] + (size_t)rr * HIDU + c0) = v;
            }
        }
    }
}

// ---------------- fused attention: one thread per (node, head) ----------------
// online softmax over incoming edges; e-embedding folded algebraically:
//   q.e = edge_attr . g   where g[t] = sum_j We[t][h*32+j]*q[j]   (per-thread precompute)
//   sum_e w*e = (sum_e w*edge_attr) @ We_h                        (epilogue transform)
__global__ __launch_bounds__(256) void attn(
    const float* __restrict__ qb, const float* __restrict__ kb, const float* __restrict__ vb,
    const float* __restrict__ sb, const float* __restrict__ eattr, const float* __restrict__ We,
    const int* __restrict__ row_ptr, const int2* __restrict__ csr_se,
    float* __restrict__ hout, int nnodes)
{
    __shared__ float WeS[4 * 513];   // [h][t*32+j]
    #pragma unroll
    for (int i = 0; i < 8; i++) {
        int idx = threadIdx.x + i * 256;   // t*128 + c over 16x128
        int tt = idx >> 7, c = idx & 127;
        int h = c >> 5, j = c & 31;
        WeS[h * 513 + tt * 32 + j] = We[idx];
    }
    __syncthreads();

    int tid = blockIdx.x * 256 + threadIdx.x;
    int n = tid >> 2, h = tid & 3;
    if (n >= nnodes) return;
    const float* WeH = &WeS[h * 513];

    float qreg[32];
    {
        const f4* qp = (const f4*)(qb + (size_t)n * HIDU + h * DH);
        #pragma unroll
        for (int c = 0; c < 8; c++) {
            f4 x = qp[c];
            #pragma unroll
            for (int j = 0; j < 4; j++) qreg[c * 4 + j] = x[j];
        }
    }
    float g[16];
    #pragma unroll
    for (int t16 = 0; t16 < 16; t16++) {
        float a = 0.f;
        #pragma unroll
        for (int j = 0; j < 32; j++) a += qreg[j] * WeH[t16 * 32 + j];
        g[t16] = a;
    }

    float m = -INFINITY, l = 0.f;
    float O[32];
    float a16[16];
    #pragma unroll
    for (int j = 0; j < 32; j++) O[j] = 0.f;
    #pragma unroll
    for (int t16 = 0; t16 < 16; t16++) a16[t16] = 0.f;

    const int r0 = row_ptr[n], r1 = row_ptr[n + 1];
    const float inv = 0.17677669529663687f;   // 1/sqrt(32)

    int2 se_next;
    if (r0 < r1) se_next = csr_se[r0];
    for (int e = r0; e < r1; e++) {
        int2 se = se_next;
        if (e + 1 < r1) se_next = csr_se[e + 1];
        int src = se.x;
        int eid = se.y;
        const f4* kp = (const f4*)(kb + (size_t)src * HIDU + h * DH);
        const f4* ep = (const f4*)(eattr + (size_t)eid * 16);
        const f4* vp = (const f4*)(vb + (size_t)src * HIDU + h * DH);

        float ea[16];
        #pragma unroll
        for (int c = 0; c < 4; c++) {
            f4 x = ep[c];
            #pragma unroll
            for (int j = 0; j < 4; j++) ea[c * 4 + j] = x[j];
        }
        float dot = 0.f;
        #pragma unroll
        for (int c = 0; c < 8; c++) {
            f4 x = kp[c];
            #pragma unroll
            for (int j = 0; j < 4; j++) dot += qreg[c * 4 + j] * x[j];
        }
        #pragma unroll
        for (int t16 = 0; t16 < 16; t16++) dot += g[t16] * ea[t16];

        float logit = dot * inv;
        float mn = fmaxf(m, logit);
        float corr = __expf(m - mn);      // first edge: exp(-inf)=0
        float w = __expf(logit - mn);
        l = l * corr + w;
        #pragma unroll
        for (int c = 0; c < 8; c++) {
            f4 x = vp[c];
            #pragma unroll
            for (int j = 0; j < 4; j++) O[c * 4 + j] = O[c * 4 + j] * corr + w * x[j];
        }
        #pragma unroll
        for (int t16 = 0; t16 < 16; t16++) a16[t16] = a16[t16] * corr + w * ea[t16];
        m = mn;
    }

    float invl = 1.0f / (l + 1e-16f);     // PyG softmax eps; zero-degree -> O=0
    const float* sp = sb + (size_t)n * HIDU + h * DH;
    float* op = hout + (size_t)n * HIDU + h * DH;
    #pragma unroll
    for (int j = 0; j < 32; j++) {
        float ev = 0.f;
        #pragma unroll
        for (int t16 = 0; t16 < 16; t16++) ev += a16[t16] * WeH[t16 * 32 + j];
        float val = (O[j] + ev) * invl + sp[j];
        op[j] = fmaxf(val, 0.f);          // relu(conv_out)
    }
}

// ---------------- head: logits + log_softmax ----------------
__global__ __launch_bounds__(256) void head_out(
    const float* __restrict__ hb, const float* __restrict__ Wout, const float* __restrict__ bout,
    float* __restrict__ out, int nnodes)
{
    __shared__ float Ws[HIDU * NC];
    __shared__ float bs[NC];
    for (int i = 0; i < 5; i++) {
        int idx = threadIdx.x + i * 256;
        if (idx < HIDU * NC) Ws[idx] = Wout[idx];
    }
    if (threadIdx.x < NC) bs[threadIdx.x] = bout[threadIdx.x];
    __syncthreads();

    int n = blockIdx.x * 256 + threadIdx.x;
    if (n >= nnodes) return;

    float lg[NC];
    #pragma unroll
    for (int c = 0; c < NC; c++) lg[c] = bs[c];
    const f4* hp = (const f4*)(hb + (size_t)n * HIDU);
    #pragma unroll
    for (int kc = 0; kc < 32; kc++) {
        f4 hv = hp[kc];
        #pragma unroll
        for (int j = 0; j < 4; j++) {
            float h = hv[j];
            int kk = kc * 4 + j;
            #pragma unroll
            for (int c = 0; c < NC; c++) lg[c] += h * Ws[kk * NC + c];
        }
    }
    float mx = lg[0];
    #pragma unroll
    for (int c = 1; c < NC; c++) mx = fmaxf(mx, lg[c]);
    float sum = 0.f;
    #pragma unroll
    for (int c = 0; c < NC; c++) sum += __expf(lg[c] - mx);
    float lse = mx + __logf(sum);
    #pragma unroll
    for (int c = 0; c < NC; c++) out[(size_t)n * NC + c] = lg[c] - lse;
}

// ---------------- launch ----------------
extern "C" void kernel_launch(void* const* d_in, const int* in_sizes, int n_in,
                              void* d_out, int out_size, void* d_ws, size_t ws_size,
                              hipStream_t stream) {
    const float* x     = (const float*)d_in[0];
    const int*   ei    = (const int*)d_in[1];
    const float* eattr = (const float*)d_in[2];
    const float *Wq0 = (const float*)d_in[3],  *bq0 = (const float*)d_in[4];
    const float *Wk0 = (const float*)d_in[5],  *bk0 = (const float*)d_in[6];
    const float *Wv0 = (const float*)d_in[7],  *bv0 = (const float*)d_in[8];
    const float *We0 = (const float*)d_in[9];
    const float *Ws0 = (const float*)d_in[10], *bs0 = (const float*)d_in[11];
    const float *Wq1 = (const float*)d_in[12], *bq1 = (const float*)d_in[13];
    const float *Wk1 = (const float*)d_in[14], *bk1 = (const float*)d_in[15];
    const float *Wv1 = (const float*)d_in[16], *bv1 = (const float*)d_in[17];
    const float *We1 = (const float*)d_in[18];
    const float *Ws1 = (const float*)d_in[19], *bs1 = (const float*)d_in[20];
    const float *Wout = (const float*)d_in[21], *bout = (const float*)d_in[22];

    char* p = (char*)d_ws;
    auto alloc = [&](size_t bytes) -> void* {
        void* r = (void*)p;
        p += (bytes + 255) & ~(size_t)255;
        return r;
    };
    int* deg      = (int*)alloc(NN * 4);
    int* row_ptr  = (int*)alloc((NN + 1) * 4);
    int* cursor   = (int*)alloc(NN * 4);
    int2* csr_se  = (int2*)alloc((size_t)NE * 8);
    float* qb     = (float*)alloc((size_t)NN * HIDU * 4);
    float* kb     = (float*)alloc((size_t)NN * HIDU * 4);
    float* vb     = (float*)alloc((size_t)NN * HIDU * 4);
    float* sbuf   = (float*)alloc((size_t)NN * HIDU * 4);
    float* hbuf   = (float*)alloc((size_t)NN * HIDU * 4);

    // CSR build (every call: inputs/ws are re-poisoned)
    k_zero<<<(NN + 255) / 256, 256, 0, stream>>>(deg, NN);
    k_hist<<<(NE + 255) / 256, 256, 0, stream>>>(ei + NE, deg);
    k_scan<<<1, 1024, 0, stream>>>(deg, row_ptr, cursor);
    k_scatter<<<(NE + 255) / 256, 256, 0, stream>>>(ei, cursor, csr_se);

    const int gm = (NN + GR - 1) / GR;             // 1563
    const int ga = (NN * HEADS + 255) / 256;       // 782
    // layer 1
    gemm_qkvs<<<gm, 256, 0, stream>>>(x, Wq0, Wk0, Wv0, Ws0,
                                      bq0, bk0, bv0, bs0, qb, kb, vb, sbuf, NN);
    attn<<<ga, 256, 0, stream>>>(qb, kb, vb, sbuf, eattr, We0,
                                 row_ptr, csr_se, hbuf, NN);
    // layer 2 (attn output overwrites hbuf: attn never reads it)
    gemm_qkvs<<<gm, 256, 0, stream>>>(hbuf, Wq1, Wk1, Wv1, Ws1,
                                      bq1, bk1, bv1, bs1, qb, kb, vb, sbuf, NN);
    attn<<<ga, 256, 0, stream>>>(qb, kb, vb, sbuf, eattr, We1,
                                 row_ptr, csr_se, hbuf, NN);
    // head
    head_out<<<(NN + 255) / 256, 256, 0, stream>>>(hbuf, Wout, bout, (float*)d_out, NN);
}

// Round 4
// 971.596 us; speedup vs baseline: 1.6212x; 1.6212x over previous
//
#include <hip/hip_runtime.h>

typedef unsigned short u16;
typedef __attribute__((ext_vector_type(8))) u16 u16x8;
typedef __attribute__((ext_vector_type(8))) short short8;   // MFMA A/B frag (8 bf16)
typedef __attribute__((ext_vector_type(4))) float f32x4;    // MFMA C/D frag
typedef __attribute__((ext_vector_type(4))) float f4;

#define NN 50000
#define NE 600000
#define HEADS 4
#define DH 32
#define HIDU 128
#define NC 10

__device__ __forceinline__ float bf2f(u16 u) {
    union { unsigned int i; float f; } c; c.i = ((unsigned int)u) << 16; return c.f;
}
__device__ __forceinline__ u16 f2bf(float f) {
    union { float f; unsigned int i; } c; c.f = f;
    unsigned int x = c.i;
    return (u16)((x + 0x7fffu + ((x >> 16) & 1u)) >> 16);  // RNE
}

// ---------------- CSR build ----------------
__global__ void k_zero(int* p, int n) {
    int i = blockIdx.x * blockDim.x + threadIdx.x;
    if (i < n) p[i] = 0;
}

__global__ void k_hist(const int* __restrict__ dst, int* __restrict__ deg) {
    int i = blockIdx.x * blockDim.x + threadIdx.x;
    if (i < NE) atomicAdd(&deg[dst[i]], 1);
}

__global__ __launch_bounds__(1024) void k_scan(const int* __restrict__ deg,
                                               int* __restrict__ row_ptr,
                                               int* __restrict__ cursor) {
    __shared__ int sums[1024];
    int t = threadIdx.x;
    const int CH = (NN + 1023) / 1024;  // 49
    int base = t * CH;
    int s = 0;
    for (int i = 0; i < CH; i++) { int idx = base + i; if (idx < NN) s += deg[idx]; }
    sums[t] = s;
    __syncthreads();
    for (int off = 1; off < 1024; off <<= 1) {
        int v = 0;
        if (t >= off) v = sums[t - off];
        __syncthreads();
        sums[t] += v;
        __syncthreads();
    }
    int run = sums[t] - s;  // exclusive prefix of this chunk
    for (int i = 0; i < CH; i++) {
        int idx = base + i;
        if (idx < NN) { row_ptr[idx] = run; cursor[idx] = run; run += deg[idx]; }
    }
    if (t == 1023) row_ptr[NN] = run;   // == NE
}

__global__ void k_scatter(const int* __restrict__ ei, int* __restrict__ cursor,
                          int2* __restrict__ csr_se) {
    int i = blockIdx.x * blockDim.x + threadIdx.x;
    if (i < NE) {
        int s = ei[i];
        int d = ei[NE + i];
        int pos = atomicAdd(&cursor[d], 1);
        csr_se[pos] = make_int2(s, i);
    }
}

// ---------------- fp32 -> bf16 hi/lo split ----------------
__global__ __launch_bounds__(256) void k_cvt(const float* __restrict__ in,
                                             u16* __restrict__ hi, u16* __restrict__ lo) {
    int i = blockIdx.x * 256 + threadIdx.x;      // one thread per 8 elems
    const f4* p = (const f4*)(in + (size_t)i * 8);
    f4 a = p[0], b = p[1];
    float v[8] = {a[0], a[1], a[2], a[3], b[0], b[1], b[2], b[3]};
    u16x8 h, l;
    #pragma unroll
    for (int j = 0; j < 8; j++) {
        u16 hh = f2bf(v[j]);
        float r = v[j] - bf2f(hh);
        h[j] = hh; l[j] = f2bf(r);
    }
    *(u16x8*)(hi + (size_t)i * 8) = h;
    *(u16x8*)(lo + (size_t)i * 8) = l;
}

// weights: convert + transpose W[k][n] -> Wt[n][k], hi/lo
__global__ void k_cvtw(const float* w0, const float* w1, const float* w2, const float* w3,
                       const float* w4, const float* w5, const float* w6, const float* w7,
                       u16* __restrict__ hi, u16* __restrict__ lo) {
    const float* w;
    switch (blockIdx.x) {
        case 0: w = w0; break; case 1: w = w1; break;
        case 2: w = w2; break; case 3: w = w3; break;
        case 4: w = w4; break; case 5: w = w5; break;
        case 6: w = w6; break; default: w = w7; break;
    }
    u16* oh = hi + blockIdx.x * 16384;
    u16* ol = lo + blockIdx.x * 16384;
    for (int i = 0; i < 64; i++) {
        int idx = threadIdx.x + i * 256;   // k*128 + n
        int k = idx >> 7, n = idx & 127;
        float v = w[idx];
        u16 h = f2bf(v);
        float r = v - bf2f(h);
        oh[n * 128 + k] = h;
        ol[n * 128 + k] = f2bf(r);
    }
}

// ---------------- MFMA GEMM, bf16x3 split: out = X(Nx128) @ W(128x128) + b ----------------
// grid (782, 4 mats), block 256 = 4 waves x 16 rows. A/B frags direct from global.
__global__ __launch_bounds__(256) void gemm_mfma(
    const u16* __restrict__ Xhi, const u16* __restrict__ Xlo,
    const u16* __restrict__ WtHi, const u16* __restrict__ WtLo,   // this layer's 4 mats
    const float* __restrict__ b0, const float* __restrict__ b1,
    const float* __restrict__ b2, const float* __restrict__ b3,
    float* __restrict__ outq, float* __restrict__ outk, float* __restrict__ outv,
    float* __restrict__ outs, int nrows)
{
    const int mat = blockIdx.y;
    const u16* wh = WtHi + mat * 16384;
    const u16* wl = WtLo + mat * 16384;
    const float* bia = (mat == 0) ? b0 : (mat == 1) ? b1 : (mat == 2) ? b2 : b3;
    float* o = (mat == 0) ? outq : (mat == 1) ? outk : (mat == 2) ? outv : outs;

    const int wave = threadIdx.x >> 6, lane = threadIdx.x & 63;
    const int n0 = lane & 15;              // A row / B col / D col
    const int kq = (lane >> 4) * 8;        // k offset within K32 chunk

    int arow = blockIdx.x * 64 + wave * 16 + n0;
    int arow_c = arow < nrows ? arow : nrows - 1;
    const u16* xh = Xhi + (size_t)arow_c * HIDU + kq;
    const u16* xl = Xlo + (size_t)arow_c * HIDU + kq;

    f32x4 acc[8];
    #pragma unroll
    for (int nt = 0; nt < 8; nt++) acc[nt] = (f32x4){0.f, 0.f, 0.f, 0.f};

    #pragma unroll
    for (int ks = 0; ks < 4; ks++) {
        short8 ah = *(const short8*)(xh + ks * 32);
        short8 al = *(const short8*)(xl + ks * 32);
        #pragma unroll
        for (int nt = 0; nt < 8; nt++) {
            const int boff = (nt * 16 + n0) * 128 + ks * 32 + kq;
            short8 bh = *(const short8*)(wh + boff);
            short8 bl = *(const short8*)(wl + boff);
            acc[nt] = __builtin_amdgcn_mfma_f32_16x16x32_bf16(ah, bh, acc[nt], 0, 0, 0);
            acc[nt] = __builtin_amdgcn_mfma_f32_16x16x32_bf16(al, bh, acc[nt], 0, 0, 0);
            acc[nt] = __builtin_amdgcn_mfma_f32_16x16x32_bf16(ah, bl, acc[nt], 0, 0, 0);
        }
    }

    const int rbase = blockIdx.x * 64 + wave * 16 + (lane >> 4) * 4;
    #pragma unroll
    for (int nt = 0; nt < 8; nt++) {
        int col = nt * 16 + n0;
        float bv = bia[col];
        #pragma unroll
        for (int r = 0; r < 4; r++) {
            int grow = rbase + r;
            if (grow < nrows) o[(size_t)grow * HIDU + col] = acc[nt][r] + bv;
        }
    }
}

// ---------------- fused attention: one thread per (node, head) ----------------
// online softmax over incoming edges; e-embedding folded algebraically:
//   q.e = edge_attr . g   where g[t] = sum_j We[t][h*32+j]*q[j]   (per-thread precompute)
//   sum_e w*e = (sum_e w*edge_attr) @ We_h                        (epilogue transform)
__global__ __launch_bounds__(256) void attn(
    const float* __restrict__ qb, const float* __restrict__ kb, const float* __restrict__ vb,
    const float* __restrict__ sb, const float* __restrict__ eattr, const float* __restrict__ We,
    const int* __restrict__ row_ptr, const int2* __restrict__ csr_se,
    float* __restrict__ hout, int nnodes)
{
    __shared__ float WeS[4 * 513];   // [h][t*32+j]
    #pragma unroll
    for (int i = 0; i < 8; i++) {
        int idx = threadIdx.x + i * 256;   // t*128 + c over 16x128
        int tt = idx >> 7, c = idx & 127;
        int h = c >> 5, j = c & 31;
        WeS[h * 513 + tt * 32 + j] = We[idx];
    }
    __syncthreads();

    int tid = blockIdx.x * 256 + threadIdx.x;
    int n = tid >> 2, h = tid & 3;
    if (n >= nnodes) return;
    const float* WeH = &WeS[h * 513];

    float qreg[32];
    {
        const f4* qp = (const f4*)(qb + (size_t)n * HIDU + h * DH);
        #pragma unroll
        for (int c = 0; c < 8; c++) {
            f4 x = qp[c];
            #pragma unroll
            for (int j = 0; j < 4; j++) qreg[c * 4 + j] = x[j];
        }
    }
    float g[16];
    #pragma unroll
    for (int t16 = 0; t16 < 16; t16++) {
        float a = 0.f;
        #pragma unroll
        for (int j = 0; j < 32; j++) a += qreg[j] * WeH[t16 * 32 + j];
        g[t16] = a;
    }

    float m = -INFINITY, l = 0.f;
    float O[32];
    float a16[16];
    #pragma unroll
    for (int j = 0; j < 32; j++) O[j] = 0.f;
    #pragma unroll
    for (int t16 = 0; t16 < 16; t16++) a16[t16] = 0.f;

    const int r0 = row_ptr[n], r1 = row_ptr[n + 1];
    const float inv = 0.17677669529663687f;   // 1/sqrt(32)

    for (int e = r0; e < r1; e++) {
        int2 se = csr_se[e];
        int src = se.x;
        int eid = se.y;
        const f4* kp = (const f4*)(kb + (size_t)src * HIDU + h * DH);
        const f4* ep = (const f4*)(eattr + (size_t)eid * 16);
        const f4* vp = (const f4*)(vb + (size_t)src * HIDU + h * DH);

        float ea[16];
        #pragma unroll
        for (int c = 0; c < 4; c++) {
            f4 x = ep[c];
            #pragma unroll
            for (int j = 0; j < 4; j++) ea[c * 4 + j] = x[j];
        }
        float dot = 0.f;
        #pragma unroll
        for (int c = 0; c < 8; c++) {
            f4 x = kp[c];
            #pragma unroll
            for (int j = 0; j < 4; j++) dot += qreg[c * 4 + j] * x[j];
        }
        #pragma unroll
        for (int t16 = 0; t16 < 16; t16++) dot += g[t16] * ea[t16];

        float logit = dot * inv;
        float mn = fmaxf(m, logit);
        float corr = __expf(m - mn);      // first edge: exp(-inf)=0
        float w = __expf(logit - mn);
        l = l * corr + w;
        #pragma unroll
        for (int c = 0; c < 8; c++) {
            f4 x = vp[c];
            #pragma unroll
            for (int j = 0; j < 4; j++) O[c * 4 + j] = O[c * 4 + j] * corr + w * x[j];
        }
        #pragma unroll
        for (int t16 = 0; t16 < 16; t16++) a16[t16] = a16[t16] * corr + w * ea[t16];
        m = mn;
    }

    float invl = 1.0f / (l + 1e-16f);     // PyG softmax eps; zero-degree -> O=0
    const float* sp = sb + (size_t)n * HIDU + h * DH;
    float* op = hout + (size_t)n * HIDU + h * DH;
    #pragma unroll
    for (int j = 0; j < 32; j++) {
        float ev = 0.f;
        #pragma unroll
        for (int t16 = 0; t16 < 16; t16++) ev += a16[t16] * WeH[t16 * 32 + j];
        float val = (O[j] + ev) * invl + sp[j];
        op[j] = fmaxf(val, 0.f);          // relu(conv_out)
    }
}

// ---------------- head: logits + log_softmax ----------------
__global__ __launch_bounds__(256) void head_out(
    const float* __restrict__ hb, const float* __restrict__ Wout, const float* __restrict__ bout,
    float* __restrict__ out, int nnodes)
{
    __shared__ float Ws[HIDU * NC];
    __shared__ float bs[NC];
    for (int i = 0; i < 5; i++) {
        int idx = threadIdx.x + i * 256;
        if (idx < HIDU * NC) Ws[idx] = Wout[idx];
    }
    if (threadIdx.x < NC) bs[threadIdx.x] = bout[threadIdx.x];
    __syncthreads();

    int n = blockIdx.x * 256 + threadIdx.x;
    if (n >= nnodes) return;

    float lg[NC];
    #pragma unroll
    for (int c = 0; c < NC; c++) lg[c] = bs[c];
    const f4* hp = (const f4*)(hb + (size_t)n * HIDU);
    #pragma unroll
    for (int kc = 0; kc < 32; kc++) {
        f4 hv = hp[kc];
        #pragma unroll
        for (int j = 0; j < 4; j++) {
            float h = hv[j];
            int kk = kc * 4 + j;
            #pragma unroll
            for (int c = 0; c < NC; c++) lg[c] += h * Ws[kk * NC + c];
        }
    }
    float mx = lg[0];
    #pragma unroll
    for (int c = 1; c < NC; c++) mx = fmaxf(mx, lg[c]);
    float sum = 0.f;
    #pragma unroll
    for (int c = 0; c < NC; c++) sum += __expf(lg[c] - mx);
    float lse = mx + __logf(sum);
    #pragma unroll
    for (int c = 0; c < NC; c++) out[(size_t)n * NC + c] = lg[c] - lse;
}

// ---------------- launch ----------------
extern "C" void kernel_launch(void* const* d_in, const int* in_sizes, int n_in,
                              void* d_out, int out_size, void* d_ws, size_t ws_size,
                              hipStream_t stream) {
    const float* x     = (const float*)d_in[0];
    const int*   ei    = (const int*)d_in[1];
    const float* eattr = (const float*)d_in[2];
    const float *Wq0 = (const float*)d_in[3],  *bq0 = (const float*)d_in[4];
    const float *Wk0 = (const float*)d_in[5],  *bk0 = (const float*)d_in[6];
    const float *Wv0 = (const float*)d_in[7],  *bv0 = (const float*)d_in[8];
    const float *We0 = (const float*)d_in[9];
    const float *Ws0 = (const float*)d_in[10], *bs0 = (const float*)d_in[11];
    const float *Wq1 = (const float*)d_in[12], *bq1 = (const float*)d_in[13];
    const float *Wk1 = (const float*)d_in[14], *bk1 = (const float*)d_in[15];
    const float *Wv1 = (const float*)d_in[16], *bv1 = (const float*)d_in[17];
    const float *We1 = (const float*)d_in[18];
    const float *Ws1 = (const float*)d_in[19], *bs1 = (const float*)d_in[20];
    const float *Wout = (const float*)d_in[21], *bout = (const float*)d_in[22];

    char* p = (char*)d_ws;
    auto alloc = [&](size_t bytes) -> void* {
        void* r = (void*)p;
        p += (bytes + 255) & ~(size_t)255;
        return r;
    };
    int* deg      = (int*)alloc(NN * 4);
    int* row_ptr  = (int*)alloc((NN + 1) * 4);
    int* cursor   = (int*)alloc(NN * 4);
    int2* csr_se  = (int2*)alloc((size_t)NE * 8);
    float* qb     = (float*)alloc((size_t)NN * HIDU * 4);
    float* kb     = (float*)alloc((size_t)NN * HIDU * 4);
    float* vb     = (float*)alloc((size_t)NN * HIDU * 4);
    float* sbuf   = (float*)alloc((size_t)NN * HIDU * 4);
    float* hbuf   = (float*)alloc((size_t)NN * HIDU * 4);
    u16* xhi      = (u16*)alloc((size_t)NN * HIDU * 2);   // reused for h in layer 2
    u16* xlo      = (u16*)alloc((size_t)NN * HIDU * 2);
    u16* wthi     = (u16*)alloc(8 * 16384 * 2);
    u16* wtlo     = (u16*)alloc(8 * 16384 * 2);

    // CSR build (every call: inputs/ws are re-poisoned)
    k_zero<<<(NN + 255) / 256, 256, 0, stream>>>(deg, NN);
    k_hist<<<(NE + 255) / 256, 256, 0, stream>>>(ei + NE, deg);
    k_scan<<<1, 1024, 0, stream>>>(deg, row_ptr, cursor);
    k_scatter<<<(NE + 255) / 256, 256, 0, stream>>>(ei, cursor, csr_se);

    // weights -> transposed bf16 hi/lo (mats 0-3: layer 0 q,k,v,s; 4-7: layer 1)
    k_cvtw<<<8, 256, 0, stream>>>(Wq0, Wk0, Wv0, Ws0, Wq1, Wk1, Wv1, Ws1, wthi, wtlo);

    const int gcv = (NN * HIDU / 8 + 255) / 256;   // 3125
    const int gm = (NN + 63) / 64;                 // 782
    const int ga = (NN * HEADS + 255) / 256;       // 782

    // layer 1
    k_cvt<<<gcv, 256, 0, stream>>>(x, xhi, xlo);
    gemm_mfma<<<dim3(gm, 4), 256, 0, stream>>>(xhi, xlo, wthi, wtlo,
                                               bq0, bk0, bv0, bs0, qb, kb, vb, sbuf, NN);
    attn<<<ga, 256, 0, stream>>>(qb, kb, vb, sbuf, eattr, We0,
                                 row_ptr, csr_se, hbuf, NN);
    // layer 2
    k_cvt<<<gcv, 256, 0, stream>>>(hbuf, xhi, xlo);
    gemm_mfma<<<dim3(gm, 4), 256, 0, stream>>>(xhi, xlo, wthi + 4 * 16384, wtlo + 4 * 16384,
                                               bq1, bk1, bv1, bs1, qb, kb, vb, sbuf, NN);
    attn<<<ga, 256, 0, stream>>>(qb, kb, vb, sbuf, eattr, We1,
                                 row_ptr, csr_se, hbuf, NN);
    // head
    head_out<<<(NN + 255) / 256, 256, 0, stream>>>(hbuf, Wout, bout, (float*)d_out, NN);
}

// Round 5
// 867.264 us; speedup vs baseline: 1.8162x; 1.1203x over previous
//
#include <hip/hip_runtime.h>

typedef unsigned short u16;
typedef __attribute__((ext_vector_type(8))) u16 u16x8;
typedef __attribute__((ext_vector_type(8))) short short8;   // MFMA A/B frag (8 bf16)
typedef __attribute__((ext_vector_type(4))) float f32x4;    // MFMA C/D frag
typedef __attribute__((ext_vector_type(4))) float f4;

#define NN 50000
#define NE 600000
#define HEADS 4
#define DH 32
#define HIDU 128
#define NC 10

__device__ __forceinline__ float bf2f(u16 u) {
    union { unsigned int i; float f; } c; c.i = ((unsigned int)u) << 16; return c.f;
}
__device__ __forceinline__ u16 f2bf(float f) {
    union { float f; unsigned int i; } c; c.f = f;
    unsigned int x = c.i;
    return (u16)((x + 0x7fffu + ((x >> 16) & 1u)) >> 16);  // RNE
}

// ---------------- CSR build ----------------
__global__ void k_zero(int* p, int n) {
    int i = blockIdx.x * blockDim.x + threadIdx.x;
    if (i < n) p[i] = 0;
}

__global__ void k_hist(const int* __restrict__ dst, int* __restrict__ deg) {
    int i = blockIdx.x * blockDim.x + threadIdx.x;
    if (i < NE) atomicAdd(&deg[dst[i]], 1);
}

__global__ __launch_bounds__(1024) void k_scan(const int* __restrict__ deg,
                                               int* __restrict__ row_ptr,
                                               int* __restrict__ cursor) {
    __shared__ int sums[1024];
    int t = threadIdx.x;
    const int CH = (NN + 1023) / 1024;  // 49
    int base = t * CH;
    int s = 0;
    for (int i = 0; i < CH; i++) { int idx = base + i; if (idx < NN) s += deg[idx]; }
    sums[t] = s;
    __syncthreads();
    for (int off = 1; off < 1024; off <<= 1) {
        int v = 0;
        if (t >= off) v = sums[t - off];
        __syncthreads();
        sums[t] += v;
        __syncthreads();
    }
    int run = sums[t] - s;  // exclusive prefix of this chunk
    for (int i = 0; i < CH; i++) {
        int idx = base + i;
        if (idx < NN) { row_ptr[idx] = run; cursor[idx] = run; run += deg[idx]; }
    }
    if (t == 1023) row_ptr[NN] = run;   // == NE
}

__global__ void k_scatter(const int* __restrict__ ei, int* __restrict__ cursor,
                          int2* __restrict__ csr_se) {
    int i = blockIdx.x * blockDim.x + threadIdx.x;
    if (i < NE) {
        int s = ei[i];
        int d = ei[NE + i];
        int pos = atomicAdd(&cursor[d], 1);
        csr_se[pos] = make_int2(s, i);
    }
}

// ---------------- fp32 -> bf16 hi/lo split ----------------
__global__ __launch_bounds__(256) void k_cvt(const float* __restrict__ in,
                                             u16* __restrict__ hi, u16* __restrict__ lo) {
    int i = blockIdx.x * 256 + threadIdx.x;      // one thread per 8 elems
    const f4* p = (const f4*)(in + (size_t)i * 8);
    f4 a = p[0], b = p[1];
    float v[8] = {a[0], a[1], a[2], a[3], b[0], b[1], b[2], b[3]};
    u16x8 h, l;
    #pragma unroll
    for (int j = 0; j < 8; j++) {
        u16 hh = f2bf(v[j]);
        float r = v[j] - bf2f(hh);
        h[j] = hh; l[j] = f2bf(r);
    }
    *(u16x8*)(hi + (size_t)i * 8) = h;
    *(u16x8*)(lo + (size_t)i * 8) = l;
}

// weights: convert + transpose W[k][n] -> Wt[n][k], hi/lo
__global__ void k_cvtw(const float* w0, const float* w1, const float* w2, const float* w3,
                       const float* w4, const float* w5, const float* w6, const float* w7,
                       u16* __restrict__ hi, u16* __restrict__ lo) {
    const float* w;
    switch (blockIdx.x) {
        case 0: w = w0; break; case 1: w = w1; break;
        case 2: w = w2; break; case 3: w = w3; break;
        case 4: w = w4; break; case 5: w = w5; break;
        case 6: w = w6; break; default: w = w7; break;
    }
    u16* oh = hi + blockIdx.x * 16384;
    u16* ol = lo + blockIdx.x * 16384;
    for (int i = 0; i < 64; i++) {
        int idx = threadIdx.x + i * 256;   // k*128 + n
        int k = idx >> 7, n = idx & 127;
        float v = w[idx];
        u16 h = f2bf(v);
        float r = v - bf2f(h);
        oh[n * 128 + k] = h;
        ol[n * 128 + k] = f2bf(r);
    }
}

// ---------------- MFMA GEMM, bf16x3 split: out = X(Nx128) @ W(128x128) + b ----------------
// grid (782, 4 mats), block 256 = 4 waves x 16 rows. A/B frags direct from global.
__global__ __launch_bounds__(256) void gemm_mfma(
    const u16* __restrict__ Xhi, const u16* __restrict__ Xlo,
    const u16* __restrict__ WtHi, const u16* __restrict__ WtLo,   // this layer's 4 mats
    const float* __restrict__ b0, const float* __restrict__ b1,
    const float* __restrict__ b2, const float* __restrict__ b3,
    float* __restrict__ outq, float* __restrict__ outk, float* __restrict__ outv,
    float* __restrict__ outs, int nrows)
{
    const int mat = blockIdx.y;
    const u16* wh = WtHi + mat * 16384;
    const u16* wl = WtLo + mat * 16384;
    const float* bia = (mat == 0) ? b0 : (mat == 1) ? b1 : (mat == 2) ? b2 : b3;
    float* o = (mat == 0) ? outq : (mat == 1) ? outk : (mat == 2) ? outv : outs;

    const int wave = threadIdx.x >> 6, lane = threadIdx.x & 63;
    const int n0 = lane & 15;              // A row / B col / D col
    const int kq = (lane >> 4) * 8;        // k offset within K32 chunk

    int arow = blockIdx.x * 64 + wave * 16 + n0;
    int arow_c = arow < nrows ? arow : nrows - 1;
    const u16* xh = Xhi + (size_t)arow_c * HIDU + kq;
    const u16* xl = Xlo + (size_t)arow_c * HIDU + kq;

    f32x4 acc[8];
    #pragma unroll
    for (int nt = 0; nt < 8; nt++) acc[nt] = (f32x4){0.f, 0.f, 0.f, 0.f};

    #pragma unroll
    for (int ks = 0; ks < 4; ks++) {
        short8 ah = *(const short8*)(xh + ks * 32);
        short8 al = *(const short8*)(xl + ks * 32);
        #pragma unroll
        for (int nt = 0; nt < 8; nt++) {
            const int boff = (nt * 16 + n0) * 128 + ks * 32 + kq;
            short8 bh = *(const short8*)(wh + boff);
            short8 bl = *(const short8*)(wl + boff);
            acc[nt] = __builtin_amdgcn_mfma_f32_16x16x32_bf16(ah, bh, acc[nt], 0, 0, 0);
            acc[nt] = __builtin_amdgcn_mfma_f32_16x16x32_bf16(al, bh, acc[nt], 0, 0, 0);
            acc[nt] = __builtin_amdgcn_mfma_f32_16x16x32_bf16(ah, bl, acc[nt], 0, 0, 0);
        }
    }

    const int rbase = blockIdx.x * 64 + wave * 16 + (lane >> 4) * 4;
    #pragma unroll
    for (int nt = 0; nt < 8; nt++) {
        int col = nt * 16 + n0;
        float bv = bia[col];
        #pragma unroll
        for (int r = 0; r < 4; r++) {
            int grow = rbase + r;
            if (grow < nrows) o[(size_t)grow * HIDU + col] = acc[nt][r] + bv;
        }
    }
}

// ---------------- fused attention: FOUR lanes per (node, head) ----------------
// lane owns 8 of 32 channels; q.k partial reduced via 4-lane shfl-xor butterfly;
// e-dot computed redundantly per lane (added AFTER the butterfly, so counted once).
// online softmax state m,l identical across the 4 lanes (divergence-free).
//   q.e = edge_attr . g   where g[t] = sum_j We[t][h*32+j]*q[j]
//   sum_e w*e = (sum_e w*edge_attr) @ We_h  (epilogue)
__global__ __launch_bounds__(256) void attn(
    const float* __restrict__ qb, const float* __restrict__ kb, const float* __restrict__ vb,
    const float* __restrict__ sb, const float* __restrict__ eattr, const float* __restrict__ We,
    const int* __restrict__ row_ptr, const int2* __restrict__ csr_se,
    float* __restrict__ hout, int nnodes)
{
    __shared__ float WeS[4 * 513];   // [h][t*32+j]
    #pragma unroll
    for (int i = 0; i < 8; i++) {
        int idx = threadIdx.x + i * 256;   // t*128 + c over 16x128
        int tt = idx >> 7, c = idx & 127;
        int h = c >> 5, j = c & 31;
        WeS[h * 513 + tt * 32 + j] = We[idx];
    }
    __syncthreads();

    int gtid = blockIdx.x * 256 + threadIdx.x;   // grid is exactly NN*HEADS*4 threads
    int pair = gtid >> 2;        // (node, head)
    int sub  = gtid & 3;         // lane-in-group
    int n = pair >> 2, h = pair & 3;
    const float* WeH = &WeS[h * 513];
    const int j0 = sub * 8;      // own channel base

    // own 8 q channels
    float qreg[8];
    {
        const f4* qp = (const f4*)(qb + (size_t)n * HIDU + h * DH + j0);
        f4 a = qp[0], b = qp[1];
        #pragma unroll
        for (int j = 0; j < 4; j++) { qreg[j] = a[j]; qreg[4 + j] = b[j]; }
    }

    // g[t] full per lane: partial over own j, butterfly over the 4-lane group
    float g[16];
    #pragma unroll
    for (int t16 = 0; t16 < 16; t16++) {
        float a = 0.f;
        #pragma unroll
        for (int jj = 0; jj < 8; jj++) a += qreg[jj] * WeH[t16 * 32 + j0 + jj];
        g[t16] = a;
    }
    #pragma unroll
    for (int t16 = 0; t16 < 16; t16++) g[t16] += __shfl_xor(g[t16], 1);
    #pragma unroll
    for (int t16 = 0; t16 < 16; t16++) g[t16] += __shfl_xor(g[t16], 2);

    float m = -INFINITY, l = 0.f;
    float O[8];
    float a16[16];
    #pragma unroll
    for (int j = 0; j < 8; j++) O[j] = 0.f;
    #pragma unroll
    for (int t16 = 0; t16 < 16; t16++) a16[t16] = 0.f;

    const int r0 = row_ptr[n], r1 = row_ptr[n + 1];
    const float inv = 0.17677669529663687f;   // 1/sqrt(32)

    for (int e = r0; e < r1; e++) {
        int2 se = csr_se[e];
        const float* kp = kb + (size_t)se.x * HIDU + h * DH + j0;
        const float* vp = vb + (size_t)se.x * HIDU + h * DH + j0;
        const f4* ep = (const f4*)(eattr + (size_t)se.y * 16);

        f4 k0 = *(const f4*)kp,       k1 = *(const f4*)(kp + 4);
        f4 v0 = *(const f4*)vp,       v1 = *(const f4*)(vp + 4);
        f4 e0 = ep[0], e1 = ep[1], e2 = ep[2], e3 = ep[3];
        float ea[16];
        #pragma unroll
        for (int j = 0; j < 4; j++) {
            ea[j] = e0[j]; ea[4 + j] = e1[j]; ea[8 + j] = e2[j]; ea[12 + j] = e3[j];
        }

        // partial k-dot over own 8 channels, butterfly to full
        float dp = 0.f;
        #pragma unroll
        for (int j = 0; j < 4; j++) dp += qreg[j] * k0[j] + qreg[4 + j] * k1[j];
        dp += __shfl_xor(dp, 1);
        dp += __shfl_xor(dp, 2);
        // full e-dot locally (identical in all 4 lanes, added once)
        float dot = dp;
        #pragma unroll
        for (int t16 = 0; t16 < 16; t16++) dot += g[t16] * ea[t16];

        float logit = dot * inv;
        float mn = fmaxf(m, logit);
        float corr = __expf(m - mn);      // first edge: exp(-inf)=0
        float w = __expf(logit - mn);
        l = l * corr + w;
        #pragma unroll
        for (int j = 0; j < 4; j++) {
            O[j]     = O[j]     * corr + w * v0[j];
            O[4 + j] = O[4 + j] * corr + w * v1[j];
        }
        #pragma unroll
        for (int t16 = 0; t16 < 16; t16++) a16[t16] = a16[t16] * corr + w * ea[t16];
        m = mn;
    }

    float invl = 1.0f / (l + 1e-16f);     // PyG softmax eps; zero-degree -> O=0
    const float* sp = sb + (size_t)n * HIDU + h * DH + j0;
    float* op = hout + (size_t)n * HIDU + h * DH + j0;
    f4 r0v, r1v;
    #pragma unroll
    for (int j = 0; j < 8; j++) {
        float ev = 0.f;
        #pragma unroll
        for (int t16 = 0; t16 < 16; t16++) ev += a16[t16] * WeH[t16 * 32 + j0 + j];
        float val = (O[j] + ev) * invl + sp[j];
        val = fmaxf(val, 0.f);            // relu(conv_out)
        if (j < 4) r0v[j] = val; else r1v[j - 4] = val;
    }
    *(f4*)op = r0v;
    *(f4*)(op + 4) = r1v;
}

// ---------------- head: logits + log_softmax ----------------
__global__ __launch_bounds__(256) void head_out(
    const float* __restrict__ hb, const float* __restrict__ Wout, const float* __restrict__ bout,
    float* __restrict__ out, int nnodes)
{
    __shared__ float Ws[HIDU * NC];
    __shared__ float bs[NC];
    for (int i = 0; i < 5; i++) {
        int idx = threadIdx.x + i * 256;
        if (idx < HIDU * NC) Ws[idx] = Wout[idx];
    }
    if (threadIdx.x < NC) bs[threadIdx.x] = bout[threadIdx.x];
    __syncthreads();

    int n = blockIdx.x * 256 + threadIdx.x;
    if (n >= nnodes) return;

    float lg[NC];
    #pragma unroll
    for (int c = 0; c < NC; c++) lg[c] = bs[c];
    const f4* hp = (const f4*)(hb + (size_t)n * HIDU);
    #pragma unroll
    for (int kc = 0; kc < 32; kc++) {
        f4 hv = hp[kc];
        #pragma unroll
        for (int j = 0; j < 4; j++) {
            float h = hv[j];
            int kk = kc * 4 + j;
            #pragma unroll
            for (int c = 0; c < NC; c++) lg[c] += h * Ws[kk * NC + c];
        }
    }
    float mx = lg[0];
    #pragma unroll
    for (int c = 1; c < NC; c++) mx = fmaxf(mx, lg[c]);
    float sum = 0.f;
    #pragma unroll
    for (int c = 0; c < NC; c++) sum += __expf(lg[c] - mx);
    float lse = mx + __logf(sum);
    #pragma unroll
    for (int c = 0; c < NC; c++) out[(size_t)n * NC + c] = lg[c] - lse;
}

// ---------------- launch ----------------
extern "C" void kernel_launch(void* const* d_in, const int* in_sizes, int n_in,
                              void* d_out, int out_size, void* d_ws, size_t ws_size,
                              hipStream_t stream) {
    const float* x     = (const float*)d_in[0];
    const int*   ei    = (const int*)d_in[1];
    const float* eattr = (const float*)d_in[2];
    const float *Wq0 = (const float*)d_in[3],  *bq0 = (const float*)d_in[4];
    const float *Wk0 = (const float*)d_in[5],  *bk0 = (const float*)d_in[6];
    const float *Wv0 = (const float*)d_in[7],  *bv0 = (const float*)d_in[8];
    const float *We0 = (const float*)d_in[9];
    const float *Ws0 = (const float*)d_in[10], *bs0 = (const float*)d_in[11];
    const float *Wq1 = (const float*)d_in[12], *bq1 = (const float*)d_in[13];
    const float *Wk1 = (const float*)d_in[14], *bk1 = (const float*)d_in[15];
    const float *Wv1 = (const float*)d_in[16], *bv1 = (const float*)d_in[17];
    const float *We1 = (const float*)d_in[18];
    const float *Ws1 = (const float*)d_in[19], *bs1 = (const float*)d_in[20];
    const float *Wout = (const float*)d_in[21], *bout = (const float*)d_in[22];

    char* p = (char*)d_ws;
    auto alloc = [&](size_t bytes) -> void* {
        void* r = (void*)p;
        p += (bytes + 255) & ~(size_t)255;
        return r;
    };
    int* deg      = (int*)alloc(NN * 4);
    int* row_ptr  = (int*)alloc((NN + 1) * 4);
    int* cursor   = (int*)alloc(NN * 4);
    int2* csr_se  = (int2*)alloc((size_t)NE * 8);
    float* qb     = (float*)alloc((size_t)NN * HIDU * 4);
    float* kb     = (float*)alloc((size_t)NN * HIDU * 4);
    float* vb     = (float*)alloc((size_t)NN * HIDU * 4);
    float* sbuf   = (float*)alloc((size_t)NN * HIDU * 4);
    float* hbuf   = (float*)alloc((size_t)NN * HIDU * 4);
    u16* xhi      = (u16*)alloc((size_t)NN * HIDU * 2);   // reused for h in layer 2
    u16* xlo      = (u16*)alloc((size_t)NN * HIDU * 2);
    u16* wthi     = (u16*)alloc(8 * 16384 * 2);
    u16* wtlo     = (u16*)alloc(8 * 16384 * 2);

    // CSR build (every call: inputs/ws are re-poisoned)
    k_zero<<<(NN + 255) / 256, 256, 0, stream>>>(deg, NN);
    k_hist<<<(NE + 255) / 256, 256, 0, stream>>>(ei + NE, deg);
    k_scan<<<1, 1024, 0, stream>>>(deg, row_ptr, cursor);
    k_scatter<<<(NE + 255) / 256, 256, 0, stream>>>(ei, cursor, csr_se);

    // weights -> transposed bf16 hi/lo (mats 0-3: layer 0 q,k,v,s; 4-7: layer 1)
    k_cvtw<<<8, 256, 0, stream>>>(Wq0, Wk0, Wv0, Ws0, Wq1, Wk1, Wv1, Ws1, wthi, wtlo);

    const int gcv = (NN * HIDU / 8 + 255) / 256;   // 3125
    const int gm = (NN + 63) / 64;                 // 782
    const int ga = (NN * HEADS * 4) / 256;         // 3125 (exact)

    // layer 1
    k_cvt<<<gcv, 256, 0, stream>>>(x, xhi, xlo);
    gemm_mfma<<<dim3(gm, 4), 256, 0, stream>>>(xhi, xlo, wthi, wtlo,
                                               bq0, bk0, bv0, bs0, qb, kb, vb, sbuf, NN);
    attn<<<ga, 256, 0, stream>>>(qb, kb, vb, sbuf, eattr, We0,
                                 row_ptr, csr_se, hbuf, NN);
    // layer 2
    k_cvt<<<gcv, 256, 0, stream>>>(hbuf, xhi, xlo);
    gemm_mfma<<<dim3(gm, 4), 256, 0, stream>>>(xhi, xlo, wthi + 4 * 16384, wtlo + 4 * 16384,
                                               bq1, bk1, bv1, bs1, qb, kb, vb, sbuf, NN);
    attn<<<ga, 256, 0, stream>>>(qb, kb, vb, sbuf, eattr, We1,
                                 row_ptr, csr_se, hbuf, NN);
    // head
    head_out<<<(NN + 255) / 256, 256, 0, stream>>>(hbuf, Wout, bout, (float*)d_out, NN);
}

// Round 6
// 705.471 us; speedup vs baseline: 2.2328x; 1.2293x over previous
//
#include <hip/hip_runtime.h>

typedef unsigned short u16;
typedef __attribute__((ext_vector_type(8))) u16 u16x8;
typedef __attribute__((ext_vector_type(8))) short short8;   // MFMA A/B frag (8 bf16)
typedef __attribute__((ext_vector_type(4))) float f32x4;    // MFMA C/D frag
typedef __attribute__((ext_vector_type(4))) float f4;

#define NN 50000
#define NE 600000
#define HEADS 4
#define DH 32
#define HIDU 128
#define NC 10

__device__ __forceinline__ float bf2f(u16 u) {
    union { unsigned int i; float f; } c; c.i = ((unsigned int)u) << 16; return c.f;
}
__device__ __forceinline__ u16 f2bf(float f) {
    union { float f; unsigned int i; } c; c.f = f;
    unsigned int x = c.i;
    return (u16)((x + 0x7fffu + ((x >> 16) & 1u)) >> 16);  // RNE
}

// ---------------- CSR build ----------------
__global__ void k_zero(int* p, int n) {
    int i = blockIdx.x * blockDim.x + threadIdx.x;
    if (i < n) p[i] = 0;
}

__global__ void k_hist(const int* __restrict__ dst, int* __restrict__ deg) {
    int i = blockIdx.x * blockDim.x + threadIdx.x;
    if (i < NE) atomicAdd(&deg[dst[i]], 1);
}

__global__ __launch_bounds__(1024) void k_scan(const int* __restrict__ deg,
                                               int* __restrict__ row_ptr,
                                               int* __restrict__ cursor) {
    __shared__ int sums[1024];
    int t = threadIdx.x;
    const int CH = (NN + 1023) / 1024;  // 49
    int base = t * CH;
    int s = 0;
    for (int i = 0; i < CH; i++) { int idx = base + i; if (idx < NN) s += deg[idx]; }
    sums[t] = s;
    __syncthreads();
    for (int off = 1; off < 1024; off <<= 1) {
        int v = 0;
        if (t >= off) v = sums[t - off];
        __syncthreads();
        sums[t] += v;
        __syncthreads();
    }
    int run = sums[t] - s;  // exclusive prefix of this chunk
    for (int i = 0; i < CH; i++) {
        int idx = base + i;
        if (idx < NN) { row_ptr[idx] = run; cursor[idx] = run; run += deg[idx]; }
    }
    if (t == 1023) row_ptr[NN] = run;   // == NE
}

__global__ void k_scatter(const int* __restrict__ ei, int* __restrict__ cursor,
                          int2* __restrict__ csr_se) {
    int i = blockIdx.x * blockDim.x + threadIdx.x;
    if (i < NE) {
        int s = ei[i];
        int d = ei[NE + i];
        int pos = atomicAdd(&cursor[d], 1);
        csr_se[pos] = make_int2(s, i);
    }
}

// ---------------- fp32 -> bf16 hi/lo split ----------------
__global__ __launch_bounds__(256) void k_cvt(const float* __restrict__ in,
                                             u16* __restrict__ hi, u16* __restrict__ lo) {
    int i = blockIdx.x * 256 + threadIdx.x;      // one thread per 8 elems
    const f4* p = (const f4*)(in + (size_t)i * 8);
    f4 a = p[0], b = p[1];
    float v[8] = {a[0], a[1], a[2], a[3], b[0], b[1], b[2], b[3]};
    u16x8 h, l;
    #pragma unroll
    for (int j = 0; j < 8; j++) {
        u16 hh = f2bf(v[j]);
        float r = v[j] - bf2f(hh);
        h[j] = hh; l[j] = f2bf(r);
    }
    *(u16x8*)(hi + (size_t)i * 8) = h;
    *(u16x8*)(lo + (size_t)i * 8) = l;
}

// weights: convert + transpose W[k][n] -> Wt[n][k], hi/lo
__global__ void k_cvtw(const float* w0, const float* w1, const float* w2, const float* w3,
                       const float* w4, const float* w5, const float* w6, const float* w7,
                       u16* __restrict__ hi, u16* __restrict__ lo) {
    const float* w;
    switch (blockIdx.x) {
        case 0: w = w0; break; case 1: w = w1; break;
        case 2: w = w2; break; case 3: w = w3; break;
        case 4: w = w4; break; case 5: w = w5; break;
        case 6: w = w6; break; default: w = w7; break;
    }
    u16* oh = hi + blockIdx.x * 16384;
    u16* ol = lo + blockIdx.x * 16384;
    for (int i = 0; i < 64; i++) {
        int idx = threadIdx.x + i * 256;   // k*128 + n
        int k = idx >> 7, n = idx & 127;
        float v = w[idx];
        u16 h = f2bf(v);
        float r = v - bf2f(h);
        oh[n * 128 + k] = h;
        ol[n * 128 + k] = f2bf(r);
    }
}

// ---------------- MFMA GEMM, bf16x3 split, B staged in LDS (xor-swizzled) ----------------
// grid (391, 4 mats), block 256 = 4 waves x 32 rows (2 rowtiles of 16).
// LDS: hi+lo weight tile = 64 KB exactly. Granule swizzle g' = g ^ (n&15)
// makes frag reads <=2-way bank-aliased (free) without padding.
__global__ __launch_bounds__(256) void gemm_mfma(
    const u16* __restrict__ Xhi, const u16* __restrict__ Xlo,
    const u16* __restrict__ WtHi, const u16* __restrict__ WtLo,   // this layer's 4 mats
    const float* __restrict__ b0, const float* __restrict__ b1,
    const float* __restrict__ b2, const float* __restrict__ b3,
    float* __restrict__ outq, float* __restrict__ outk, float* __restrict__ outv,
    float* __restrict__ outs, int nrows)
{
    __shared__ u16 Bs[2 * 128 * 128];   // [level][n*128 + swizzled k]
    const int mat = blockIdx.y;
    const u16* wh = WtHi + mat * 16384;
    const u16* wl = WtLo + mat * 16384;

    // one-shot staging: 2048 chunks of 8 elems per level, 256 threads -> 8 iters
    #pragma unroll
    for (int i = 0; i < 8; i++) {
        int idx = threadIdx.x + i * 256;        // chunk: row n = idx>>4, granule g = idx&15
        int n = idx >> 4, g = idx & 15;
        int dst = n * 128 + ((g ^ (n & 15)) << 3);
        *(u16x8*)(&Bs[dst])         = *(const u16x8*)(wh + n * 128 + g * 8);
        *(u16x8*)(&Bs[16384 + dst]) = *(const u16x8*)(wl + n * 128 + g * 8);
    }
    __syncthreads();

    const int wave = threadIdx.x >> 6, lane = threadIdx.x & 63;
    const int n0 = lane & 15;              // A row / B col / D col
    const int qw = lane >> 4;
    const int kq = qw * 8;                 // k offset within K32 chunk

    const u16* xh[2]; const u16* xl[2];
    #pragma unroll
    for (int rt = 0; rt < 2; rt++) {
        int arow = blockIdx.x * 128 + wave * 32 + rt * 16 + n0;
        int arow_c = arow < nrows ? arow : nrows - 1;
        xh[rt] = Xhi + (size_t)arow_c * HIDU + kq;
        xl[rt] = Xlo + (size_t)arow_c * HIDU + kq;
    }

    f32x4 acc[2][8];
    #pragma unroll
    for (int rt = 0; rt < 2; rt++)
        #pragma unroll
        for (int nt = 0; nt < 8; nt++) acc[rt][nt] = (f32x4){0.f, 0.f, 0.f, 0.f};

    #pragma unroll
    for (int ks = 0; ks < 4; ks++) {
        short8 ah[2], al[2];
        #pragma unroll
        for (int rt = 0; rt < 2; rt++) {
            ah[rt] = *(const short8*)(xh[rt] + ks * 32);
            al[rt] = *(const short8*)(xl[rt] + ks * 32);
        }
        #pragma unroll
        for (int nt = 0; nt < 8; nt++) {
            const int boff = (nt * 16 + n0) * 128 + (((ks << 2) + qw) ^ n0) * 8;
            short8 bh = *(const short8*)(&Bs[boff]);
            short8 bl = *(const short8*)(&Bs[16384 + boff]);
            #pragma unroll
            for (int rt = 0; rt < 2; rt++) {
                acc[rt][nt] = __builtin_amdgcn_mfma_f32_16x16x32_bf16(ah[rt], bh, acc[rt][nt], 0, 0, 0);
                acc[rt][nt] = __builtin_amdgcn_mfma_f32_16x16x32_bf16(al[rt], bh, acc[rt][nt], 0, 0, 0);
                acc[rt][nt] = __builtin_amdgcn_mfma_f32_16x16x32_bf16(ah[rt], bl, acc[rt][nt], 0, 0, 0);
            }
        }
    }

    const float* bia = (mat == 0) ? b0 : (mat == 1) ? b1 : (mat == 2) ? b2 : b3;
    float* o = (mat == 0) ? outq : (mat == 1) ? outk : (mat == 2) ? outv : outs;
    #pragma unroll
    for (int rt = 0; rt < 2; rt++) {
        const int rbase = blockIdx.x * 128 + wave * 32 + rt * 16 + qw * 4;
        #pragma unroll
        for (int nt = 0; nt < 8; nt++) {
            int col = nt * 16 + n0;
            float bv = bia[col];
            #pragma unroll
            for (int r = 0; r < 4; r++) {
                int grow = rbase + r;
                if (grow < nrows) o[(size_t)grow * HIDU + col] = acc[rt][nt][r] + bv;
            }
        }
    }
}

// ---------------- fused attention: FOUR lanes per (node, head) ----------------
// lane owns 8 of 32 channels; q.k partial reduced via 4-lane shfl-xor butterfly;
// e-dot computed redundantly per lane (added AFTER the butterfly, so counted once).
// online softmax state m,l identical across the 4 lanes (divergence-free).
// mode 0: emit bf16 hi/lo split (feeds next gemm); mode 1: emit fp32.
__global__ __launch_bounds__(256) void attn(
    const float* __restrict__ qb, const float* __restrict__ kb, const float* __restrict__ vb,
    const float* __restrict__ sb, const float* __restrict__ eattr, const float* __restrict__ We,
    const int* __restrict__ row_ptr, const int2* __restrict__ csr_se,
    float* __restrict__ hout_f32, u16* __restrict__ hout_hi, u16* __restrict__ hout_lo,
    int mode)
{
    __shared__ float WeS[4 * 513];   // [h][t*32+j]
    #pragma unroll
    for (int i = 0; i < 8; i++) {
        int idx = threadIdx.x + i * 256;   // t*128 + c over 16x128
        int tt = idx >> 7, c = idx & 127;
        int h = c >> 5, j = c & 31;
        WeS[h * 513 + tt * 32 + j] = We[idx];
    }
    __syncthreads();

    int gtid = blockIdx.x * 256 + threadIdx.x;   // grid is exactly NN*HEADS*4 threads
    int pair = gtid >> 2;        // (node, head)
    int sub  = gtid & 3;         // lane-in-group
    int n = pair >> 2, h = pair & 3;
    const float* WeH = &WeS[h * 513];
    const int j0 = sub * 8;      // own channel base

    // own 8 q channels
    float qreg[8];
    {
        const f4* qp = (const f4*)(qb + (size_t)n * HIDU + h * DH + j0);
        f4 a = qp[0], b = qp[1];
        #pragma unroll
        for (int j = 0; j < 4; j++) { qreg[j] = a[j]; qreg[4 + j] = b[j]; }
    }

    // g[t] full per lane: partial over own j, butterfly over the 4-lane group
    float g[16];
    #pragma unroll
    for (int t16 = 0; t16 < 16; t16++) {
        float a = 0.f;
        #pragma unroll
        for (int jj = 0; jj < 8; jj++) a += qreg[jj] * WeH[t16 * 32 + j0 + jj];
        g[t16] = a;
    }
    #pragma unroll
    for (int t16 = 0; t16 < 16; t16++) g[t16] += __shfl_xor(g[t16], 1);
    #pragma unroll
    for (int t16 = 0; t16 < 16; t16++) g[t16] += __shfl_xor(g[t16], 2);

    float m = -INFINITY, l = 0.f;
    float O[8];
    float a16[16];
    #pragma unroll
    for (int j = 0; j < 8; j++) O[j] = 0.f;
    #pragma unroll
    for (int t16 = 0; t16 < 16; t16++) a16[t16] = 0.f;

    const int r0 = row_ptr[n], r1 = row_ptr[n + 1];
    const float inv = 0.17677669529663687f;   // 1/sqrt(32)

    for (int e = r0; e < r1; e++) {
        int2 se = csr_se[e];
        const float* kp = kb + (size_t)se.x * HIDU + h * DH + j0;
        const float* vp = vb + (size_t)se.x * HIDU + h * DH + j0;
        const f4* ep = (const f4*)(eattr + (size_t)se.y * 16);

        f4 k0 = *(const f4*)kp,       k1 = *(const f4*)(kp + 4);
        f4 v0 = *(const f4*)vp,       v1 = *(const f4*)(vp + 4);
        f4 e0 = ep[0], e1 = ep[1], e2 = ep[2], e3 = ep[3];
        float ea[16];
        #pragma unroll
        for (int j = 0; j < 4; j++) {
            ea[j] = e0[j]; ea[4 + j] = e1[j]; ea[8 + j] = e2[j]; ea[12 + j] = e3[j];
        }

        // partial k-dot over own 8 channels, butterfly to full
        float dp = 0.f;
        #pragma unroll
        for (int j = 0; j < 4; j++) dp += qreg[j] * k0[j] + qreg[4 + j] * k1[j];
        dp += __shfl_xor(dp, 1);
        dp += __shfl_xor(dp, 2);
        // full e-dot locally (identical in all 4 lanes, added once)
        float dot = dp;
        #pragma unroll
        for (int t16 = 0; t16 < 16; t16++) dot += g[t16] * ea[t16];

        float logit = dot * inv;
        float mn = fmaxf(m, logit);
        float corr = __expf(m - mn);      // first edge: exp(-inf)=0
        float w = __expf(logit - mn);
        l = l * corr + w;
        #pragma unroll
        for (int j = 0; j < 4; j++) {
            O[j]     = O[j]     * corr + w * v0[j];
            O[4 + j] = O[4 + j] * corr + w * v1[j];
        }
        #pragma unroll
        for (int t16 = 0; t16 < 16; t16++) a16[t16] = a16[t16] * corr + w * ea[t16];
        m = mn;
    }

    float invl = 1.0f / (l + 1e-16f);     // PyG softmax eps; zero-degree -> O=0
    const float* sp = sb + (size_t)n * HIDU + h * DH + j0;
    const size_t obase = (size_t)n * HIDU + h * DH + j0;

    float vals[8];
    #pragma unroll
    for (int j = 0; j < 8; j++) {
        float ev = 0.f;
        #pragma unroll
        for (int t16 = 0; t16 < 16; t16++) ev += a16[t16] * WeH[t16 * 32 + j0 + j];
        vals[j] = fmaxf((O[j] + ev) * invl + sp[j], 0.f);   // relu(conv_out)
    }
    if (mode == 0) {
        u16x8 hh, ll;
        #pragma unroll
        for (int j = 0; j < 8; j++) {
            u16 hv = f2bf(vals[j]);
            hh[j] = hv;
            ll[j] = f2bf(vals[j] - bf2f(hv));
        }
        *(u16x8*)(hout_hi + obase) = hh;
        *(u16x8*)(hout_lo + obase) = ll;
    } else {
        f4 r0v, r1v;
        #pragma unroll
        for (int j = 0; j < 4; j++) { r0v[j] = vals[j]; r1v[j] = vals[4 + j]; }
        *(f4*)(hout_f32 + obase) = r0v;
        *(f4*)(hout_f32 + obase + 4) = r1v;
    }
}

// ---------------- head: logits + log_softmax ----------------
__global__ __launch_bounds__(256) void head_out(
    const float* __restrict__ hb, const float* __restrict__ Wout, const float* __restrict__ bout,
    float* __restrict__ out, int nnodes)
{
    __shared__ float Ws[HIDU * NC];
    __shared__ float bs[NC];
    for (int i = 0; i < 5; i++) {
        int idx = threadIdx.x + i * 256;
        if (idx < HIDU * NC) Ws[idx] = Wout[idx];
    }
    if (threadIdx.x < NC) bs[threadIdx.x] = bout[threadIdx.x];
    __syncthreads();

    int n = blockIdx.x * 256 + threadIdx.x;
    if (n >= nnodes) return;

    float lg[NC];
    #pragma unroll
    for (int c = 0; c < NC; c++) lg[c] = bs[c];
    const f4* hp = (const f4*)(hb + (size_t)n * HIDU);
    #pragma unroll
    for (int kc = 0; kc < 32; kc++) {
        f4 hv = hp[kc];
        #pragma unroll
        for (int j = 0; j < 4; j++) {
            float h = hv[j];
            int kk = kc * 4 + j;
            #pragma unroll
            for (int c = 0; c < NC; c++) lg[c] += h * Ws[kk * NC + c];
        }
    }
    float mx = lg[0];
    #pragma unroll
    for (int c = 1; c < NC; c++) mx = fmaxf(mx, lg[c]);
    float sum = 0.f;
    #pragma unroll
    for (int c = 0; c < NC; c++) sum += __expf(lg[c] - mx);
    float lse = mx + __logf(sum);
    #pragma unroll
    for (int c = 0; c < NC; c++) out[(size_t)n * NC + c] = lg[c] - lse;
}

// ---------------- launch ----------------
extern "C" void kernel_launch(void* const* d_in, const int* in_sizes, int n_in,
                              void* d_out, int out_size, void* d_ws, size_t ws_size,
                              hipStream_t stream) {
    const float* x     = (const float*)d_in[0];
    const int*   ei    = (const int*)d_in[1];
    const float* eattr = (const float*)d_in[2];
    const float *Wq0 = (const float*)d_in[3],  *bq0 = (const float*)d_in[4];
    const float *Wk0 = (const float*)d_in[5],  *bk0 = (const float*)d_in[6];
    const float *Wv0 = (const float*)d_in[7],  *bv0 = (const float*)d_in[8];
    const float *We0 = (const float*)d_in[9];
    const float *Ws0 = (const float*)d_in[10], *bs0 = (const float*)d_in[11];
    const float *Wq1 = (const float*)d_in[12], *bq1 = (const float*)d_in[13];
    const float *Wk1 = (const float*)d_in[14], *bk1 = (const float*)d_in[15];
    const float *Wv1 = (const float*)d_in[16], *bv1 = (const float*)d_in[17];
    const float *We1 = (const float*)d_in[18];
    const float *Ws1 = (const float*)d_in[19], *bs1 = (const float*)d_in[20];
    const float *Wout = (const float*)d_in[21], *bout = (const float*)d_in[22];

    char* p = (char*)d_ws;
    auto alloc = [&](size_t bytes) -> void* {
        void* r = (void*)p;
        p += (bytes + 255) & ~(size_t)255;
        return r;
    };
    int* deg      = (int*)alloc(NN * 4);
    int* row_ptr  = (int*)alloc((NN + 1) * 4);
    int* cursor   = (int*)alloc(NN * 4);
    int2* csr_se  = (int2*)alloc((size_t)NE * 8);
    float* qb     = (float*)alloc((size_t)NN * HIDU * 4);
    float* kb     = (float*)alloc((size_t)NN * HIDU * 4);
    float* vb     = (float*)alloc((size_t)NN * HIDU * 4);
    float* sbuf   = (float*)alloc((size_t)NN * HIDU * 4);
    float* hbuf   = (float*)alloc((size_t)NN * HIDU * 4);
    u16* xhi      = (u16*)alloc((size_t)NN * HIDU * 2);   // layer-1: cvt(x); layer-2: attn1 output
    u16* xlo      = (u16*)alloc((size_t)NN * HIDU * 2);
    u16* wthi     = (u16*)alloc(8 * 16384 * 2);
    u16* wtlo     = (u16*)alloc(8 * 16384 * 2);

    // CSR build (every call: inputs/ws are re-poisoned)
    k_zero<<<(NN + 255) / 256, 256, 0, stream>>>(deg, NN);
    k_hist<<<(NE + 255) / 256, 256, 0, stream>>>(ei + NE, deg);
    k_scan<<<1, 1024, 0, stream>>>(deg, row_ptr, cursor);
    k_scatter<<<(NE + 255) / 256, 256, 0, stream>>>(ei, cursor, csr_se);

    // weights -> transposed bf16 hi/lo (mats 0-3: layer 0 q,k,v,s; 4-7: layer 1)
    k_cvtw<<<8, 256, 0, stream>>>(Wq0, Wk0, Wv0, Ws0, Wq1, Wk1, Wv1, Ws1, wthi, wtlo);

    const int gcv = (NN * HIDU / 8 + 255) / 256;   // 3125
    const int gm = (NN + 127) / 128;               // 391
    const int ga = (NN * HEADS * 4) / 256;         // 3125 (exact)

    // layer 1
    k_cvt<<<gcv, 256, 0, stream>>>(x, xhi, xlo);
    gemm_mfma<<<dim3(gm, 4), 256, 0, stream>>>(xhi, xlo, wthi, wtlo,
                                               bq0, bk0, bv0, bs0, qb, kb, vb, sbuf, NN);
    attn<<<ga, 256, 0, stream>>>(qb, kb, vb, sbuf, eattr, We0,
                                 row_ptr, csr_se, hbuf, xhi, xlo, 0);  // h1 -> bf16 hi/lo
    // layer 2 (gemm consumes attn1's split output directly)
    gemm_mfma<<<dim3(gm, 4), 256, 0, stream>>>(xhi, xlo, wthi + 4 * 16384, wtlo + 4 * 16384,
                                               bq1, bk1, bv1, bs1, qb, kb, vb, sbuf, NN);
    attn<<<ga, 256, 0, stream>>>(qb, kb, vb, sbuf, eattr, We1,
                                 row_ptr, csr_se, hbuf, (u16*)nullptr, (u16*)nullptr, 1);
    // head
    head_out<<<(NN + 255) / 256, 256, 0, stream>>>(hbuf, Wout, bout, (float*)d_out, NN);
}

// Round 7
// 560.833 us; speedup vs baseline: 2.8086x; 1.2579x over previous
//
#include <hip/hip_runtime.h>

typedef unsigned short u16;
typedef __attribute__((ext_vector_type(8))) u16 u16x8;
typedef __attribute__((ext_vector_type(8))) short short8;   // MFMA A/B frag (8 bf16)
typedef __attribute__((ext_vector_type(4))) float f32x4;    // MFMA C/D frag
typedef __attribute__((ext_vector_type(4))) float f4;

#define NN 50000
#define NE 600000
#define HEADS 4
#define DH 32
#define HIDU 128
#define NC 10
#define NBLK 196   // ceil(NN/256)

__device__ __forceinline__ float bf2f(u16 u) {
    union { unsigned int i; float f; } c; c.i = ((unsigned int)u) << 16; return c.f;
}
__device__ __forceinline__ u16 f2bf(float f) {
    union { float f; unsigned int i; } c; c.f = f;
    unsigned int x = c.i;
    return (u16)((x + 0x7fffu + ((x >> 16) & 1u)) >> 16);  // RNE
}

// ---------------- CSR build ----------------
__global__ void k_zero(int* p, int n) {
    int i = blockIdx.x * blockDim.x + threadIdx.x;
    if (i < n) p[i] = 0;
}

__global__ void k_hist(const int* __restrict__ dst, int* __restrict__ deg) {
    int i = blockIdx.x * blockDim.x + threadIdx.x;
    if (i < NE) atomicAdd(&deg[dst[i]], 1);
}

// multi-block scan: A) per-block sums  B) scan of block sums  C) per-element
__global__ __launch_bounds__(256) void scan_a(const int* __restrict__ deg,
                                              int* __restrict__ bsum) {
    __shared__ int red[4];
    int i = blockIdx.x * 256 + threadIdx.x;
    int v = (i < NN) ? deg[i] : 0;
    #pragma unroll
    for (int off = 1; off < 64; off <<= 1) v += __shfl_xor(v, off);
    if ((threadIdx.x & 63) == 0) red[threadIdx.x >> 6] = v;
    __syncthreads();
    if (threadIdx.x == 0) bsum[blockIdx.x] = red[0] + red[1] + red[2] + red[3];
}

__global__ __launch_bounds__(256) void scan_b(const int* __restrict__ bsum,
                                              int* __restrict__ boff,
                                              int* __restrict__ row_ptr) {
    __shared__ int s[256];
    int t = threadIdx.x;
    int v = (t < NBLK) ? bsum[t] : 0;
    s[t] = v;
    __syncthreads();
    for (int off = 1; off < 256; off <<= 1) {
        int x = (t >= off) ? s[t - off] : 0;
        __syncthreads();
        s[t] += x;
        __syncthreads();
    }
    if (t < NBLK) boff[t] = s[t] - v;   // exclusive
    if (t == 0) row_ptr[NN] = NE;       // total degree is statically NE
}

__global__ __launch_bounds__(256) void scan_c(const int* __restrict__ deg,
                                              const int* __restrict__ boff,
                                              int* __restrict__ row_ptr,
                                              int* __restrict__ cursor) {
    __shared__ int s[256];
    int t = threadIdx.x;
    int i = blockIdx.x * 256 + t;
    int v = (i < NN) ? deg[i] : 0;
    s[t] = v;
    __syncthreads();
    for (int off = 1; off < 256; off <<= 1) {
        int x = (t >= off) ? s[t - off] : 0;
        __syncthreads();
        s[t] += x;
        __syncthreads();
    }
    if (i < NN) {
        int r = boff[blockIdx.x] + s[t] - v;
        row_ptr[i] = r;
        cursor[i] = r;
    }
}

__global__ void k_scatter(const int* __restrict__ ei, int* __restrict__ cursor,
                          int2* __restrict__ csr_se) {
    int i = blockIdx.x * blockDim.x + threadIdx.x;
    if (i < NE) {
        int s = ei[i];
        int d = ei[NE + i];
        int pos = atomicAdd(&cursor[d], 1);
        csr_se[pos] = make_int2(s, i);
    }
}

// ---------------- fp32 -> bf16 hi/lo split ----------------
__global__ __launch_bounds__(256) void k_cvt(const float* __restrict__ in,
                                             u16* __restrict__ hi, u16* __restrict__ lo) {
    int i = blockIdx.x * 256 + threadIdx.x;      // one thread per 8 elems
    const f4* p = (const f4*)(in + (size_t)i * 8);
    f4 a = p[0], b = p[1];
    float v[8] = {a[0], a[1], a[2], a[3], b[0], b[1], b[2], b[3]};
    u16x8 h, l;
    #pragma unroll
    for (int j = 0; j < 8; j++) {
        u16 hh = f2bf(v[j]);
        float r = v[j] - bf2f(hh);
        h[j] = hh; l[j] = f2bf(r);
    }
    *(u16x8*)(hi + (size_t)i * 8) = h;
    *(u16x8*)(lo + (size_t)i * 8) = l;
}

// weights: convert + transpose W[k][n] -> Wt[n][k], hi/lo
__global__ void k_cvtw(const float* w0, const float* w1, const float* w2, const float* w3,
                       const float* w4, const float* w5, const float* w6, const float* w7,
                       u16* __restrict__ hi, u16* __restrict__ lo) {
    const float* w;
    switch (blockIdx.x) {
        case 0: w = w0; break; case 1: w = w1; break;
        case 2: w = w2; break; case 3: w = w3; break;
        case 4: w = w4; break; case 5: w = w5; break;
        case 6: w = w6; break; default: w = w7; break;
    }
    u16* oh = hi + blockIdx.x * 16384;
    u16* ol = lo + blockIdx.x * 16384;
    for (int i = 0; i < 64; i++) {
        int idx = threadIdx.x + i * 256;   // k*128 + n
        int k = idx >> 7, n = idx & 127;
        float v = w[idx];
        u16 h = f2bf(v);
        float r = v - bf2f(h);
        oh[n * 128 + k] = h;
        ol[n * 128 + k] = f2bf(r);
    }
}

// ---------------- MFMA GEMM, bf16x3 split, B staged in LDS (xor-swizzled) ----------------
// grid (391, 4 mats), block 256 = 4 waves x 32 rows (2 rowtiles of 16).
__global__ __launch_bounds__(256) void gemm_mfma(
    const u16* __restrict__ Xhi, const u16* __restrict__ Xlo,
    const u16* __restrict__ WtHi, const u16* __restrict__ WtLo,   // this layer's 4 mats
    const float* __restrict__ b0, const float* __restrict__ b1,
    const float* __restrict__ b2, const float* __restrict__ b3,
    float* __restrict__ outq, float* __restrict__ outk, float* __restrict__ outv,
    float* __restrict__ outs, int nrows)
{
    __shared__ u16 Bs[2 * 128 * 128];   // [level][n*128 + swizzled k]
    const int mat = blockIdx.y;
    const u16* wh = WtHi + mat * 16384;
    const u16* wl = WtLo + mat * 16384;

    #pragma unroll
    for (int i = 0; i < 8; i++) {
        int idx = threadIdx.x + i * 256;        // chunk: row n = idx>>4, granule g = idx&15
        int n = idx >> 4, g = idx & 15;
        int dst = n * 128 + ((g ^ (n & 15)) << 3);
        *(u16x8*)(&Bs[dst])         = *(const u16x8*)(wh + n * 128 + g * 8);
        *(u16x8*)(&Bs[16384 + dst]) = *(const u16x8*)(wl + n * 128 + g * 8);
    }
    __syncthreads();

    const int wave = threadIdx.x >> 6, lane = threadIdx.x & 63;
    const int n0 = lane & 15;              // A row / B col / D col
    const int qw = lane >> 4;
    const int kq = qw * 8;                 // k offset within K32 chunk

    const u16* xh[2]; const u16* xl[2];
    #pragma unroll
    for (int rt = 0; rt < 2; rt++) {
        int arow = blockIdx.x * 128 + wave * 32 + rt * 16 + n0;
        int arow_c = arow < nrows ? arow : nrows - 1;
        xh[rt] = Xhi + (size_t)arow_c * HIDU + kq;
        xl[rt] = Xlo + (size_t)arow_c * HIDU + kq;
    }

    f32x4 acc[2][8];
    #pragma unroll
    for (int rt = 0; rt < 2; rt++)
        #pragma unroll
        for (int nt = 0; nt < 8; nt++) acc[rt][nt] = (f32x4){0.f, 0.f, 0.f, 0.f};

    #pragma unroll
    for (int ks = 0; ks < 4; ks++) {
        short8 ah[2], al[2];
        #pragma unroll
        for (int rt = 0; rt < 2; rt++) {
            ah[rt] = *(const short8*)(xh[rt] + ks * 32);
            al[rt] = *(const short8*)(xl[rt] + ks * 32);
        }
        #pragma unroll
        for (int nt = 0; nt < 8; nt++) {
            const int boff = (nt * 16 + n0) * 128 + (((ks << 2) + qw) ^ n0) * 8;
            short8 bh = *(const short8*)(&Bs[boff]);
            short8 bl = *(const short8*)(&Bs[16384 + boff]);
            #pragma unroll
            for (int rt = 0; rt < 2; rt++) {
                acc[rt][nt] = __builtin_amdgcn_mfma_f32_16x16x32_bf16(ah[rt], bh, acc[rt][nt], 0, 0, 0);
                acc[rt][nt] = __builtin_amdgcn_mfma_f32_16x16x32_bf16(al[rt], bh, acc[rt][nt], 0, 0, 0);
                acc[rt][nt] = __builtin_amdgcn_mfma_f32_16x16x32_bf16(ah[rt], bl, acc[rt][nt], 0, 0, 0);
            }
        }
    }

    const float* bia = (mat == 0) ? b0 : (mat == 1) ? b1 : (mat == 2) ? b2 : b3;
    float* o = (mat == 0) ? outq : (mat == 1) ? outk : (mat == 2) ? outv : outs;
    #pragma unroll
    for (int rt = 0; rt < 2; rt++) {
        const int rbase = blockIdx.x * 128 + wave * 32 + rt * 16 + qw * 4;
        #pragma unroll
        for (int nt = 0; nt < 8; nt++) {
            int col = nt * 16 + n0;
            float bv = bia[col];
            #pragma unroll
            for (int r = 0; r < 4; r++) {
                int grow = rbase + r;
                if (grow < nrows) o[(size_t)grow * HIDU + col] = acc[rt][nt][r] + bv;
            }
        }
    }
}

// ---------------- fused attention: 4 lanes per (node, head), 2 edges/iter ----------------
// lane owns 8 of 32 k/v channels AND 4 of 16 e-channels; the single shfl-xor
// butterfly sums both k-dot and e-dot partials. g4 (own 4 rows of We_h^T q)
// computed in preamble from the full q row. a16 distributed (4/lane), gathered
// once in the epilogue via __shfl. Pairwise online softmax; odd tail handled
// by logit1=-inf -> w1=0. mode 0: emit bf16 hi/lo; mode 1: emit fp32.
__global__ __launch_bounds__(256) void attn(
    const float* __restrict__ qb, const float* __restrict__ kb, const float* __restrict__ vb,
    const float* __restrict__ sb, const float* __restrict__ eattr, const float* __restrict__ We,
    const int* __restrict__ row_ptr, const int2* __restrict__ csr_se,
    float* __restrict__ hout_f32, u16* __restrict__ hout_hi, u16* __restrict__ hout_lo,
    int mode)
{
    __shared__ float WeS[4 * 513];   // [h][t*32+j]
    #pragma unroll
    for (int i = 0; i < 8; i++) {
        int idx = threadIdx.x + i * 256;   // t*128 + c over 16x128
        int tt = idx >> 7, c = idx & 127;
        int h = c >> 5, j = c & 31;
        WeS[h * 513 + tt * 32 + j] = We[idx];
    }
    __syncthreads();

    int gtid = blockIdx.x * 256 + threadIdx.x;   // grid is exactly NN*HEADS*4 threads
    int pair = gtid >> 2;        // (node, head)
    int sub  = gtid & 3;         // lane-in-group
    int n = pair >> 2, h = pair & 3;
    const int lane = threadIdx.x & 63;
    const float* WeH = &WeS[h * 513];
    const int j0 = sub * 8;      // own k/v channel base
    const int t0 = sub * 4;      // own e-channel base

    // full q row for this head (preamble only), own 8 channels kept
    float qreg[8];
    float g4[4];
    {
        const f4* qp = (const f4*)(qb + (size_t)n * HIDU + h * DH);
        float q32[32];
        #pragma unroll
        for (int c = 0; c < 8; c++) {
            f4 x = qp[c];
            #pragma unroll
            for (int j = 0; j < 4; j++) q32[c * 4 + j] = x[j];
        }
        #pragma unroll
        for (int tt = 0; tt < 4; tt++) {
            float a = 0.f;
            #pragma unroll
            for (int j = 0; j < 32; j++) a += q32[j] * WeH[(t0 + tt) * 32 + j];
            g4[tt] = a;
        }
        const f4* qpo = (const f4*)(qb + (size_t)n * HIDU + h * DH + j0);
        f4 a = qpo[0], b = qpo[1];
        #pragma unroll
        for (int j = 0; j < 4; j++) { qreg[j] = a[j]; qreg[4 + j] = b[j]; }
    }

    float m = -INFINITY, l = 0.f;
    float O[8];
    float a4[4];
    #pragma unroll
    for (int j = 0; j < 8; j++) O[j] = 0.f;
    #pragma unroll
    for (int tt = 0; tt < 4; tt++) a4[tt] = 0.f;

    const int r0 = row_ptr[n], r1 = row_ptr[n + 1];
    const float inv = 0.17677669529663687f;   // 1/sqrt(32)

    for (int e = r0; e < r1; e += 2) {
        bool has2 = (e + 1 < r1);
        int2 se0 = csr_se[e];
        int2 se1 = csr_se[has2 ? e + 1 : e];

        const float* kp0 = kb + (size_t)se0.x * HIDU + h * DH + j0;
        const float* vp0 = vb + (size_t)se0.x * HIDU + h * DH + j0;
        const float* kp1 = kb + (size_t)se1.x * HIDU + h * DH + j0;
        const float* vp1 = vb + (size_t)se1.x * HIDU + h * DH + j0;
        f4 k0a = *(const f4*)kp0, k0b = *(const f4*)(kp0 + 4);
        f4 v0a = *(const f4*)vp0, v0b = *(const f4*)(vp0 + 4);
        f4 k1a = *(const f4*)kp1, k1b = *(const f4*)(kp1 + 4);
        f4 v1a = *(const f4*)vp1, v1b = *(const f4*)(vp1 + 4);
        f4 ea0 = *(const f4*)(eattr + (size_t)se0.y * 16 + t0);
        f4 ea1 = *(const f4*)(eattr + (size_t)se1.y * 16 + t0);

        // partial dots (k over own 8 ch + e over own 4 ch), one butterfly for both
        float d0 = 0.f, d1 = 0.f;
        #pragma unroll
        for (int j = 0; j < 4; j++) {
            d0 += qreg[j] * k0a[j] + qreg[4 + j] * k0b[j];
            d1 += qreg[j] * k1a[j] + qreg[4 + j] * k1b[j];
        }
        #pragma unroll
        for (int tt = 0; tt < 4; tt++) {
            d0 += g4[tt] * ea0[tt];
            d1 += g4[tt] * ea1[tt];
        }
        d0 += __shfl_xor(d0, 1);  d1 += __shfl_xor(d1, 1);
        d0 += __shfl_xor(d0, 2);  d1 += __shfl_xor(d1, 2);

        float logit0 = d0 * inv;
        float logit1 = has2 ? d1 * inv : -INFINITY;
        float mn = fmaxf(m, fmaxf(logit0, logit1));
        float corr = __expf(m - mn);        // first iter: exp(-inf)=0
        float w0 = __expf(logit0 - mn);
        float w1 = __expf(logit1 - mn);     // odd tail: exp(-inf)=0
        l = l * corr + w0 + w1;
        #pragma unroll
        for (int j = 0; j < 4; j++) {
            O[j]     = O[j]     * corr + w0 * v0a[j] + w1 * v1a[j];
            O[4 + j] = O[4 + j] * corr + w0 * v0b[j] + w1 * v1b[j];
        }
        #pragma unroll
        for (int tt = 0; tt < 4; tt++)
            a4[tt] = a4[tt] * corr + w0 * ea0[tt] + w1 * ea1[tt];
        m = mn;
    }

    // gather distributed a16 (once per node)
    float af[16];
    #pragma unroll
    for (int t = 0; t < 16; t++)
        af[t] = __shfl(a4[t & 3], (lane & ~3) | (t >> 2));

    float invl = 1.0f / (l + 1e-16f);     // PyG softmax eps; zero-degree -> O=0
    const float* sp = sb + (size_t)n * HIDU + h * DH + j0;
    const size_t obase = (size_t)n * HIDU + h * DH + j0;

    float vals[8];
    #pragma unroll
    for (int j = 0; j < 8; j++) {
        float ev = 0.f;
        #pragma unroll
        for (int t = 0; t < 16; t++) ev += af[t] * WeH[t * 32 + j0 + j];
        vals[j] = fmaxf((O[j] + ev) * invl + sp[j], 0.f);   // relu(conv_out)
    }
    if (mode == 0) {
        u16x8 hh, ll;
        #pragma unroll
        for (int j = 0; j < 8; j++) {
            u16 hv = f2bf(vals[j]);
            hh[j] = hv;
            ll[j] = f2bf(vals[j] - bf2f(hv));
        }
        *(u16x8*)(hout_hi + obase) = hh;
        *(u16x8*)(hout_lo + obase) = ll;
    } else {
        f4 r0v, r1v;
        #pragma unroll
        for (int j = 0; j < 4; j++) { r0v[j] = vals[j]; r1v[j] = vals[4 + j]; }
        *(f4*)(hout_f32 + obase) = r0v;
        *(f4*)(hout_f32 + obase + 4) = r1v;
    }
}

// ---------------- head: logits + log_softmax ----------------
__global__ __launch_bounds__(256) void head_out(
    const float* __restrict__ hb, const float* __restrict__ Wout, const float* __restrict__ bout,
    float* __restrict__ out, int nnodes)
{
    __shared__ float Ws[HIDU * NC];
    __shared__ float bs[NC];
    for (int i = 0; i < 5; i++) {
        int idx = threadIdx.x + i * 256;
        if (idx < HIDU * NC) Ws[idx] = Wout[idx];
    }
    if (threadIdx.x < NC) bs[threadIdx.x] = bout[threadIdx.x];
    __syncthreads();

    int n = blockIdx.x * 256 + threadIdx.x;
    if (n >= nnodes) return;

    float lg[NC];
    #pragma unroll
    for (int c = 0; c < NC; c++) lg[c] = bs[c];
    const f4* hp = (const f4*)(hb + (size_t)n * HIDU);
    #pragma unroll
    for (int kc = 0; kc < 32; kc++) {
        f4 hv = hp[kc];
        #pragma unroll
        for (int j = 0; j < 4; j++) {
            float h = hv[j];
            int kk = kc * 4 + j;
            #pragma unroll
            for (int c = 0; c < NC; c++) lg[c] += h * Ws[kk * NC + c];
        }
    }
    float mx = lg[0];
    #pragma unroll
    for (int c = 1; c < NC; c++) mx = fmaxf(mx, lg[c]);
    float sum = 0.f;
    #pragma unroll
    for (int c = 0; c < NC; c++) sum += __expf(lg[c] - mx);
    float lse = mx + __logf(sum);
    #pragma unroll
    for (int c = 0; c < NC; c++) out[(size_t)n * NC + c] = lg[c] - lse;
}

// ---------------- launch ----------------
extern "C" void kernel_launch(void* const* d_in, const int* in_sizes, int n_in,
                              void* d_out, int out_size, void* d_ws, size_t ws_size,
                              hipStream_t stream) {
    const float* x     = (const float*)d_in[0];
    const int*   ei    = (const int*)d_in[1];
    const float* eattr = (const float*)d_in[2];
    const float *Wq0 = (const float*)d_in[3],  *bq0 = (const float*)d_in[4];
    const float *Wk0 = (const float*)d_in[5],  *bk0 = (const float*)d_in[6];
    const float *Wv0 = (const float*)d_in[7],  *bv0 = (const float*)d_in[8];
    const float *We0 = (const float*)d_in[9];
    const float *Ws0 = (const float*)d_in[10], *bs0 = (const float*)d_in[11];
    const float *Wq1 = (const float*)d_in[12], *bq1 = (const float*)d_in[13];
    const float *Wk1 = (const float*)d_in[14], *bk1 = (const float*)d_in[15];
    const float *Wv1 = (const float*)d_in[16], *bv1 = (const float*)d_in[17];
    const float *We1 = (const float*)d_in[18];
    const float *Ws1 = (const float*)d_in[19], *bs1 = (const float*)d_in[20];
    const float *Wout = (const float*)d_in[21], *bout = (const float*)d_in[22];

    char* p = (char*)d_ws;
    auto alloc = [&](size_t bytes) -> void* {
        void* r = (void*)p;
        p += (bytes + 255) & ~(size_t)255;
        return r;
    };
    int* deg      = (int*)alloc(NN * 4);
    int* row_ptr  = (int*)alloc((NN + 1) * 4);
    int* cursor   = (int*)alloc(NN * 4);
    int* bsum     = (int*)alloc(NBLK * 4);
    int* boff     = (int*)alloc(NBLK * 4);
    int2* csr_se  = (int2*)alloc((size_t)NE * 8);
    float* qb     = (float*)alloc((size_t)NN * HIDU * 4);
    float* kb     = (float*)alloc((size_t)NN * HIDU * 4);
    float* vb     = (float*)alloc((size_t)NN * HIDU * 4);
    float* sbuf   = (float*)alloc((size_t)NN * HIDU * 4);
    float* hbuf   = (float*)alloc((size_t)NN * HIDU * 4);
    u16* xhi      = (u16*)alloc((size_t)NN * HIDU * 2);   // layer-1: cvt(x); layer-2: attn1 output
    u16* xlo      = (u16*)alloc((size_t)NN * HIDU * 2);
    u16* wthi     = (u16*)alloc(8 * 16384 * 2);
    u16* wtlo     = (u16*)alloc(8 * 16384 * 2);

    // CSR build (every call: inputs/ws are re-poisoned)
    k_zero<<<(NN + 255) / 256, 256, 0, stream>>>(deg, NN);
    k_hist<<<(NE + 255) / 256, 256, 0, stream>>>(ei + NE, deg);
    scan_a<<<NBLK, 256, 0, stream>>>(deg, bsum);
    scan_b<<<1, 256, 0, stream>>>(bsum, boff, row_ptr);
    scan_c<<<NBLK, 256, 0, stream>>>(deg, boff, row_ptr, cursor);
    k_scatter<<<(NE + 255) / 256, 256, 0, stream>>>(ei, cursor, csr_se);

    // weights -> transposed bf16 hi/lo (mats 0-3: layer 0 q,k,v,s; 4-7: layer 1)
    k_cvtw<<<8, 256, 0, stream>>>(Wq0, Wk0, Wv0, Ws0, Wq1, Wk1, Wv1, Ws1, wthi, wtlo);

    const int gcv = (NN * HIDU / 8 + 255) / 256;   // 3125
    const int gm = (NN + 127) / 128;               // 391
    const int ga = (NN * HEADS * 4) / 256;         // 3125 (exact)

    // layer 1
    k_cvt<<<gcv, 256, 0, stream>>>(x, xhi, xlo);
    gemm_mfma<<<dim3(gm, 4), 256, 0, stream>>>(xhi, xlo, wthi, wtlo,
                                               bq0, bk0, bv0, bs0, qb, kb, vb, sbuf, NN);
    attn<<<ga, 256, 0, stream>>>(qb, kb, vb, sbuf, eattr, We0,
                                 row_ptr, csr_se, hbuf, xhi, xlo, 0);  // h1 -> bf16 hi/lo
    // layer 2 (gemm consumes attn1's split output directly)
    gemm_mfma<<<dim3(gm, 4), 256, 0, stream>>>(xhi, xlo, wthi + 4 * 16384, wtlo + 4 * 16384,
                                               bq1, bk1, bv1, bs1, qb, kb, vb, sbuf, NN);
    attn<<<ga, 256, 0, stream>>>(qb, kb, vb, sbuf, eattr, We1,
                                 row_ptr, csr_se, hbuf, (u16*)nullptr, (u16*)nullptr, 1);
    // head
    head_out<<<(NN + 255) / 256, 256, 0, stream>>>(hbuf, Wout, bout, (float*)d_out, NN);
}

// Round 8
// 529.974 us; speedup vs baseline: 2.9721x; 1.0582x over previous
//
#include <hip/hip_runtime.h>

typedef unsigned short u16;
typedef __attribute__((ext_vector_type(4))) u16 u16x4;
typedef __attribute__((ext_vector_type(8))) u16 u16x8;
typedef __attribute__((ext_vector_type(8))) short short8;   // MFMA A/B frag (8 bf16)
typedef __attribute__((ext_vector_type(4))) float f32x4;    // MFMA C/D frag
typedef __attribute__((ext_vector_type(4))) float f4;

#define NN 50000
#define NE 600000
#define HEADS 4
#define DH 32
#define HIDU 128
#define NC 10
#define NBLK 196   // ceil(NN/256)

__device__ __forceinline__ float bf2f(u16 u) {
    union { unsigned int i; float f; } c; c.i = ((unsigned int)u) << 16; return c.f;
}
__device__ __forceinline__ u16 f2bf(float f) {
    union { float f; unsigned int i; } c; c.f = f;
    unsigned int x = c.i;
    return (u16)((x + 0x7fffu + ((x >> 16) & 1u)) >> 16);  // RNE
}

// ---------------- CSR build ----------------
__global__ void k_zero(int* p, int n) {
    int i = blockIdx.x * blockDim.x + threadIdx.x;
    if (i < n) p[i] = 0;
}

__global__ void k_hist(const int* __restrict__ dst, int* __restrict__ deg) {
    int i = blockIdx.x * blockDim.x + threadIdx.x;
    if (i < NE) atomicAdd(&deg[dst[i]], 1);
}

// multi-block scan: A) per-block sums  B) scan of block sums  C) per-element
__global__ __launch_bounds__(256) void scan_a(const int* __restrict__ deg,
                                              int* __restrict__ bsum) {
    __shared__ int red[4];
    int i = blockIdx.x * 256 + threadIdx.x;
    int v = (i < NN) ? deg[i] : 0;
    #pragma unroll
    for (int off = 1; off < 64; off <<= 1) v += __shfl_xor(v, off);
    if ((threadIdx.x & 63) == 0) red[threadIdx.x >> 6] = v;
    __syncthreads();
    if (threadIdx.x == 0) bsum[blockIdx.x] = red[0] + red[1] + red[2] + red[3];
}

__global__ __launch_bounds__(256) void scan_b(const int* __restrict__ bsum,
                                              int* __restrict__ boff,
                                              int* __restrict__ row_ptr) {
    __shared__ int s[256];
    int t = threadIdx.x;
    int v = (t < NBLK) ? bsum[t] : 0;
    s[t] = v;
    __syncthreads();
    for (int off = 1; off < 256; off <<= 1) {
        int x = (t >= off) ? s[t - off] : 0;
        __syncthreads();
        s[t] += x;
        __syncthreads();
    }
    if (t < NBLK) boff[t] = s[t] - v;   // exclusive
    if (t == 0) row_ptr[NN] = NE;       // total degree is statically NE
}

__global__ __launch_bounds__(256) void scan_c(const int* __restrict__ deg,
                                              const int* __restrict__ boff,
                                              int* __restrict__ row_ptr,
                                              int* __restrict__ cursor) {
    __shared__ int s[256];
    int t = threadIdx.x;
    int i = blockIdx.x * 256 + t;
    int v = (i < NN) ? deg[i] : 0;
    s[t] = v;
    __syncthreads();
    for (int off = 1; off < 256; off <<= 1) {
        int x = (t >= off) ? s[t - off] : 0;
        __syncthreads();
        s[t] += x;
        __syncthreads();
    }
    if (i < NN) {
        int r = boff[blockIdx.x] + s[t] - v;
        row_ptr[i] = r;
        cursor[i] = r;
    }
}

__global__ void k_scatter(const int* __restrict__ ei, int* __restrict__ cursor,
                          int2* __restrict__ csr_se) {
    int i = blockIdx.x * blockDim.x + threadIdx.x;
    if (i < NE) {
        int s = ei[i];
        int d = ei[NE + i];
        int pos = atomicAdd(&cursor[d], 1);
        csr_se[pos] = make_int2(s, i);
    }
}

// ---------------- fp32 -> bf16 hi/lo split ----------------
__global__ __launch_bounds__(256) void k_cvt(const float* __restrict__ in,
                                             u16* __restrict__ hi, u16* __restrict__ lo) {
    int i = blockIdx.x * 256 + threadIdx.x;      // one thread per 8 elems
    const f4* p = (const f4*)(in + (size_t)i * 8);
    f4 a = p[0], b = p[1];
    float v[8] = {a[0], a[1], a[2], a[3], b[0], b[1], b[2], b[3]};
    u16x8 h, l;
    #pragma unroll
    for (int j = 0; j < 8; j++) {
        u16 hh = f2bf(v[j]);
        float r = v[j] - bf2f(hh);
        h[j] = hh; l[j] = f2bf(r);
    }
    *(u16x8*)(hi + (size_t)i * 8) = h;
    *(u16x8*)(lo + (size_t)i * 8) = l;
}

// plain fp32 -> bf16 (for edge_attr)
__global__ __launch_bounds__(256) void k_cvt_bf(const float* __restrict__ in,
                                                u16* __restrict__ out, int n8) {
    int i = blockIdx.x * 256 + threadIdx.x;      // one thread per 8 elems
    if (i >= n8) return;
    const f4* p = (const f4*)(in + (size_t)i * 8);
    f4 a = p[0], b = p[1];
    float v[8] = {a[0], a[1], a[2], a[3], b[0], b[1], b[2], b[3]};
    u16x8 o;
    #pragma unroll
    for (int j = 0; j < 8; j++) o[j] = f2bf(v[j]);
    *(u16x8*)(out + (size_t)i * 8) = o;
}

// weights: convert + transpose W[k][n] -> Wt[n][k], hi/lo
__global__ void k_cvtw(const float* w0, const float* w1, const float* w2, const float* w3,
                       const float* w4, const float* w5, const float* w6, const float* w7,
                       u16* __restrict__ hi, u16* __restrict__ lo) {
    const float* w;
    switch (blockIdx.x) {
        case 0: w = w0; break; case 1: w = w1; break;
        case 2: w = w2; break; case 3: w = w3; break;
        case 4: w = w4; break; case 5: w = w5; break;
        case 6: w = w6; break; default: w = w7; break;
    }
    u16* oh = hi + blockIdx.x * 16384;
    u16* ol = lo + blockIdx.x * 16384;
    for (int i = 0; i < 64; i++) {
        int idx = threadIdx.x + i * 256;   // k*128 + n
        int k = idx >> 7, n = idx & 127;
        float v = w[idx];
        u16 h = f2bf(v);
        float r = v - bf2f(h);
        oh[n * 128 + k] = h;
        ol[n * 128 + k] = f2bf(r);
    }
}

// ---------------- MFMA GEMM, bf16x3 split, B staged in LDS (xor-swizzled) ----------------
// grid (391, 4 mats), block 256 = 4 waves x 32 rows (2 rowtiles of 16).
// q (mat 0) and s (mat 3) -> fp32; k (mat 1) and v (mat 2) -> bf16 (attn gather payload).
__global__ __launch_bounds__(256) void gemm_mfma(
    const u16* __restrict__ Xhi, const u16* __restrict__ Xlo,
    const u16* __restrict__ WtHi, const u16* __restrict__ WtLo,   // this layer's 4 mats
    const float* __restrict__ b0, const float* __restrict__ b1,
    const float* __restrict__ b2, const float* __restrict__ b3,
    float* __restrict__ outq, u16* __restrict__ outk, u16* __restrict__ outv,
    float* __restrict__ outs, int nrows)
{
    __shared__ u16 Bs[2 * 128 * 128];   // [level][n*128 + swizzled k]
    const int mat = blockIdx.y;
    const u16* wh = WtHi + mat * 16384;
    const u16* wl = WtLo + mat * 16384;

    #pragma unroll
    for (int i = 0; i < 8; i++) {
        int idx = threadIdx.x + i * 256;        // chunk: row n = idx>>4, granule g = idx&15
        int n = idx >> 4, g = idx & 15;
        int dst = n * 128 + ((g ^ (n & 15)) << 3);
        *(u16x8*)(&Bs[dst])         = *(const u16x8*)(wh + n * 128 + g * 8);
        *(u16x8*)(&Bs[16384 + dst]) = *(const u16x8*)(wl + n * 128 + g * 8);
    }
    __syncthreads();

    const int wave = threadIdx.x >> 6, lane = threadIdx.x & 63;
    const int n0 = lane & 15;              // A row / B col / D col
    const int qw = lane >> 4;
    const int kq = qw * 8;                 // k offset within K32 chunk

    const u16* xh[2]; const u16* xl[2];
    #pragma unroll
    for (int rt = 0; rt < 2; rt++) {
        int arow = blockIdx.x * 128 + wave * 32 + rt * 16 + n0;
        int arow_c = arow < nrows ? arow : nrows - 1;
        xh[rt] = Xhi + (size_t)arow_c * HIDU + kq;
        xl[rt] = Xlo + (size_t)arow_c * HIDU + kq;
    }

    f32x4 acc[2][8];
    #pragma unroll
    for (int rt = 0; rt < 2; rt++)
        #pragma unroll
        for (int nt = 0; nt < 8; nt++) acc[rt][nt] = (f32x4){0.f, 0.f, 0.f, 0.f};

    #pragma unroll
    for (int ks = 0; ks < 4; ks++) {
        short8 ah[2], al[2];
        #pragma unroll
        for (int rt = 0; rt < 2; rt++) {
            ah[rt] = *(const short8*)(xh[rt] + ks * 32);
            al[rt] = *(const short8*)(xl[rt] + ks * 32);
        }
        #pragma unroll
        for (int nt = 0; nt < 8; nt++) {
            const int boff = (nt * 16 + n0) * 128 + (((ks << 2) + qw) ^ n0) * 8;
            short8 bh = *(const short8*)(&Bs[boff]);
            short8 bl = *(const short8*)(&Bs[16384 + boff]);
            #pragma unroll
            for (int rt = 0; rt < 2; rt++) {
                acc[rt][nt] = __builtin_amdgcn_mfma_f32_16x16x32_bf16(ah[rt], bh, acc[rt][nt], 0, 0, 0);
                acc[rt][nt] = __builtin_amdgcn_mfma_f32_16x16x32_bf16(al[rt], bh, acc[rt][nt], 0, 0, 0);
                acc[rt][nt] = __builtin_amdgcn_mfma_f32_16x16x32_bf16(ah[rt], bl, acc[rt][nt], 0, 0, 0);
            }
        }
    }

    const float* bia = (mat == 0) ? b0 : (mat == 1) ? b1 : (mat == 2) ? b2 : b3;
    const bool is16 = (mat == 1) || (mat == 2);
    u16* o16 = (mat == 1) ? outk : outv;
    float* o32 = (mat == 0) ? outq : outs;
    #pragma unroll
    for (int rt = 0; rt < 2; rt++) {
        const int rbase = blockIdx.x * 128 + wave * 32 + rt * 16 + qw * 4;
        #pragma unroll
        for (int nt = 0; nt < 8; nt++) {
            int col = nt * 16 + n0;
            float bv = bia[col];
            #pragma unroll
            for (int r = 0; r < 4; r++) {
                int grow = rbase + r;
                if (grow < nrows) {
                    float v = acc[rt][nt][r] + bv;
                    if (is16) o16[(size_t)grow * HIDU + col] = f2bf(v);
                    else      o32[(size_t)grow * HIDU + col] = v;
                }
            }
        }
    }
}

// ---------------- fused attention: 16 lanes per node (all 4 heads), 2 edges/iter ----------
// lane = (h, sub): owns 8 of its head's 32 k/v channels (= 8 consecutive of the
// 128-ch row -> whole-row coalesced gather) and 4 of 16 e-channels. k/v/eattr
// are bf16 (half gather bytes). Single shfl-xor butterfly (over sub) reduces
// k-dot + e-dot partials. a16 distributed 4/lane, gathered in epilogue.
// Pairwise online softmax; odd tail via logit1=-inf. mode 0: bf16 hi/lo out.
__global__ __launch_bounds__(256) void attn(
    const float* __restrict__ qb, const u16* __restrict__ kb, const u16* __restrict__ vb,
    const float* __restrict__ sb, const u16* __restrict__ ea16, const float* __restrict__ We,
    const int* __restrict__ row_ptr, const int2* __restrict__ csr_se,
    float* __restrict__ hout_f32, u16* __restrict__ hout_hi, u16* __restrict__ hout_lo,
    int mode)
{
    __shared__ float WeS[4 * 513];   // [h][t*32+j]
    #pragma unroll
    for (int i = 0; i < 8; i++) {
        int idx = threadIdx.x + i * 256;   // t*128 + c over 16x128
        int tt = idx >> 7, c = idx & 127;
        int h = c >> 5, j = c & 31;
        WeS[h * 513 + tt * 32 + j] = We[idx];
    }
    __syncthreads();

    int gtid = blockIdx.x * 256 + threadIdx.x;   // grid is exactly NN*16 threads
    int n   = gtid >> 4;         // node
    int l16 = gtid & 15;         // lane in 16-lane cluster
    int h   = l16 >> 2;          // head
    int sub = l16 & 3;
    const int lane = threadIdx.x & 63;
    const float* WeH = &WeS[h * 513];
    const int j0  = sub * 8;     // channel base within head
    const int ch0 = h * DH + j0; // = l16*8, channel base within row
    const int t0  = sub * 4;     // e-channel base

    // full q_h for g4 (preamble only; 4 lanes of same h read same addrs -> broadcast)
    float qreg[8];
    float g4[4];
    {
        const f4* qp = (const f4*)(qb + (size_t)n * HIDU + h * DH);
        float q32[32];
        #pragma unroll
        for (int c = 0; c < 8; c++) {
            f4 x = qp[c];
            #pragma unroll
            for (int j = 0; j < 4; j++) q32[c * 4 + j] = x[j];
        }
        #pragma unroll
        for (int tt = 0; tt < 4; tt++) {
            float a = 0.f;
            #pragma unroll
            for (int j = 0; j < 32; j++) a += q32[j] * WeH[(t0 + tt) * 32 + j];
            g4[tt] = a;
        }
        #pragma unroll
        for (int j = 0; j < 8; j++) qreg[j] = q32[j0 + j];
    }

    float m = -INFINITY, l = 0.f;
    float O[8];
    float a4[4];
    #pragma unroll
    for (int j = 0; j < 8; j++) O[j] = 0.f;
    #pragma unroll
    for (int tt = 0; tt < 4; tt++) a4[tt] = 0.f;

    const int r0 = row_ptr[n], r1 = row_ptr[n + 1];
    const float inv = 0.17677669529663687f;   // 1/sqrt(32)

    for (int e = r0; e < r1; e += 2) {
        bool has2 = (e + 1 < r1);
        int2 se0 = csr_se[e];                  // same addr across cluster -> broadcast
        int2 se1 = csr_se[has2 ? e + 1 : e];

        u16x8 k0 = *(const u16x8*)(kb + (size_t)se0.x * HIDU + ch0);   // 16B coalesced
        u16x8 v0 = *(const u16x8*)(vb + (size_t)se0.x * HIDU + ch0);
        u16x8 k1 = *(const u16x8*)(kb + (size_t)se1.x * HIDU + ch0);
        u16x8 v1 = *(const u16x8*)(vb + (size_t)se1.x * HIDU + ch0);
        u16x4 e0 = *(const u16x4*)(ea16 + (size_t)se0.y * 16 + t0);    // 8B
        u16x4 e1 = *(const u16x4*)(ea16 + (size_t)se1.y * 16 + t0);

        float ea0[4], ea1[4];
        #pragma unroll
        for (int tt = 0; tt < 4; tt++) { ea0[tt] = bf2f(e0[tt]); ea1[tt] = bf2f(e1[tt]); }

        // partial dots (k over own 8 ch + e over own 4 ch), one butterfly for both
        float d0 = 0.f, d1 = 0.f;
        #pragma unroll
        for (int j = 0; j < 8; j++) {
            d0 += qreg[j] * bf2f(k0[j]);
            d1 += qreg[j] * bf2f(k1[j]);
        }
        #pragma unroll
        for (int tt = 0; tt < 4; tt++) {
            d0 += g4[tt] * ea0[tt];
            d1 += g4[tt] * ea1[tt];
        }
        d0 += __shfl_xor(d0, 1);  d1 += __shfl_xor(d1, 1);
        d0 += __shfl_xor(d0, 2);  d1 += __shfl_xor(d1, 2);

        float logit0 = d0 * inv;
        float logit1 = has2 ? d1 * inv : -INFINITY;
        float mn = fmaxf(m, fmaxf(logit0, logit1));
        float corr = __expf(m - mn);        // first iter: exp(-inf)=0
        float w0 = __expf(logit0 - mn);
        float w1 = __expf(logit1 - mn);     // odd tail: exp(-inf)=0
        l = l * corr + w0 + w1;
        #pragma unroll
        for (int j = 0; j < 8; j++)
            O[j] = O[j] * corr + w0 * bf2f(v0[j]) + w1 * bf2f(v1[j]);
        #pragma unroll
        for (int tt = 0; tt < 4; tt++)
            a4[tt] = a4[tt] * corr + w0 * ea0[tt] + w1 * ea1[tt];
        m = mn;
    }

    // gather distributed a16 (from the 4 lanes of this head)
    float af[16];
    #pragma unroll
    for (int t = 0; t < 16; t++)
        af[t] = __shfl(a4[t & 3], (lane & ~3) | (t >> 2));

    float invl = 1.0f / (l + 1e-16f);     // PyG softmax eps; zero-degree -> O=0
    const float* sp = sb + (size_t)n * HIDU + ch0;
    const size_t obase = (size_t)n * HIDU + ch0;

    float vals[8];
    #pragma unroll
    for (int j = 0; j < 8; j++) {
        float ev = 0.f;
        #pragma unroll
        for (int t = 0; t < 16; t++) ev += af[t] * WeH[t * 32 + j0 + j];
        vals[j] = fmaxf((O[j] + ev) * invl + sp[j], 0.f);   // relu(conv_out)
    }
    if (mode == 0) {
        u16x8 hh, ll;
        #pragma unroll
        for (int j = 0; j < 8; j++) {
            u16 hv = f2bf(vals[j]);
            hh[j] = hv;
            ll[j] = f2bf(vals[j] - bf2f(hv));
        }
        *(u16x8*)(hout_hi + obase) = hh;
        *(u16x8*)(hout_lo + obase) = ll;
    } else {
        f4 r0v, r1v;
        #pragma unroll
        for (int j = 0; j < 4; j++) { r0v[j] = vals[j]; r1v[j] = vals[4 + j]; }
        *(f4*)(hout_f32 + obase) = r0v;
        *(f4*)(hout_f32 + obase + 4) = r1v;
    }
}

// ---------------- head: logits + log_softmax ----------------
__global__ __launch_bounds__(256) void head_out(
    const float* __restrict__ hb, const float* __restrict__ Wout, const float* __restrict__ bout,
    float* __restrict__ out, int nnodes)
{
    __shared__ float Ws[HIDU * NC];
    __shared__ float bs[NC];
    for (int i = 0; i < 5; i++) {
        int idx = threadIdx.x + i * 256;
        if (idx < HIDU * NC) Ws[idx] = Wout[idx];
    }
    if (threadIdx.x < NC) bs[threadIdx.x] = bout[threadIdx.x];
    __syncthreads();

    int n = blockIdx.x * 256 + threadIdx.x;
    if (n >= nnodes) return;

    float lg[NC];
    #pragma unroll
    for (int c = 0; c < NC; c++) lg[c] = bs[c];
    const f4* hp = (const f4*)(hb + (size_t)n * HIDU);
    #pragma unroll
    for (int kc = 0; kc < 32; kc++) {
        f4 hv = hp[kc];
        #pragma unroll
        for (int j = 0; j < 4; j++) {
            float h = hv[j];
            int kk = kc * 4 + j;
            #pragma unroll
            for (int c = 0; c < NC; c++) lg[c] += h * Ws[kk * NC + c];
        }
    }
    float mx = lg[0];
    #pragma unroll
    for (int c = 1; c < NC; c++) mx = fmaxf(mx, lg[c]);
    float sum = 0.f;
    #pragma unroll
    for (int c = 0; c < NC; c++) sum += __expf(lg[c] - mx);
    float lse = mx + __logf(sum);
    #pragma unroll
    for (int c = 0; c < NC; c++) out[(size_t)n * NC + c] = lg[c] - lse;
}

// ---------------- launch ----------------
extern "C" void kernel_launch(void* const* d_in, const int* in_sizes, int n_in,
                              void* d_out, int out_size, void* d_ws, size_t ws_size,
                              hipStream_t stream) {
    const float* x     = (const float*)d_in[0];
    const int*   ei    = (const int*)d_in[1];
    const float* eattr = (const float*)d_in[2];
    const float *Wq0 = (const float*)d_in[3],  *bq0 = (const float*)d_in[4];
    const float *Wk0 = (const float*)d_in[5],  *bk0 = (const float*)d_in[6];
    const float *Wv0 = (const float*)d_in[7],  *bv0 = (const float*)d_in[8];
    const float *We0 = (const float*)d_in[9];
    const float *Ws0 = (const float*)d_in[10], *bs0 = (const float*)d_in[11];
    const float *Wq1 = (const float*)d_in[12], *bq1 = (const float*)d_in[13];
    const float *Wk1 = (const float*)d_in[14], *bk1 = (const float*)d_in[15];
    const float *Wv1 = (const float*)d_in[16], *bv1 = (const float*)d_in[17];
    const float *We1 = (const float*)d_in[18];
    const float *Ws1 = (const float*)d_in[19], *bs1 = (const float*)d_in[20];
    const float *Wout = (const float*)d_in[21], *bout = (const float*)d_in[22];

    char* p = (char*)d_ws;
    auto alloc = [&](size_t bytes) -> void* {
        void* r = (void*)p;
        p += (bytes + 255) & ~(size_t)255;
        return r;
    };
    int* deg      = (int*)alloc(NN * 4);
    int* row_ptr  = (int*)alloc((NN + 1) * 4);
    int* cursor   = (int*)alloc(NN * 4);
    int* bsum     = (int*)alloc(NBLK * 4);
    int* boff     = (int*)alloc(NBLK * 4);
    int2* csr_se  = (int2*)alloc((size_t)NE * 8);
    float* qb     = (float*)alloc((size_t)NN * HIDU * 4);
    u16* kb       = (u16*)alloc((size_t)NN * HIDU * 2);
    u16* vb       = (u16*)alloc((size_t)NN * HIDU * 2);
    float* sbuf   = (float*)alloc((size_t)NN * HIDU * 4);
    float* hbuf   = (float*)alloc((size_t)NN * HIDU * 4);
    u16* ea16     = (u16*)alloc((size_t)NE * 16 * 2);
    u16* xhi      = (u16*)alloc((size_t)NN * HIDU * 2);   // layer-1: cvt(x); layer-2: attn1 output
    u16* xlo      = (u16*)alloc((size_t)NN * HIDU * 2);
    u16* wthi     = (u16*)alloc(8 * 16384 * 2);
    u16* wtlo     = (u16*)alloc(8 * 16384 * 2);

    // CSR build (every call: inputs/ws are re-poisoned)
    k_zero<<<(NN + 255) / 256, 256, 0, stream>>>(deg, NN);
    k_hist<<<(NE + 255) / 256, 256, 0, stream>>>(ei + NE, deg);
    scan_a<<<NBLK, 256, 0, stream>>>(deg, bsum);
    scan_b<<<1, 256, 0, stream>>>(bsum, boff, row_ptr);
    scan_c<<<NBLK, 256, 0, stream>>>(deg, boff, row_ptr, cursor);
    k_scatter<<<(NE + 255) / 256, 256, 0, stream>>>(ei, cursor, csr_se);

    // weights -> transposed bf16 hi/lo (mats 0-3: layer 0 q,k,v,s; 4-7: layer 1)
    k_cvtw<<<8, 256, 0, stream>>>(Wq0, Wk0, Wv0, Ws0, Wq1, Wk1, Wv1, Ws1, wthi, wtlo);
    // edge_attr -> bf16 (shared by both attn layers)
    const int ne8 = NE * 16 / 8;                   // 1.2M
    k_cvt_bf<<<(ne8 + 255) / 256, 256, 0, stream>>>(eattr, ea16, ne8);

    const int gcv = (NN * HIDU / 8 + 255) / 256;   // 3125
    const int gm = (NN + 127) / 128;               // 391
    const int ga = (NN * 16) / 256;                // 3125 (exact)

    // layer 1
    k_cvt<<<gcv, 256, 0, stream>>>(x, xhi, xlo);
    gemm_mfma<<<dim3(gm, 4), 256, 0, stream>>>(xhi, xlo, wthi, wtlo,
                                               bq0, bk0, bv0, bs0, qb, kb, vb, sbuf, NN);
    attn<<<ga, 256, 0, stream>>>(qb, kb, vb, sbuf, ea16, We0,
                                 row_ptr, csr_se, hbuf, xhi, xlo, 0);  // h1 -> bf16 hi/lo
    // layer 2 (gemm consumes attn1's split output directly)
    gemm_mfma<<<dim3(gm, 4), 256, 0, stream>>>(xhi, xlo, wthi + 4 * 16384, wtlo + 4 * 16384,
                                               bq1, bk1, bv1, bs1, qb, kb, vb, sbuf, NN);
    attn<<<ga, 256, 0, stream>>>(qb, kb, vb, sbuf, ea16, We1,
                                 row_ptr, csr_se, hbuf, (u16*)nullptr, (u16*)nullptr, 1);
    // head
    head_out<<<(NN + 255) / 256, 256, 0, stream>>>(hbuf, Wout, bout, (float*)d_out, NN);
}

// Round 9
// 489.813 us; speedup vs baseline: 3.2158x; 1.0820x over previous
//
#include <hip/hip_runtime.h>

typedef unsigned short u16;
typedef __attribute__((ext_vector_type(4))) u16 u16x4;
typedef __attribute__((ext_vector_type(8))) u16 u16x8;
typedef __attribute__((ext_vector_type(8))) short short8;   // MFMA A/B frag (8 bf16)
typedef __attribute__((ext_vector_type(4))) float f32x4;    // MFMA C/D frag
typedef __attribute__((ext_vector_type(4))) float f4;

#define NN 50000
#define NE 600000
#define HEADS 4
#define DH 32
#define HIDU 128
#define NC 10
#define NBLK 196   // ceil(NN/256)

__device__ __forceinline__ float bf2f(u16 u) {
    union { unsigned int i; float f; } c; c.i = ((unsigned int)u) << 16; return c.f;
}
__device__ __forceinline__ u16 f2bf(float f) {
    union { float f; unsigned int i; } c; c.f = f;
    unsigned int x = c.i;
    return (u16)((x + 0x7fffu + ((x >> 16) & 1u)) >> 16);  // RNE
}

// ---------------- CSR build ----------------
__global__ void k_zero(int* p, int n) {
    int i = blockIdx.x * blockDim.x + threadIdx.x;
    if (i < n) p[i] = 0;
}

__global__ void k_hist(const int* __restrict__ dst, int* __restrict__ deg) {
    int i = blockIdx.x * blockDim.x + threadIdx.x;
    if (i < NE) atomicAdd(&deg[dst[i]], 1);
}

// multi-block scan: A) per-block sums  B) scan of block sums  C) per-element
__global__ __launch_bounds__(256) void scan_a(const int* __restrict__ deg,
                                              int* __restrict__ bsum) {
    __shared__ int red[4];
    int i = blockIdx.x * 256 + threadIdx.x;
    int v = (i < NN) ? deg[i] : 0;
    #pragma unroll
    for (int off = 1; off < 64; off <<= 1) v += __shfl_xor(v, off);
    if ((threadIdx.x & 63) == 0) red[threadIdx.x >> 6] = v;
    __syncthreads();
    if (threadIdx.x == 0) bsum[blockIdx.x] = red[0] + red[1] + red[2] + red[3];
}

__global__ __launch_bounds__(256) void scan_b(const int* __restrict__ bsum,
                                              int* __restrict__ boff,
                                              int* __restrict__ row_ptr) {
    __shared__ int s[256];
    int t = threadIdx.x;
    int v = (t < NBLK) ? bsum[t] : 0;
    s[t] = v;
    __syncthreads();
    for (int off = 1; off < 256; off <<= 1) {
        int x = (t >= off) ? s[t - off] : 0;
        __syncthreads();
        s[t] += x;
        __syncthreads();
    }
    if (t < NBLK) boff[t] = s[t] - v;   // exclusive
    if (t == 0) row_ptr[NN] = NE;       // total degree is statically NE
}

__global__ __launch_bounds__(256) void scan_c(const int* __restrict__ deg,
                                              const int* __restrict__ boff,
                                              int* __restrict__ row_ptr,
                                              int* __restrict__ cursor) {
    __shared__ int s[256];
    int t = threadIdx.x;
    int i = blockIdx.x * 256 + t;
    int v = (i < NN) ? deg[i] : 0;
    s[t] = v;
    __syncthreads();
    for (int off = 1; off < 256; off <<= 1) {
        int x = (t >= off) ? s[t - off] : 0;
        __syncthreads();
        s[t] += x;
        __syncthreads();
    }
    if (i < NN) {
        int r = boff[blockIdx.x] + s[t] - v;
        row_ptr[i] = r;
        cursor[i] = r;
    }
}

// scatter: build csr_src AND permute edge_attr into CSR order (fp32 -> bf16)
__global__ void k_scatter(const int* __restrict__ ei, const float* __restrict__ eattr,
                          int* __restrict__ cursor,
                          int* __restrict__ csr_src, u16* __restrict__ ea16) {
    int i = blockIdx.x * blockDim.x + threadIdx.x;
    if (i < NE) {
        int s = ei[i];
        int d = ei[NE + i];
        int pos = atomicAdd(&cursor[d], 1);
        csr_src[pos] = s;
        const f4* ep = (const f4*)(eattr + (size_t)i * 16);
        f4 a = ep[0], b = ep[1], c = ep[2], dd = ep[3];
        u16x8 o0, o1;
        #pragma unroll
        for (int j = 0; j < 4; j++) {
            o0[j] = f2bf(a[j]); o0[4 + j] = f2bf(b[j]);
            o1[j] = f2bf(c[j]); o1[4 + j] = f2bf(dd[j]);
        }
        *(u16x8*)(ea16 + (size_t)pos * 16)     = o0;
        *(u16x8*)(ea16 + (size_t)pos * 16 + 8) = o1;
    }
}

// ---------------- fp32 -> bf16 hi/lo split ----------------
__global__ __launch_bounds__(256) void k_cvt(const float* __restrict__ in,
                                             u16* __restrict__ hi, u16* __restrict__ lo) {
    int i = blockIdx.x * 256 + threadIdx.x;      // one thread per 8 elems
    const f4* p = (const f4*)(in + (size_t)i * 8);
    f4 a = p[0], b = p[1];
    float v[8] = {a[0], a[1], a[2], a[3], b[0], b[1], b[2], b[3]};
    u16x8 h, l;
    #pragma unroll
    for (int j = 0; j < 8; j++) {
        u16 hh = f2bf(v[j]);
        float r = v[j] - bf2f(hh);
        h[j] = hh; l[j] = f2bf(r);
    }
    *(u16x8*)(hi + (size_t)i * 8) = h;
    *(u16x8*)(lo + (size_t)i * 8) = l;
}

// weights: convert + transpose W[k][n] -> Wt[n][k], hi/lo
__global__ void k_cvtw(const float* w0, const float* w1, const float* w2, const float* w3,
                       const float* w4, const float* w5, const float* w6, const float* w7,
                       u16* __restrict__ hi, u16* __restrict__ lo) {
    const float* w;
    switch (blockIdx.x) {
        case 0: w = w0; break; case 1: w = w1; break;
        case 2: w = w2; break; case 3: w = w3; break;
        case 4: w = w4; break; case 5: w = w5; break;
        case 6: w = w6; break; default: w = w7; break;
    }
    u16* oh = hi + blockIdx.x * 16384;
    u16* ol = lo + blockIdx.x * 16384;
    for (int i = 0; i < 64; i++) {
        int idx = threadIdx.x + i * 256;   // k*128 + n
        int k = idx >> 7, n = idx & 127;
        float v = w[idx];
        u16 h = f2bf(v);
        float r = v - bf2f(h);
        oh[n * 128 + k] = h;
        ol[n * 128 + k] = f2bf(r);
    }
}

// ---------------- q/k/v GEMM: plain bf16 MFMA (1 pass), B-hi staged in LDS ----------------
// grid (391, 3 mats), block 256 = 4 waves x 32 rows. Error ~2^-9 relative: safe.
__global__ __launch_bounds__(256) void gemm_qkv(
    const u16* __restrict__ Xhi, const u16* __restrict__ WtHi,
    const float* __restrict__ b0, const float* __restrict__ b1,
    const float* __restrict__ b2,
    float* __restrict__ outq, u16* __restrict__ outk, u16* __restrict__ outv,
    int nrows)
{
    __shared__ u16 Bs[128 * 128];   // 32 KB, [n*128 + swizzled k]
    const int mat = blockIdx.y;     // 0=q 1=k 2=v
    const u16* wh = WtHi + mat * 16384;

    #pragma unroll
    for (int i = 0; i < 8; i++) {
        int idx = threadIdx.x + i * 256;        // chunk: row n = idx>>4, granule g = idx&15
        int n = idx >> 4, g = idx & 15;
        Bs[0] = Bs[0];  // no-op
        *(u16x8*)(&Bs[n * 128 + ((g ^ (n & 15)) << 3)]) = *(const u16x8*)(wh + n * 128 + g * 8);
    }
    __syncthreads();

    const int wave = threadIdx.x >> 6, lane = threadIdx.x & 63;
    const int n0 = lane & 15;
    const int qw = lane >> 4;
    const int kq = qw * 8;

    const u16* xh[2];
    #pragma unroll
    for (int rt = 0; rt < 2; rt++) {
        int arow = blockIdx.x * 128 + wave * 32 + rt * 16 + n0;
        int arow_c = arow < nrows ? arow : nrows - 1;
        xh[rt] = Xhi + (size_t)arow_c * HIDU + kq;
    }

    f32x4 acc[2][8];
    #pragma unroll
    for (int rt = 0; rt < 2; rt++)
        #pragma unroll
        for (int nt = 0; nt < 8; nt++) acc[rt][nt] = (f32x4){0.f, 0.f, 0.f, 0.f};

    #pragma unroll
    for (int ks = 0; ks < 4; ks++) {
        short8 ah[2];
        #pragma unroll
        for (int rt = 0; rt < 2; rt++) ah[rt] = *(const short8*)(xh[rt] + ks * 32);
        #pragma unroll
        for (int nt = 0; nt < 8; nt++) {
            const int boff = (nt * 16 + n0) * 128 + (((ks << 2) + qw) ^ n0) * 8;
            short8 bh = *(const short8*)(&Bs[boff]);
            #pragma unroll
            for (int rt = 0; rt < 2; rt++)
                acc[rt][nt] = __builtin_amdgcn_mfma_f32_16x16x32_bf16(ah[rt], bh, acc[rt][nt], 0, 0, 0);
        }
    }

    const float* bia = (mat == 0) ? b0 : (mat == 1) ? b1 : b2;
    #pragma unroll
    for (int rt = 0; rt < 2; rt++) {
        const int rbase = blockIdx.x * 128 + wave * 32 + rt * 16 + qw * 4;
        #pragma unroll
        for (int nt = 0; nt < 8; nt++) {
            int col = nt * 16 + n0;
            float bv = bia[col];
            #pragma unroll
            for (int r = 0; r < 4; r++) {
                int grow = rbase + r;
                if (grow < nrows) {
                    float v = acc[rt][nt][r] + bv;
                    if (mat == 0)      outq[(size_t)grow * HIDU + col] = v;
                    else if (mat == 1) outk[(size_t)grow * HIDU + col] = f2bf(v);
                    else               outv[(size_t)grow * HIDU + col] = f2bf(v);
                }
            }
        }
    }
}

// ---------------- s GEMM: bf16x3 split (residual path needs fp32 accuracy) ----------------
__global__ __launch_bounds__(256) void gemm_s(
    const u16* __restrict__ Xhi, const u16* __restrict__ Xlo,
    const u16* __restrict__ wh, const u16* __restrict__ wl,
    const float* __restrict__ bia, float* __restrict__ outs, int nrows)
{
    __shared__ u16 Bs[2 * 128 * 128];   // 64 KB

    #pragma unroll
    for (int i = 0; i < 8; i++) {
        int idx = threadIdx.x + i * 256;
        int n = idx >> 4, g = idx & 15;
        int dst = n * 128 + ((g ^ (n & 15)) << 3);
        *(u16x8*)(&Bs[dst])         = *(const u16x8*)(wh + n * 128 + g * 8);
        *(u16x8*)(&Bs[16384 + dst]) = *(const u16x8*)(wl + n * 128 + g * 8);
    }
    __syncthreads();

    const int wave = threadIdx.x >> 6, lane = threadIdx.x & 63;
    const int n0 = lane & 15;
    const int qw = lane >> 4;
    const int kq = qw * 8;

    const u16* xh[2]; const u16* xl[2];
    #pragma unroll
    for (int rt = 0; rt < 2; rt++) {
        int arow = blockIdx.x * 128 + wave * 32 + rt * 16 + n0;
        int arow_c = arow < nrows ? arow : nrows - 1;
        xh[rt] = Xhi + (size_t)arow_c * HIDU + kq;
        xl[rt] = Xlo + (size_t)arow_c * HIDU + kq;
    }

    f32x4 acc[2][8];
    #pragma unroll
    for (int rt = 0; rt < 2; rt++)
        #pragma unroll
        for (int nt = 0; nt < 8; nt++) acc[rt][nt] = (f32x4){0.f, 0.f, 0.f, 0.f};

    #pragma unroll
    for (int ks = 0; ks < 4; ks++) {
        short8 ah[2], al[2];
        #pragma unroll
        for (int rt = 0; rt < 2; rt++) {
            ah[rt] = *(const short8*)(xh[rt] + ks * 32);
            al[rt] = *(const short8*)(xl[rt] + ks * 32);
        }
        #pragma unroll
        for (int nt = 0; nt < 8; nt++) {
            const int boff = (nt * 16 + n0) * 128 + (((ks << 2) + qw) ^ n0) * 8;
            short8 bh = *(const short8*)(&Bs[boff]);
            short8 bl = *(const short8*)(&Bs[16384 + boff]);
            #pragma unroll
            for (int rt = 0; rt < 2; rt++) {
                acc[rt][nt] = __builtin_amdgcn_mfma_f32_16x16x32_bf16(ah[rt], bh, acc[rt][nt], 0, 0, 0);
                acc[rt][nt] = __builtin_amdgcn_mfma_f32_16x16x32_bf16(al[rt], bh, acc[rt][nt], 0, 0, 0);
                acc[rt][nt] = __builtin_amdgcn_mfma_f32_16x16x32_bf16(ah[rt], bl, acc[rt][nt], 0, 0, 0);
            }
        }
    }

    #pragma unroll
    for (int rt = 0; rt < 2; rt++) {
        const int rbase = blockIdx.x * 128 + wave * 32 + rt * 16 + qw * 4;
        #pragma unroll
        for (int nt = 0; nt < 8; nt++) {
            int col = nt * 16 + n0;
            float bv = bia[col];
            #pragma unroll
            for (int r = 0; r < 4; r++) {
                int grow = rbase + r;
                if (grow < nrows) outs[(size_t)grow * HIDU + col] = acc[rt][nt][r] + bv;
            }
        }
    }
}

// ---------------- fused attention: 16 lanes per node (all 4 heads), 2 edges/iter ----------
// lane = (h, sub): owns 8 of its head's 32 k/v channels and 4 of 16 e-channels.
// k/v bf16; edge_attr pre-permuted to CSR order (sequential reads, bf16).
// Single shfl-xor butterfly (over sub) reduces k-dot + e-dot partials.
// Pairwise online softmax; odd tail via logit1=-inf. mode 0: bf16 hi/lo out.
__global__ __launch_bounds__(256) void attn(
    const float* __restrict__ qb, const u16* __restrict__ kb, const u16* __restrict__ vb,
    const float* __restrict__ sb, const u16* __restrict__ ea16, const float* __restrict__ We,
    const int* __restrict__ row_ptr, const int* __restrict__ csr_src,
    float* __restrict__ hout_f32, u16* __restrict__ hout_hi, u16* __restrict__ hout_lo,
    int mode)
{
    __shared__ float WeS[4 * 513];   // [h][t*32+j]
    #pragma unroll
    for (int i = 0; i < 8; i++) {
        int idx = threadIdx.x + i * 256;   // t*128 + c over 16x128
        int tt = idx >> 7, c = idx & 127;
        int h = c >> 5, j = c & 31;
        WeS[h * 513 + tt * 32 + j] = We[idx];
    }
    __syncthreads();

    int gtid = blockIdx.x * 256 + threadIdx.x;   // grid is exactly NN*16 threads
    int n   = gtid >> 4;         // node
    int l16 = gtid & 15;         // lane in 16-lane cluster
    int h   = l16 >> 2;          // head
    int sub = l16 & 3;
    const int lane = threadIdx.x & 63;
    const float* WeH = &WeS[h * 513];
    const int j0  = sub * 8;     // channel base within head
    const int ch0 = h * DH + j0; // = l16*8, channel base within row
    const int t0  = sub * 4;     // e-channel base

    // full q_h for g4 (preamble only; 4 lanes of same h read same addrs -> broadcast)
    float qreg[8];
    float g4[4];
    {
        const f4* qp = (const f4*)(qb + (size_t)n * HIDU + h * DH);
        float q32[32];
        #pragma unroll
        for (int c = 0; c < 8; c++) {
            f4 x = qp[c];
            #pragma unroll
            for (int j = 0; j < 4; j++) q32[c * 4 + j] = x[j];
        }
        #pragma unroll
        for (int tt = 0; tt < 4; tt++) {
            float a = 0.f;
            #pragma unroll
            for (int j = 0; j < 32; j++) a += q32[j] * WeH[(t0 + tt) * 32 + j];
            g4[tt] = a;
        }
        #pragma unroll
        for (int j = 0; j < 8; j++) qreg[j] = q32[j0 + j];
    }

    float m = -INFINITY, l = 0.f;
    float O[8];
    float a4[4];
    #pragma unroll
    for (int j = 0; j < 8; j++) O[j] = 0.f;
    #pragma unroll
    for (int tt = 0; tt < 4; tt++) a4[tt] = 0.f;

    const int r0 = row_ptr[n], r1 = row_ptr[n + 1];
    const float inv = 0.17677669529663687f;   // 1/sqrt(32)

    for (int e = r0; e < r1; e += 2) {
        bool has2 = (e + 1 < r1);
        int e1i = has2 ? e + 1 : e;
        int s0 = csr_src[e];                   // broadcast across cluster
        int s1 = csr_src[e1i];
        // ea: sequential in e (pre-permuted) -- no dependent gather
        u16x4 e0 = *(const u16x4*)(ea16 + (size_t)e * 16 + t0);
        u16x4 e1 = *(const u16x4*)(ea16 + (size_t)e1i * 16 + t0);

        u16x8 k0 = *(const u16x8*)(kb + (size_t)s0 * HIDU + ch0);   // 16B coalesced
        u16x8 v0 = *(const u16x8*)(vb + (size_t)s0 * HIDU + ch0);
        u16x8 k1 = *(const u16x8*)(kb + (size_t)s1 * HIDU + ch0);
        u16x8 v1 = *(const u16x8*)(vb + (size_t)s1 * HIDU + ch0);

        float ea0[4], ea1[4];
        #pragma unroll
        for (int tt = 0; tt < 4; tt++) { ea0[tt] = bf2f(e0[tt]); ea1[tt] = bf2f(e1[tt]); }

        // partial dots (k over own 8 ch + e over own 4 ch), one butterfly for both
        float d0 = 0.f, d1 = 0.f;
        #pragma unroll
        for (int j = 0; j < 8; j++) {
            d0 += qreg[j] * bf2f(k0[j]);
            d1 += qreg[j] * bf2f(k1[j]);
        }
        #pragma unroll
        for (int tt = 0; tt < 4; tt++) {
            d0 += g4[tt] * ea0[tt];
            d1 += g4[tt] * ea1[tt];
        }
        d0 += __shfl_xor(d0, 1);  d1 += __shfl_xor(d1, 1);
        d0 += __shfl_xor(d0, 2);  d1 += __shfl_xor(d1, 2);

        float logit0 = d0 * inv;
        float logit1 = has2 ? d1 * inv : -INFINITY;
        float mn = fmaxf(m, fmaxf(logit0, logit1));
        float corr = __expf(m - mn);        // first iter: exp(-inf)=0
        float w0 = __expf(logit0 - mn);
        float w1 = __expf(logit1 - mn);     // odd tail: exp(-inf)=0
        l = l * corr + w0 + w1;
        #pragma unroll
        for (int j = 0; j < 8; j++)
            O[j] = O[j] * corr + w0 * bf2f(v0[j]) + w1 * bf2f(v1[j]);
        #pragma unroll
        for (int tt = 0; tt < 4; tt++)
            a4[tt] = a4[tt] * corr + w0 * ea0[tt] + w1 * ea1[tt];
        m = mn;
    }

    // gather distributed a16 (from the 4 lanes of this head)
    float af[16];
    #pragma unroll
    for (int t = 0; t < 16; t++)
        af[t] = __shfl(a4[t & 3], (lane & ~3) | (t >> 2));

    float invl = 1.0f / (l + 1e-16f);     // PyG softmax eps; zero-degree -> O=0
    const float* sp = sb + (size_t)n * HIDU + ch0;
    const size_t obase = (size_t)n * HIDU + ch0;

    float vals[8];
    #pragma unroll
    for (int j = 0; j < 8; j++) {
        float ev = 0.f;
        #pragma unroll
        for (int t = 0; t < 16; t++) ev += af[t] * WeH[t * 32 + j0 + j];
        vals[j] = fmaxf((O[j] + ev) * invl + sp[j], 0.f);   // relu(conv_out)
    }
    if (mode == 0) {
        u16x8 hh, ll;
        #pragma unroll
        for (int j = 0; j < 8; j++) {
            u16 hv = f2bf(vals[j]);
            hh[j] = hv;
            ll[j] = f2bf(vals[j] - bf2f(hv));
        }
        *(u16x8*)(hout_hi + obase) = hh;
        *(u16x8*)(hout_lo + obase) = ll;
    } else {
        f4 r0v, r1v;
        #pragma unroll
        for (int j = 0; j < 4; j++) { r0v[j] = vals[j]; r1v[j] = vals[4 + j]; }
        *(f4*)(hout_f32 + obase) = r0v;
        *(f4*)(hout_f32 + obase + 4) = r1v;
    }
}

// ---------------- head: logits + log_softmax ----------------
__global__ __launch_bounds__(256) void head_out(
    const float* __restrict__ hb, const float* __restrict__ Wout, const float* __restrict__ bout,
    float* __restrict__ out, int nnodes)
{
    __shared__ float Ws[HIDU * NC];
    __shared__ float bs[NC];
    for (int i = 0; i < 5; i++) {
        int idx = threadIdx.x + i * 256;
        if (idx < HIDU * NC) Ws[idx] = Wout[idx];
    }
    if (threadIdx.x < NC) bs[threadIdx.x] = bout[threadIdx.x];
    __syncthreads();

    int n = blockIdx.x * 256 + threadIdx.x;
    if (n >= nnodes) return;

    float lg[NC];
    #pragma unroll
    for (int c = 0; c < NC; c++) lg[c] = bs[c];
    const f4* hp = (const f4*)(hb + (size_t)n * HIDU);
    #pragma unroll
    for (int kc = 0; kc < 32; kc++) {
        f4 hv = hp[kc];
        #pragma unroll
        for (int j = 0; j < 4; j++) {
            float h = hv[j];
            int kk = kc * 4 + j;
            #pragma unroll
            for (int c = 0; c < NC; c++) lg[c] += h * Ws[kk * NC + c];
        }
    }
    float mx = lg[0];
    #pragma unroll
    for (int c = 1; c < NC; c++) mx = fmaxf(mx, lg[c]);
    float sum = 0.f;
    #pragma unroll
    for (int c = 0; c < NC; c++) sum += __expf(lg[c] - mx);
    float lse = mx + __logf(sum);
    #pragma unroll
    for (int c = 0; c < NC; c++) out[(size_t)n * NC + c] = lg[c] - lse;
}

// ---------------- launch ----------------
extern "C" void kernel_launch(void* const* d_in, const int* in_sizes, int n_in,
                              void* d_out, int out_size, void* d_ws, size_t ws_size,
                              hipStream_t stream) {
    const float* x     = (const float*)d_in[0];
    const int*   ei    = (const int*)d_in[1];
    const float* eattr = (const float*)d_in[2];
    const float *Wq0 = (const float*)d_in[3],  *bq0 = (const float*)d_in[4];
    const float *Wk0 = (const float*)d_in[5],  *bk0 = (const float*)d_in[6];
    const float *Wv0 = (const float*)d_in[7],  *bv0 = (const float*)d_in[8];
    const float *We0 = (const float*)d_in[9];
    const float *Ws0 = (const float*)d_in[10], *bs0 = (const float*)d_in[11];
    const float *Wq1 = (const float*)d_in[12], *bq1 = (const float*)d_in[13];
    const float *Wk1 = (const float*)d_in[14], *bk1 = (const float*)d_in[15];
    const float *Wv1 = (const float*)d_in[16], *bv1 = (const float*)d_in[17];
    const float *We1 = (const float*)d_in[18];
    const float *Ws1 = (const float*)d_in[19], *bs1 = (const float*)d_in[20];
    const float *Wout = (const float*)d_in[21], *bout = (const float*)d_in[22];

    char* p = (char*)d_ws;
    auto alloc = [&](size_t bytes) -> void* {
        void* r = (void*)p;
        p += (bytes + 255) & ~(size_t)255;
        return r;
    };
    int* deg      = (int*)alloc(NN * 4);
    int* row_ptr  = (int*)alloc((NN + 1) * 4);
    int* cursor   = (int*)alloc(NN * 4);
    int* bsum     = (int*)alloc(NBLK * 4);
    int* boff     = (int*)alloc(NBLK * 4);
    int* csr_src  = (int*)alloc((size_t)NE * 4);
    float* qb     = (float*)alloc((size_t)NN * HIDU * 4);
    u16* kb       = (u16*)alloc((size_t)NN * HIDU * 2);
    u16* vb       = (u16*)alloc((size_t)NN * HIDU * 2);
    float* sbuf   = (float*)alloc((size_t)NN * HIDU * 4);
    float* hbuf   = (float*)alloc((size_t)NN * HIDU * 4);
    u16* ea16     = (u16*)alloc((size_t)NE * 16 * 2);     // CSR-ordered bf16 edge_attr
    u16* xhi      = (u16*)alloc((size_t)NN * HIDU * 2);   // layer-1: cvt(x); layer-2: attn1 output
    u16* xlo      = (u16*)alloc((size_t)NN * HIDU * 2);
    u16* wthi     = (u16*)alloc(8 * 16384 * 2);
    u16* wtlo     = (u16*)alloc(8 * 16384 * 2);

    // CSR build (every call: inputs/ws are re-poisoned)
    k_zero<<<(NN + 255) / 256, 256, 0, stream>>>(deg, NN);
    k_hist<<<(NE + 255) / 256, 256, 0, stream>>>(ei + NE, deg);
    scan_a<<<NBLK, 256, 0, stream>>>(deg, bsum);
    scan_b<<<1, 256, 0, stream>>>(bsum, boff, row_ptr);
    scan_c<<<NBLK, 256, 0, stream>>>(deg, boff, row_ptr, cursor);
    k_scatter<<<(NE + 255) / 256, 256, 0, stream>>>(ei, eattr, cursor, csr_src, ea16);

    // weights -> transposed bf16 hi/lo (mats 0-3: layer 0 q,k,v,s; 4-7: layer 1)
    k_cvtw<<<8, 256, 0, stream>>>(Wq0, Wk0, Wv0, Ws0, Wq1, Wk1, Wv1, Ws1, wthi, wtlo);

    const int gcv = (NN * HIDU / 8 + 255) / 256;   // 3125
    const int gm = (NN + 127) / 128;               // 391
    const int ga = (NN * 16) / 256;                // 3125 (exact)

    // layer 1
    k_cvt<<<gcv, 256, 0, stream>>>(x, xhi, xlo);
    gemm_qkv<<<dim3(gm, 3), 256, 0, stream>>>(xhi, wthi, bq0, bk0, bv0, qb, kb, vb, NN);
    gemm_s<<<gm, 256, 0, stream>>>(xhi, xlo, wthi + 3 * 16384, wtlo + 3 * 16384, bs0, sbuf, NN);
    attn<<<ga, 256, 0, stream>>>(qb, kb, vb, sbuf, ea16, We0,
                                 row_ptr, csr_src, hbuf, xhi, xlo, 0);  // h1 -> bf16 hi/lo
    // layer 2 (gemm consumes attn1's split output directly)
    gemm_qkv<<<dim3(gm, 3), 256, 0, stream>>>(xhi, wthi + 4 * 16384, bq1, bk1, bv1, qb, kb, vb, NN);
    gemm_s<<<gm, 256, 0, stream>>>(xhi, xlo, wthi + 7 * 16384, wtlo + 7 * 16384, bs1, sbuf, NN);
    attn<<<ga, 256, 0, stream>>>(qb, kb, vb, sbuf, ea16, We1,
                                 row_ptr, csr_src, hbuf, (u16*)nullptr, (u16*)nullptr, 1);
    // head
    head_out<<<(NN + 255) / 256, 256, 0, stream>>>(hbuf, Wout, bout, (float*)d_out, NN);
}

// Round 10
// 469.175 us; speedup vs baseline: 3.3573x; 1.0440x over previous
//
#include <hip/hip_runtime.h>

typedef unsigned short u16;
typedef __attribute__((ext_vector_type(4))) u16 u16x4;
typedef __attribute__((ext_vector_type(8))) u16 u16x8;
typedef __attribute__((ext_vector_type(8))) short short8;   // MFMA A/B frag (8 bf16)
typedef __attribute__((ext_vector_type(4))) float f32x4;    // MFMA C/D frag
typedef __attribute__((ext_vector_type(4))) float f4;

#define NN 50000
#define NE 600000
#define HEADS 4
#define DH 32
#define HIDU 128
#define NC 10
#define NBLK 196   // ceil(NN/256)

__device__ __forceinline__ float bf2f(u16 u) {
    union { unsigned int i; float f; } c; c.i = ((unsigned int)u) << 16; return c.f;
}
__device__ __forceinline__ u16 f2bf(float f) {
    union { float f; unsigned int i; } c; c.f = f;
    unsigned int x = c.i;
    return (u16)((x + 0x7fffu + ((x >> 16) & 1u)) >> 16);  // RNE
}
// quad butterflies via DPP (VALU-only; replaces ds_swizzle shuffles)
__device__ __forceinline__ float qadd_xor1(float v) {
    int o = __builtin_amdgcn_update_dpp(0, __float_as_int(v), 0xB1, 0xF, 0xF, true);
    return v + __int_as_float(o);
}
__device__ __forceinline__ float qadd_xor2(float v) {
    int o = __builtin_amdgcn_update_dpp(0, __float_as_int(v), 0x4E, 0xF, 0xF, true);
    return v + __int_as_float(o);
}

// ---------------- CSR build ----------------
__global__ void k_zero(int* p, int n) {
    int i = blockIdx.x * blockDim.x + threadIdx.x;
    if (i < n) p[i] = 0;
}

__global__ void k_hist(const int* __restrict__ dst, int* __restrict__ deg) {
    int i = blockIdx.x * blockDim.x + threadIdx.x;
    if (i < NE) atomicAdd(&deg[dst[i]], 1);
}

__global__ __launch_bounds__(256) void scan_a(const int* __restrict__ deg,
                                              int* __restrict__ bsum) {
    __shared__ int red[4];
    int i = blockIdx.x * 256 + threadIdx.x;
    int v = (i < NN) ? deg[i] : 0;
    #pragma unroll
    for (int off = 1; off < 64; off <<= 1) v += __shfl_xor(v, off);
    if ((threadIdx.x & 63) == 0) red[threadIdx.x >> 6] = v;
    __syncthreads();
    if (threadIdx.x == 0) bsum[blockIdx.x] = red[0] + red[1] + red[2] + red[3];
}

__global__ __launch_bounds__(256) void scan_b(const int* __restrict__ bsum,
                                              int* __restrict__ boff,
                                              int* __restrict__ row_ptr) {
    __shared__ int s[256];
    int t = threadIdx.x;
    int v = (t < NBLK) ? bsum[t] : 0;
    s[t] = v;
    __syncthreads();
    for (int off = 1; off < 256; off <<= 1) {
        int x = (t >= off) ? s[t - off] : 0;
        __syncthreads();
        s[t] += x;
        __syncthreads();
    }
    if (t < NBLK) boff[t] = s[t] - v;   // exclusive
    if (t == 0) row_ptr[NN] = NE;
}

__global__ __launch_bounds__(256) void scan_c(const int* __restrict__ deg,
                                              const int* __restrict__ boff,
                                              int* __restrict__ row_ptr,
                                              int* __restrict__ cursor) {
    __shared__ int s[256];
    int t = threadIdx.x;
    int i = blockIdx.x * 256 + t;
    int v = (i < NN) ? deg[i] : 0;
    s[t] = v;
    __syncthreads();
    for (int off = 1; off < 256; off <<= 1) {
        int x = (t >= off) ? s[t - off] : 0;
        __syncthreads();
        s[t] += x;
        __syncthreads();
    }
    if (i < NN) {
        int r = boff[blockIdx.x] + s[t] - v;
        row_ptr[i] = r;
        cursor[i] = r;
    }
}

// scatter: build csr_src AND permute edge_attr into CSR order (fp32 -> bf16)
__global__ void k_scatter(const int* __restrict__ ei, const float* __restrict__ eattr,
                          int* __restrict__ cursor,
                          int* __restrict__ csr_src, u16* __restrict__ ea16) {
    int i = blockIdx.x * blockDim.x + threadIdx.x;
    if (i < NE) {
        int s = ei[i];
        int d = ei[NE + i];
        int pos = atomicAdd(&cursor[d], 1);
        csr_src[pos] = s;
        const f4* ep = (const f4*)(eattr + (size_t)i * 16);
        f4 a = ep[0], b = ep[1], c = ep[2], dd = ep[3];
        u16x8 o0, o1;
        #pragma unroll
        for (int j = 0; j < 4; j++) {
            o0[j] = f2bf(a[j]); o0[4 + j] = f2bf(b[j]);
            o1[j] = f2bf(c[j]); o1[4 + j] = f2bf(dd[j]);
        }
        *(u16x8*)(ea16 + (size_t)pos * 16)     = o0;
        *(u16x8*)(ea16 + (size_t)pos * 16 + 8) = o1;
    }
}

// weights: convert + transpose W[k][n] -> Wt[n][k], hi/lo
__global__ void k_cvtw(const float* w0, const float* w1, const float* w2, const float* w3,
                       const float* w4, const float* w5, const float* w6, const float* w7,
                       u16* __restrict__ hi, u16* __restrict__ lo) {
    const float* w;
    switch (blockIdx.x) {
        case 0: w = w0; break; case 1: w = w1; break;
        case 2: w = w2; break; case 3: w = w3; break;
        case 4: w = w4; break; case 5: w = w5; break;
        case 6: w = w6; break; default: w = w7; break;
    }
    u16* oh = hi + blockIdx.x * 16384;
    u16* ol = lo + blockIdx.x * 16384;
    for (int i = 0; i < 64; i++) {
        int idx = threadIdx.x + i * 256;   // k*128 + n
        int k = idx >> 7, n = idx & 127;
        float v = w[idx];
        u16 h = f2bf(v);
        float r = v - bf2f(h);
        oh[n * 128 + k] = h;
        ol[n * 128 + k] = f2bf(r);
    }
}

// ---------------- q/k/v GEMM: bf16 MFMA, fp32 X (in-register truncation) ----------------
__global__ __launch_bounds__(256) void gemm_qkv(
    const float* __restrict__ X, const u16* __restrict__ WtHi,
    const float* __restrict__ b0, const float* __restrict__ b1,
    const float* __restrict__ b2,
    float* __restrict__ outq, u16* __restrict__ outk, u16* __restrict__ outv,
    int nrows)
{
    __shared__ u16 Bs[128 * 128];   // 32 KB
    const int mat = blockIdx.y;     // 0=q 1=k 2=v
    const u16* wh = WtHi + mat * 16384;

    #pragma unroll
    for (int i = 0; i < 8; i++) {
        int idx = threadIdx.x + i * 256;
        int n = idx >> 4, g = idx & 15;
        *(u16x8*)(&Bs[n * 128 + ((g ^ (n & 15)) << 3)]) = *(const u16x8*)(wh + n * 128 + g * 8);
    }
    __syncthreads();

    const int wave = threadIdx.x >> 6, lane = threadIdx.x & 63;
    const int n0 = lane & 15;
    const int qw = lane >> 4;
    const int kq = qw * 8;

    const float* xp[2];
    #pragma unroll
    for (int rt = 0; rt < 2; rt++) {
        int arow = blockIdx.x * 128 + wave * 32 + rt * 16 + n0;
        int arow_c = arow < nrows ? arow : nrows - 1;
        xp[rt] = X + (size_t)arow_c * HIDU + kq;
    }

    f32x4 acc[2][8];
    #pragma unroll
    for (int rt = 0; rt < 2; rt++)
        #pragma unroll
        for (int nt = 0; nt < 8; nt++) acc[rt][nt] = (f32x4){0.f, 0.f, 0.f, 0.f};

    #pragma unroll
    for (int ks = 0; ks < 4; ks++) {
        short8 ah[2];
        #pragma unroll
        for (int rt = 0; rt < 2; rt++) {
            f4 a0 = *(const f4*)(xp[rt] + ks * 32);
            f4 a1 = *(const f4*)(xp[rt] + ks * 32 + 4);
            #pragma unroll
            for (int j = 0; j < 4; j++) {
                ah[rt][j]     = (short)(__float_as_uint(a0[j]) >> 16);
                ah[rt][4 + j] = (short)(__float_as_uint(a1[j]) >> 16);
            }
        }
        #pragma unroll
        for (int nt = 0; nt < 8; nt++) {
            const int boff = (nt * 16 + n0) * 128 + (((ks << 2) + qw) ^ n0) * 8;
            short8 bh = *(const short8*)(&Bs[boff]);
            #pragma unroll
            for (int rt = 0; rt < 2; rt++)
                acc[rt][nt] = __builtin_amdgcn_mfma_f32_16x16x32_bf16(ah[rt], bh, acc[rt][nt], 0, 0, 0);
        }
    }

    const float* bia = (mat == 0) ? b0 : (mat == 1) ? b1 : b2;
    #pragma unroll
    for (int rt = 0; rt < 2; rt++) {
        const int rbase = blockIdx.x * 128 + wave * 32 + rt * 16 + qw * 4;
        #pragma unroll
        for (int nt = 0; nt < 8; nt++) {
            int col = nt * 16 + n0;
            float bv = bia[col];
            #pragma unroll
            for (int r = 0; r < 4; r++) {
                int grow = rbase + r;
                if (grow < nrows) {
                    float v = acc[rt][nt][r] + bv;
                    if (mat == 0)      outq[(size_t)grow * HIDU + col] = v;
                    else if (mat == 1) outk[(size_t)grow * HIDU + col] = f2bf(v);
                    else               outv[(size_t)grow * HIDU + col] = f2bf(v);
                }
            }
        }
    }
}

// ---------------- s GEMM: bf16x3 split, fp32 X (in-register truncation split) --------------
__global__ __launch_bounds__(256) void gemm_s(
    const float* __restrict__ X,
    const u16* __restrict__ wh, const u16* __restrict__ wl,
    const float* __restrict__ bia, float* __restrict__ outs, int nrows)
{
    __shared__ u16 Bs[2 * 128 * 128];   // 64 KB

    #pragma unroll
    for (int i = 0; i < 8; i++) {
        int idx = threadIdx.x + i * 256;
        int n = idx >> 4, g = idx & 15;
        int dst = n * 128 + ((g ^ (n & 15)) << 3);
        *(u16x8*)(&Bs[dst])         = *(const u16x8*)(wh + n * 128 + g * 8);
        *(u16x8*)(&Bs[16384 + dst]) = *(const u16x8*)(wl + n * 128 + g * 8);
    }
    __syncthreads();

    const int wave = threadIdx.x >> 6, lane = threadIdx.x & 63;
    const int n0 = lane & 15;
    const int qw = lane >> 4;
    const int kq = qw * 8;

    const float* xp[2];
    #pragma unroll
    for (int rt = 0; rt < 2; rt++) {
        int arow = blockIdx.x * 128 + wave * 32 + rt * 16 + n0;
        int arow_c = arow < nrows ? arow : nrows - 1;
        xp[rt] = X + (size_t)arow_c * HIDU + kq;
    }

    f32x4 acc[2][8];
    #pragma unroll
    for (int rt = 0; rt < 2; rt++)
        #pragma unroll
        for (int nt = 0; nt < 8; nt++) acc[rt][nt] = (f32x4){0.f, 0.f, 0.f, 0.f};

    #pragma unroll
    for (int ks = 0; ks < 4; ks++) {
        short8 ah[2], al[2];
        #pragma unroll
        for (int rt = 0; rt < 2; rt++) {
            f4 a0 = *(const f4*)(xp[rt] + ks * 32);
            f4 a1 = *(const f4*)(xp[rt] + ks * 32 + 4);
            #pragma unroll
            for (int j = 0; j < 4; j++) {
                unsigned u0 = __float_as_uint(a0[j]);
                unsigned u1 = __float_as_uint(a1[j]);
                ah[rt][j]     = (short)(u0 >> 16);
                ah[rt][4 + j] = (short)(u1 >> 16);
                float r0 = a0[j] - __uint_as_float(u0 & 0xffff0000u);
                float r1 = a1[j] - __uint_as_float(u1 & 0xffff0000u);
                al[rt][j]     = (short)(__float_as_uint(r0) >> 16);
                al[rt][4 + j] = (short)(__float_as_uint(r1) >> 16);
            }
        }
        #pragma unroll
        for (int nt = 0; nt < 8; nt++) {
            const int boff = (nt * 16 + n0) * 128 + (((ks << 2) + qw) ^ n0) * 8;
            short8 bh = *(const short8*)(&Bs[boff]);
            short8 bl = *(const short8*)(&Bs[16384 + boff]);
            #pragma unroll
            for (int rt = 0; rt < 2; rt++) {
                acc[rt][nt] = __builtin_amdgcn_mfma_f32_16x16x32_bf16(ah[rt], bh, acc[rt][nt], 0, 0, 0);
                acc[rt][nt] = __builtin_amdgcn_mfma_f32_16x16x32_bf16(al[rt], bh, acc[rt][nt], 0, 0, 0);
                acc[rt][nt] = __builtin_amdgcn_mfma_f32_16x16x32_bf16(ah[rt], bl, acc[rt][nt], 0, 0, 0);
            }
        }
    }

    #pragma unroll
    for (int rt = 0; rt < 2; rt++) {
        const int rbase = blockIdx.x * 128 + wave * 32 + rt * 16 + qw * 4;
        #pragma unroll
        for (int nt = 0; nt < 8; nt++) {
            int col = nt * 16 + n0;
            float bv = bia[col];
            #pragma unroll
            for (int r = 0; r < 4; r++) {
                int grow = rbase + r;
                if (grow < nrows) outs[(size_t)grow * HIDU + col] = acc[rt][nt][r] + bv;
            }
        }
    }
}

// ---------------- fused attention (+ optional fused head) ----------------
// 16 lanes per node (4 heads x 4 subs); DPP quad butterflies (no LDS);
// k/v bf16, edge_attr CSR-ordered bf16; pairwise online softmax.
// mode 0: write fp32 h. mode 1: fuse classification head (logits + log_softmax).
__global__ __launch_bounds__(256) void attn(
    const float* __restrict__ qb, const u16* __restrict__ kb, const u16* __restrict__ vb,
    const float* __restrict__ sb, const u16* __restrict__ ea16, const float* __restrict__ We,
    const int* __restrict__ row_ptr, const int* __restrict__ csr_src,
    float* __restrict__ hout_f32,
    const float* __restrict__ Wout, const float* __restrict__ bout,
    float* __restrict__ out_logits, int mode)
{
    __shared__ float WeS[4 * 513];      // [h][t*32+j]
    __shared__ float WoS[HIDU * NC];    // head weights (mode 1)
    __shared__ float boS[NC];
    __shared__ float hrowS[16 * 132];   // per-cluster h row (padded: 132f -> +4 banks/cluster)
    __shared__ float lgS[16 * 16];      // per-cluster logits

    #pragma unroll
    for (int i = 0; i < 8; i++) {
        int idx = threadIdx.x + i * 256;   // t*128 + c over 16x128
        int tt = idx >> 7, c = idx & 127;
        int h = c >> 5, j = c & 31;
        WeS[h * 513 + tt * 32 + j] = We[idx];
    }
    if (mode == 1) {
        for (int i = 0; i < 5; i++) {
            int idx = threadIdx.x + i * 256;
            if (idx < HIDU * NC) WoS[idx] = Wout[idx];
        }
        if (threadIdx.x < NC) boS[threadIdx.x] = bout[threadIdx.x];
    }
    __syncthreads();

    int gtid = blockIdx.x * 256 + threadIdx.x;   // grid is exactly NN*16 threads
    int n   = gtid >> 4;         // node
    int l16 = gtid & 15;         // lane in 16-lane cluster
    int h   = l16 >> 2;          // head
    int sub = l16 & 3;
    const int lane = threadIdx.x & 63;
    const float* WeH = &WeS[h * 513];
    const int j0  = sub * 8;     // channel base within head
    const int ch0 = h * DH + j0; // = l16*8
    const int t0  = sub * 4;     // e-channel base

    float qreg[8];
    float g4[4];
    {
        const f4* qp = (const f4*)(qb + (size_t)n * HIDU + h * DH);
        float q32[32];
        #pragma unroll
        for (int c = 0; c < 8; c++) {
            f4 x = qp[c];
            #pragma unroll
            for (int j = 0; j < 4; j++) q32[c * 4 + j] = x[j];
        }
        #pragma unroll
        for (int tt = 0; tt < 4; tt++) {
            float a = 0.f;
            #pragma unroll
            for (int j = 0; j < 32; j++) a += q32[j] * WeH[(t0 + tt) * 32 + j];
            g4[tt] = a;
        }
        #pragma unroll
        for (int j = 0; j < 8; j++) qreg[j] = q32[j0 + j];
    }

    float m = -INFINITY, l = 0.f;
    float O[8];
    float a4[4];
    #pragma unroll
    for (int j = 0; j < 8; j++) O[j] = 0.f;
    #pragma unroll
    for (int tt = 0; tt < 4; tt++) a4[tt] = 0.f;

    const int r0 = row_ptr[n], r1 = row_ptr[n + 1];
    const float inv = 0.17677669529663687f;   // 1/sqrt(32)

    for (int e = r0; e < r1; e += 2) {
        bool has2 = (e + 1 < r1);
        int e1i = has2 ? e + 1 : e;
        int s0 = csr_src[e];
        int s1 = csr_src[e1i];
        u16x4 e0 = *(const u16x4*)(ea16 + (size_t)e * 16 + t0);
        u16x4 e1 = *(const u16x4*)(ea16 + (size_t)e1i * 16 + t0);

        u16x8 k0 = *(const u16x8*)(kb + (size_t)s0 * HIDU + ch0);
        u16x8 v0 = *(const u16x8*)(vb + (size_t)s0 * HIDU + ch0);
        u16x8 k1 = *(const u16x8*)(kb + (size_t)s1 * HIDU + ch0);
        u16x8 v1 = *(const u16x8*)(vb + (size_t)s1 * HIDU + ch0);

        float ea0[4], ea1[4];
        #pragma unroll
        for (int tt = 0; tt < 4; tt++) { ea0[tt] = bf2f(e0[tt]); ea1[tt] = bf2f(e1[tt]); }

        float d0 = 0.f, d1 = 0.f;
        #pragma unroll
        for (int j = 0; j < 8; j++) {
            d0 += qreg[j] * bf2f(k0[j]);
            d1 += qreg[j] * bf2f(k1[j]);
        }
        #pragma unroll
        for (int tt = 0; tt < 4; tt++) {
            d0 += g4[tt] * ea0[tt];
            d1 += g4[tt] * ea1[tt];
        }
        d0 = qadd_xor1(d0);  d1 = qadd_xor1(d1);   // DPP quad butterfly (no LDS)
        d0 = qadd_xor2(d0);  d1 = qadd_xor2(d1);

        float logit0 = d0 * inv;
        float logit1 = has2 ? d1 * inv : -INFINITY;
        float mn = fmaxf(m, fmaxf(logit0, logit1));
        float corr = __expf(m - mn);
        float w0 = __expf(logit0 - mn);
        float w1 = __expf(logit1 - mn);
        l = l * corr + w0 + w1;
        #pragma unroll
        for (int j = 0; j < 8; j++)
            O[j] = O[j] * corr + w0 * bf2f(v0[j]) + w1 * bf2f(v1[j]);
        #pragma unroll
        for (int tt = 0; tt < 4; tt++)
            a4[tt] = a4[tt] * corr + w0 * ea0[tt] + w1 * ea1[tt];
        m = mn;
    }

    // gather distributed a16 (from the 4 lanes of this head)
    float af[16];
    #pragma unroll
    for (int t = 0; t < 16; t++)
        af[t] = __shfl(a4[t & 3], (lane & ~3) | (t >> 2));

    float invl = 1.0f / (l + 1e-16f);     // PyG softmax eps; zero-degree -> O=0
    const float* sp = sb + (size_t)n * HIDU + ch0;

    float vals[8];
    #pragma unroll
    for (int j = 0; j < 8; j++) {
        float ev = 0.f;
        #pragma unroll
        for (int t = 0; t < 16; t++) ev += af[t] * WeH[t * 32 + j0 + j];
        vals[j] = fmaxf((O[j] + ev) * invl + sp[j], 0.f);   // relu(conv_out)
    }

    if (mode == 0) {
        const size_t obase = (size_t)n * HIDU + ch0;
        f4 r0v, r1v;
        #pragma unroll
        for (int j = 0; j < 4; j++) { r0v[j] = vals[j]; r1v[j] = vals[4 + j]; }
        *(f4*)(hout_f32 + obase) = r0v;
        *(f4*)(hout_f32 + obase + 4) = r1v;
    } else {
        // fused head: cluster writes h row to LDS (wave-synchronous), 10 lanes
        // compute logits, redundant lse, write log_softmax.
        const int cb = threadIdx.x >> 4;   // cluster in block
        float* hr = &hrowS[cb * 132];
        f4 w0v, w1v;
        #pragma unroll
        for (int j = 0; j < 4; j++) { w0v[j] = vals[j]; w1v[j] = vals[4 + j]; }
        *(f4*)(hr + ch0) = w0v;
        *(f4*)(hr + ch0 + 4) = w1v;
        // same wave: LDS ops complete in order; no barrier needed
        if (l16 < NC) {
            float lg = boS[l16];
            for (int ch = 0; ch < HIDU; ch += 4) {
                f4 hv = *(const f4*)(hr + ch);
                #pragma unroll
                for (int j = 0; j < 4; j++) lg += hv[j] * WoS[(ch + j) * NC + l16];
            }
            lgS[cb * 16 + l16] = lg;
        }
        if (l16 < NC) {
            float lgc = lgS[cb * 16 + l16];
            float mx = -INFINITY;
            #pragma unroll
            for (int c = 0; c < NC; c++) mx = fmaxf(mx, lgS[cb * 16 + c]);
            float sum = 0.f;
            #pragma unroll
            for (int c = 0; c < NC; c++) sum += __expf(lgS[cb * 16 + c] - mx);
            float lse = mx + __logf(sum);
            out_logits[(size_t)n * NC + l16] = lgc - lse;
        }
    }
}

// ---------------- launch ----------------
extern "C" void kernel_launch(void* const* d_in, const int* in_sizes, int n_in,
                              void* d_out, int out_size, void* d_ws, size_t ws_size,
                              hipStream_t stream) {
    const float* x     = (const float*)d_in[0];
    const int*   ei    = (const int*)d_in[1];
    const float* eattr = (const float*)d_in[2];
    const float *Wq0 = (const float*)d_in[3],  *bq0 = (const float*)d_in[4];
    const float *Wk0 = (const float*)d_in[5],  *bk0 = (const float*)d_in[6];
    const float *Wv0 = (const float*)d_in[7],  *bv0 = (const float*)d_in[8];
    const float *We0 = (const float*)d_in[9];
    const float *Ws0 = (const float*)d_in[10], *bs0 = (const float*)d_in[11];
    const float *Wq1 = (const float*)d_in[12], *bq1 = (const float*)d_in[13];
    const float *Wk1 = (const float*)d_in[14], *bk1 = (const float*)d_in[15];
    const float *Wv1 = (const float*)d_in[16], *bv1 = (const float*)d_in[17];
    const float *We1 = (const float*)d_in[18];
    const float *Ws1 = (const float*)d_in[19], *bs1 = (const float*)d_in[20];
    const float *Wout = (const float*)d_in[21], *bout = (const float*)d_in[22];

    char* p = (char*)d_ws;
    auto alloc = [&](size_t bytes) -> void* {
        void* r = (void*)p;
        p += (bytes + 255) & ~(size_t)255;
        return r;
    };
    int* deg      = (int*)alloc(NN * 4);
    int* row_ptr  = (int*)alloc((NN + 1) * 4);
    int* cursor   = (int*)alloc(NN * 4);
    int* bsum     = (int*)alloc(NBLK * 4);
    int* boff     = (int*)alloc(NBLK * 4);
    int* csr_src  = (int*)alloc((size_t)NE * 4);
    float* qb     = (float*)alloc((size_t)NN * HIDU * 4);
    u16* kb       = (u16*)alloc((size_t)NN * HIDU * 2);
    u16* vb       = (u16*)alloc((size_t)NN * HIDU * 2);
    float* sbuf   = (float*)alloc((size_t)NN * HIDU * 4);
    float* hbuf   = (float*)alloc((size_t)NN * HIDU * 4);
    u16* ea16     = (u16*)alloc((size_t)NE * 16 * 2);     // CSR-ordered bf16 edge_attr
    u16* wthi     = (u16*)alloc(8 * 16384 * 2);
    u16* wtlo     = (u16*)alloc(8 * 16384 * 2);

    // CSR build (every call: inputs/ws are re-poisoned)
    k_zero<<<(NN + 255) / 256, 256, 0, stream>>>(deg, NN);
    k_hist<<<(NE + 255) / 256, 256, 0, stream>>>(ei + NE, deg);
    scan_a<<<NBLK, 256, 0, stream>>>(deg, bsum);
    scan_b<<<1, 256, 0, stream>>>(bsum, boff, row_ptr);
    scan_c<<<NBLK, 256, 0, stream>>>(deg, boff, row_ptr, cursor);
    k_scatter<<<(NE + 255) / 256, 256, 0, stream>>>(ei, eattr, cursor, csr_src, ea16);

    // weights -> transposed bf16 hi/lo (mats 0-3: layer 0 q,k,v,s; 4-7: layer 1)
    k_cvtw<<<8, 256, 0, stream>>>(Wq0, Wk0, Wv0, Ws0, Wq1, Wk1, Wv1, Ws1, wthi, wtlo);

    const int gm = (NN + 127) / 128;               // 391
    const int ga = (NN * 16) / 256;                // 3125 (exact)

    // layer 1 (gemms read fp32 x directly; in-register bf16 split)
    gemm_qkv<<<dim3(gm, 3), 256, 0, stream>>>(x, wthi, bq0, bk0, bv0, qb, kb, vb, NN);
    gemm_s<<<gm, 256, 0, stream>>>(x, wthi + 3 * 16384, wtlo + 3 * 16384, bs0, sbuf, NN);
    attn<<<ga, 256, 0, stream>>>(qb, kb, vb, sbuf, ea16, We0, row_ptr, csr_src,
                                 hbuf, Wout, bout, (float*)d_out, 0);
    // layer 2
    gemm_qkv<<<dim3(gm, 3), 256, 0, stream>>>(hbuf, wthi + 4 * 16384, bq1, bk1, bv1, qb, kb, vb, NN);
    gemm_s<<<gm, 256, 0, stream>>>(hbuf, wthi + 7 * 16384, wtlo + 7 * 16384, bs1, sbuf, NN);
    attn<<<ga, 256, 0, stream>>>(qb, kb, vb, sbuf, ea16, We1, row_ptr, csr_src,
                                 hbuf, Wout, bout, (float*)d_out, 1);   // head fused
}

// Round 11
// 457.941 us; speedup vs baseline: 3.4396x; 1.0245x over previous
//
#include <hip/hip_runtime.h>

typedef unsigned short u16;
typedef unsigned int u32;
typedef __attribute__((ext_vector_type(4))) u16 u16x4;
typedef __attribute__((ext_vector_type(8))) u16 u16x8;
typedef __attribute__((ext_vector_type(4))) u32 u32x4;
typedef __attribute__((ext_vector_type(8))) short short8;   // MFMA A/B frag (8 bf16)
typedef __attribute__((ext_vector_type(4))) float f32x4;    // MFMA C/D frag
typedef __attribute__((ext_vector_type(4))) float f4;

#define NN 50000
#define NE 600000
#define HEADS 4
#define DH 32
#define HIDU 128
#define NC 10
#define NBLK 196   // ceil(NN/256)
#define WES_T 34   // WeS t-stride (bank-spread)
#define WES_H 546  // WeS h-stride = 16*34 + 2

__device__ __forceinline__ float bf2f(u16 u) {
    union { unsigned int i; float f; } c; c.i = ((unsigned int)u) << 16; return c.f;
}
__device__ __forceinline__ u16 f2bf(float f) {
    union { float f; unsigned int i; } c; c.f = f;
    unsigned int x = c.i;
    return (u16)((x + 0x7fffu + ((x >> 16) & 1u)) >> 16);  // RNE
}
__device__ __forceinline__ float lo_bf(u32 d) { return __uint_as_float(d << 16); }
__device__ __forceinline__ float hi_bf(u32 d) { return __uint_as_float(d & 0xffff0000u); }
// quad butterflies via DPP (VALU-only)
__device__ __forceinline__ float qadd_xor1(float v) {
    int o = __builtin_amdgcn_update_dpp(0, __float_as_int(v), 0xB1, 0xF, 0xF, true);
    return v + __int_as_float(o);
}
__device__ __forceinline__ float qadd_xor2(float v) {
    int o = __builtin_amdgcn_update_dpp(0, __float_as_int(v), 0x4E, 0xF, 0xF, true);
    return v + __int_as_float(o);
}

// ---------------- CSR build ----------------
__global__ void k_zero(int* p, int n) {
    int i = blockIdx.x * blockDim.x + threadIdx.x;
    if (i < n) p[i] = 0;
}

__global__ void k_hist(const int* __restrict__ dst, int* __restrict__ deg) {
    int i = blockIdx.x * blockDim.x + threadIdx.x;
    if (i < NE) atomicAdd(&deg[dst[i]], 1);
}

__global__ __launch_bounds__(256) void scan_a(const int* __restrict__ deg,
                                              int* __restrict__ bsum) {
    __shared__ int red[4];
    int i = blockIdx.x * 256 + threadIdx.x;
    int v = (i < NN) ? deg[i] : 0;
    #pragma unroll
    for (int off = 1; off < 64; off <<= 1) v += __shfl_xor(v, off);
    if ((threadIdx.x & 63) == 0) red[threadIdx.x >> 6] = v;
    __syncthreads();
    if (threadIdx.x == 0) bsum[blockIdx.x] = red[0] + red[1] + red[2] + red[3];
}

__global__ __launch_bounds__(256) void scan_b(const int* __restrict__ bsum,
                                              int* __restrict__ boff,
                                              int* __restrict__ row_ptr) {
    __shared__ int s[256];
    int t = threadIdx.x;
    int v = (t < NBLK) ? bsum[t] : 0;
    s[t] = v;
    __syncthreads();
    for (int off = 1; off < 256; off <<= 1) {
        int x = (t >= off) ? s[t - off] : 0;
        __syncthreads();
        s[t] += x;
        __syncthreads();
    }
    if (t < NBLK) boff[t] = s[t] - v;   // exclusive
    if (t == 0) row_ptr[NN] = NE;
}

__global__ __launch_bounds__(256) void scan_c(const int* __restrict__ deg,
                                              const int* __restrict__ boff,
                                              int* __restrict__ row_ptr,
                                              int* __restrict__ cursor) {
    __shared__ int s[256];
    int t = threadIdx.x;
    int i = blockIdx.x * 256 + t;
    int v = (i < NN) ? deg[i] : 0;
    s[t] = v;
    __syncthreads();
    for (int off = 1; off < 256; off <<= 1) {
        int x = (t >= off) ? s[t - off] : 0;
        __syncthreads();
        s[t] += x;
        __syncthreads();
    }
    if (i < NN) {
        int r = boff[blockIdx.x] + s[t] - v;
        row_ptr[i] = r;
        cursor[i] = r;
    }
}

// scatter: build csr_src AND permute edge_attr into CSR order (fp32 -> bf16)
__global__ void k_scatter(const int* __restrict__ ei, const float* __restrict__ eattr,
                          int* __restrict__ cursor,
                          int* __restrict__ csr_src, u16* __restrict__ ea16) {
    int i = blockIdx.x * blockDim.x + threadIdx.x;
    if (i < NE) {
        int s = ei[i];
        int d = ei[NE + i];
        int pos = atomicAdd(&cursor[d], 1);
        csr_src[pos] = s;
        const f4* ep = (const f4*)(eattr + (size_t)i * 16);
        f4 a = ep[0], b = ep[1], c = ep[2], dd = ep[3];
        u16x8 o0, o1;
        #pragma unroll
        for (int j = 0; j < 4; j++) {
            o0[j] = f2bf(a[j]); o0[4 + j] = f2bf(b[j]);
            o1[j] = f2bf(c[j]); o1[4 + j] = f2bf(dd[j]);
        }
        *(u16x8*)(ea16 + (size_t)pos * 16)     = o0;
        *(u16x8*)(ea16 + (size_t)pos * 16 + 8) = o1;
    }
}

// weights: convert + transpose W[k][n] -> Wt[n][k], hi only (single-pass bf16 GEMMs)
__global__ void k_cvtw(const float* w0, const float* w1, const float* w2, const float* w3,
                       const float* w4, const float* w5, const float* w6, const float* w7,
                       u16* __restrict__ hi) {
    const float* w;
    switch (blockIdx.x) {
        case 0: w = w0; break; case 1: w = w1; break;
        case 2: w = w2; break; case 3: w = w3; break;
        case 4: w = w4; break; case 5: w = w5; break;
        case 6: w = w6; break; default: w = w7; break;
    }
    u16* oh = hi + blockIdx.x * 16384;
    for (int i = 0; i < 64; i++) {
        int idx = threadIdx.x + i * 256;   // k*128 + n
        int k = idx >> 7, n = idx & 127;
        oh[n * 128 + k] = f2bf(w[idx]);
    }
}

// ---------------- unified q/k/v/s GEMM: single-pass bf16 MFMA, fp32 X (trunc) -----------
// grid (391, 4 mats). q,s -> fp32; k,v -> bf16.
__global__ __launch_bounds__(256) void gemm_qkvs(
    const float* __restrict__ X, const u16* __restrict__ WtHi,
    const float* __restrict__ b0, const float* __restrict__ b1,
    const float* __restrict__ b2, const float* __restrict__ b3,
    float* __restrict__ outq, u16* __restrict__ outk, u16* __restrict__ outv,
    float* __restrict__ outs, int nrows)
{
    __shared__ u16 Bs[128 * 128];   // 32 KB
    const int mat = blockIdx.y;     // 0=q 1=k 2=v 3=s
    const u16* wh = WtHi + mat * 16384;

    #pragma unroll
    for (int i = 0; i < 8; i++) {
        int idx = threadIdx.x + i * 256;
        int n = idx >> 4, g = idx & 15;
        *(u16x8*)(&Bs[n * 128 + ((g ^ (n & 15)) << 3)]) = *(const u16x8*)(wh + n * 128 + g * 8);
    }
    __syncthreads();

    const int wave = threadIdx.x >> 6, lane = threadIdx.x & 63;
    const int n0 = lane & 15;
    const int qw = lane >> 4;
    const int kq = qw * 8;

    const float* xp[2];
    #pragma unroll
    for (int rt = 0; rt < 2; rt++) {
        int arow = blockIdx.x * 128 + wave * 32 + rt * 16 + n0;
        int arow_c = arow < nrows ? arow : nrows - 1;
        xp[rt] = X + (size_t)arow_c * HIDU + kq;
    }

    f32x4 acc[2][8];
    #pragma unroll
    for (int rt = 0; rt < 2; rt++)
        #pragma unroll
        for (int nt = 0; nt < 8; nt++) acc[rt][nt] = (f32x4){0.f, 0.f, 0.f, 0.f};

    #pragma unroll
    for (int ks = 0; ks < 4; ks++) {
        short8 ah[2];
        #pragma unroll
        for (int rt = 0; rt < 2; rt++) {
            f4 a0 = *(const f4*)(xp[rt] + ks * 32);
            f4 a1 = *(const f4*)(xp[rt] + ks * 32 + 4);
            #pragma unroll
            for (int j = 0; j < 4; j++) {
                ah[rt][j]     = (short)(__float_as_uint(a0[j]) >> 16);
                ah[rt][4 + j] = (short)(__float_as_uint(a1[j]) >> 16);
            }
        }
        #pragma unroll
        for (int nt = 0; nt < 8; nt++) {
            const int boff = (nt * 16 + n0) * 128 + (((ks << 2) + qw) ^ n0) * 8;
            short8 bh = *(const short8*)(&Bs[boff]);
            #pragma unroll
            for (int rt = 0; rt < 2; rt++)
                acc[rt][nt] = __builtin_amdgcn_mfma_f32_16x16x32_bf16(ah[rt], bh, acc[rt][nt], 0, 0, 0);
        }
    }

    const float* bia = (mat == 0) ? b0 : (mat == 1) ? b1 : (mat == 2) ? b2 : b3;
    #pragma unroll
    for (int rt = 0; rt < 2; rt++) {
        const int rbase = blockIdx.x * 128 + wave * 32 + rt * 16 + qw * 4;
        #pragma unroll
        for (int nt = 0; nt < 8; nt++) {
            int col = nt * 16 + n0;
            float bv = bia[col];
            #pragma unroll
            for (int r = 0; r < 4; r++) {
                int grow = rbase + r;
                if (grow < nrows) {
                    float v = acc[rt][nt][r] + bv;
                    if (mat == 0)      outq[(size_t)grow * HIDU + col] = v;
                    else if (mat == 1) outk[(size_t)grow * HIDU + col] = f2bf(v);
                    else if (mat == 2) outv[(size_t)grow * HIDU + col] = f2bf(v);
                    else               outs[(size_t)grow * HIDU + col] = v;
                }
            }
        }
    }
}

// ---------------- fused attention (+ optional fused head) ----------------
// 16 lanes per node (4 heads x 4 subs); DPP quad butterflies; f4 packed math;
// WeS layout h*546 + t*34 + c (bank-conflict-free for both access patterns).
__global__ __launch_bounds__(256) void attn(
    const float* __restrict__ qb, const u16* __restrict__ kb, const u16* __restrict__ vb,
    const float* __restrict__ sb, const u16* __restrict__ ea16, const float* __restrict__ We,
    const int* __restrict__ row_ptr, const int* __restrict__ csr_src,
    float* __restrict__ hout_f32,
    const float* __restrict__ Wout, const float* __restrict__ bout,
    float* __restrict__ out_logits, int mode)
{
    __shared__ float WeS[4 * WES_H];    // ~8.7 KB
    __shared__ float WoS[HIDU * NC];    // head weights (mode 1)
    __shared__ float boS[NC];
    __shared__ float hrowS[16 * 132];
    __shared__ float lgS[16 * 16];

    #pragma unroll
    for (int i = 0; i < 8; i++) {
        int idx = threadIdx.x + i * 256;   // t*128 + c over 16x128
        int tt = idx >> 7, c = idx & 127;
        int h = c >> 5, j = c & 31;
        WeS[h * WES_H + tt * WES_T + j] = We[idx];
    }
    if (mode == 1) {
        for (int i = 0; i < 5; i++) {
            int idx = threadIdx.x + i * 256;
            if (idx < HIDU * NC) WoS[idx] = Wout[idx];
        }
        if (threadIdx.x < NC) boS[threadIdx.x] = bout[threadIdx.x];
    }
    __syncthreads();

    int gtid = blockIdx.x * 256 + threadIdx.x;   // grid is exactly NN*16 threads
    int n   = gtid >> 4;
    int l16 = gtid & 15;
    int h   = l16 >> 2;
    int sub = l16 & 3;
    const int lane = threadIdx.x & 63;
    const float* WeH = &WeS[h * WES_H];
    const int j0  = sub * 8;
    const int ch0 = h * DH + j0;   // = l16*8
    const int t0  = sub * 4;

    f4 qa, qbv;     // own 8 q channels as two f4
    float g4[4];
    {
        const f4* qp = (const f4*)(qb + (size_t)n * HIDU + h * DH);
        float q32[32];
        #pragma unroll
        for (int c = 0; c < 8; c++) {
            f4 x = qp[c];
            #pragma unroll
            for (int j = 0; j < 4; j++) q32[c * 4 + j] = x[j];
        }
        #pragma unroll
        for (int tt = 0; tt < 4; tt++) {
            float a = 0.f;
            #pragma unroll
            for (int j = 0; j < 32; j++) a += q32[j] * WeH[(t0 + tt) * WES_T + j];
            g4[tt] = a;
        }
        #pragma unroll
        for (int j = 0; j < 4; j++) { qa[j] = q32[j0 + j]; qbv[j] = q32[j0 + 4 + j]; }
    }

    float m = -INFINITY, l = 0.f;
    f4 O0 = {0.f, 0.f, 0.f, 0.f}, O1 = {0.f, 0.f, 0.f, 0.f};
    f4 a4 = {0.f, 0.f, 0.f, 0.f};

    const int r0 = row_ptr[n], r1 = row_ptr[n + 1];
    const float inv = 0.17677669529663687f;   // 1/sqrt(32)

    for (int e = r0; e < r1; e += 2) {
        bool has2 = (e + 1 < r1);
        int e1i = has2 ? e + 1 : e;
        int s0 = csr_src[e];
        int s1 = csr_src[e1i];
        u16x4 e0 = *(const u16x4*)(ea16 + (size_t)e * 16 + t0);
        u16x4 e1 = *(const u16x4*)(ea16 + (size_t)e1i * 16 + t0);

        u32x4 k0 = *(const u32x4*)(kb + (size_t)s0 * HIDU + ch0);
        u32x4 v0 = *(const u32x4*)(vb + (size_t)s0 * HIDU + ch0);
        u32x4 k1 = *(const u32x4*)(kb + (size_t)s1 * HIDU + ch0);
        u32x4 v1 = *(const u32x4*)(vb + (size_t)s1 * HIDU + ch0);

        // unpack bf16 pairs -> f4 (lo = d<<16, hi = d&mask)
        f4 k0a = {lo_bf(k0[0]), hi_bf(k0[0]), lo_bf(k0[1]), hi_bf(k0[1])};
        f4 k0b = {lo_bf(k0[2]), hi_bf(k0[2]), lo_bf(k0[3]), hi_bf(k0[3])};
        f4 k1a = {lo_bf(k1[0]), hi_bf(k1[0]), lo_bf(k1[1]), hi_bf(k1[1])};
        f4 k1b = {lo_bf(k1[2]), hi_bf(k1[2]), lo_bf(k1[3]), hi_bf(k1[3])};
        f4 ea0 = {bf2f(e0[0]), bf2f(e0[1]), bf2f(e0[2]), bf2f(e0[3])};
        f4 ea1 = {bf2f(e1[0]), bf2f(e1[1]), bf2f(e1[2]), bf2f(e1[3])};
        f4 g4v = {g4[0], g4[1], g4[2], g4[3]};

        f4 acc0 = qa * k0a + qbv * k0b + g4v * ea0;
        f4 acc1 = qa * k1a + qbv * k1b + g4v * ea1;
        float d0 = acc0[0] + acc0[1] + acc0[2] + acc0[3];
        float d1 = acc1[0] + acc1[1] + acc1[2] + acc1[3];
        d0 = qadd_xor1(d0);  d1 = qadd_xor1(d1);
        d0 = qadd_xor2(d0);  d1 = qadd_xor2(d1);

        float logit0 = d0 * inv;
        float logit1 = has2 ? d1 * inv : -INFINITY;
        float mn = fmaxf(m, fmaxf(logit0, logit1));
        float corr = __expf(m - mn);
        float w0 = __expf(logit0 - mn);
        float w1 = __expf(logit1 - mn);
        l = l * corr + w0 + w1;

        f4 v0a = {lo_bf(v0[0]), hi_bf(v0[0]), lo_bf(v0[1]), hi_bf(v0[1])};
        f4 v0b = {lo_bf(v0[2]), hi_bf(v0[2]), lo_bf(v0[3]), hi_bf(v0[3])};
        f4 v1a = {lo_bf(v1[0]), hi_bf(v1[0]), lo_bf(v1[1]), hi_bf(v1[1])};
        f4 v1b = {lo_bf(v1[2]), hi_bf(v1[2]), lo_bf(v1[3]), hi_bf(v1[3])};
        O0 = O0 * corr + v0a * w0 + v1a * w1;
        O1 = O1 * corr + v0b * w0 + v1b * w1;
        a4 = a4 * corr + ea0 * w0 + ea1 * w1;
        m = mn;
    }

    // gather distributed a16 (from the 4 lanes of this head)
    float af[16];
    #pragma unroll
    for (int t = 0; t < 16; t++)
        af[t] = __shfl(a4[t & 3], (lane & ~3) | (t >> 2));

    float invl = 1.0f / (l + 1e-16f);     // PyG softmax eps; zero-degree -> O=0
    const float* sp = sb + (size_t)n * HIDU + ch0;

    float vals[8];
    #pragma unroll
    for (int j = 0; j < 8; j++) {
        float ev = 0.f;
        #pragma unroll
        for (int t = 0; t < 16; t++) ev += af[t] * WeH[t * WES_T + j0 + j];
        float Oj = (j < 4) ? O0[j] : O1[j - 4];
        vals[j] = fmaxf((Oj + ev) * invl + sp[j], 0.f);   // relu(conv_out)
    }

    if (mode == 0) {
        const size_t obase = (size_t)n * HIDU + ch0;
        f4 r0v, r1v;
        #pragma unroll
        for (int j = 0; j < 4; j++) { r0v[j] = vals[j]; r1v[j] = vals[4 + j]; }
        *(f4*)(hout_f32 + obase) = r0v;
        *(f4*)(hout_f32 + obase + 4) = r1v;
    } else {
        const int cb = threadIdx.x >> 4;
        float* hr = &hrowS[cb * 132];
        f4 w0v, w1v;
        #pragma unroll
        for (int j = 0; j < 4; j++) { w0v[j] = vals[j]; w1v[j] = vals[4 + j]; }
        *(f4*)(hr + ch0) = w0v;
        *(f4*)(hr + ch0 + 4) = w1v;
        if (l16 < NC) {
            float lg = boS[l16];
            for (int ch = 0; ch < HIDU; ch += 4) {
                f4 hv = *(const f4*)(hr + ch);
                #pragma unroll
                for (int j = 0; j < 4; j++) lg += hv[j] * WoS[(ch + j) * NC + l16];
            }
            lgS[cb * 16 + l16] = lg;
        }
        if (l16 < NC) {
            float lgc = lgS[cb * 16 + l16];
            float mx = -INFINITY;
            #pragma unroll
            for (int c = 0; c < NC; c++) mx = fmaxf(mx, lgS[cb * 16 + c]);
            float sum = 0.f;
            #pragma unroll
            for (int c = 0; c < NC; c++) sum += __expf(lgS[cb * 16 + c] - mx);
            float lse = mx + __logf(sum);
            out_logits[(size_t)n * NC + l16] = lgc - lse;
        }
    }
}

// ---------------- launch ----------------
extern "C" void kernel_launch(void* const* d_in, const int* in_sizes, int n_in,
                              void* d_out, int out_size, void* d_ws, size_t ws_size,
                              hipStream_t stream) {
    const float* x     = (const float*)d_in[0];
    const int*   ei    = (const int*)d_in[1];
    const float* eattr = (const float*)d_in[2];
    const float *Wq0 = (const float*)d_in[3],  *bq0 = (const float*)d_in[4];
    const float *Wk0 = (const float*)d_in[5],  *bk0 = (const float*)d_in[6];
    const float *Wv0 = (const float*)d_in[7],  *bv0 = (const float*)d_in[8];
    const float *We0 = (const float*)d_in[9];
    const float *Ws0 = (const float*)d_in[10], *bs0 = (const float*)d_in[11];
    const float *Wq1 = (const float*)d_in[12], *bq1 = (const float*)d_in[13];
    const float *Wk1 = (const float*)d_in[14], *bk1 = (const float*)d_in[15];
    const float *Wv1 = (const float*)d_in[16], *bv1 = (const float*)d_in[17];
    const float *We1 = (const float*)d_in[18];
    const float *Ws1 = (const float*)d_in[19], *bs1 = (const float*)d_in[20];
    const float *Wout = (const float*)d_in[21], *bout = (const float*)d_in[22];

    char* p = (char*)d_ws;
    auto alloc = [&](size_t bytes) -> void* {
        void* r = (void*)p;
        p += (bytes + 255) & ~(size_t)255;
        return r;
    };
    int* deg      = (int*)alloc(NN * 4);
    int* row_ptr  = (int*)alloc((NN + 1) * 4);
    int* cursor   = (int*)alloc(NN * 4);
    int* bsum     = (int*)alloc(NBLK * 4);
    int* boff     = (int*)alloc(NBLK * 4);
    int* csr_src  = (int*)alloc((size_t)NE * 4);
    float* qb     = (float*)alloc((size_t)NN * HIDU * 4);
    u16* kb       = (u16*)alloc((size_t)NN * HIDU * 2);
    u16* vb       = (u16*)alloc((size_t)NN * HIDU * 2);
    float* sbuf   = (float*)alloc((size_t)NN * HIDU * 4);
    float* hbuf   = (float*)alloc((size_t)NN * HIDU * 4);
    u16* ea16     = (u16*)alloc((size_t)NE * 16 * 2);     // CSR-ordered bf16 edge_attr
    u16* wthi     = (u16*)alloc(8 * 16384 * 2);

    // CSR build (every call: inputs/ws are re-poisoned)
    k_zero<<<(NN + 255) / 256, 256, 0, stream>>>(deg, NN);
    k_hist<<<(NE + 255) / 256, 256, 0, stream>>>(ei + NE, deg);
    scan_a<<<NBLK, 256, 0, stream>>>(deg, bsum);
    scan_b<<<1, 256, 0, stream>>>(bsum, boff, row_ptr);
    scan_c<<<NBLK, 256, 0, stream>>>(deg, boff, row_ptr, cursor);
    k_scatter<<<(NE + 255) / 256, 256, 0, stream>>>(ei, eattr, cursor, csr_src, ea16);

    // weights -> transposed bf16 (mats 0-3: layer 0 q,k,v,s; 4-7: layer 1)
    k_cvtw<<<8, 256, 0, stream>>>(Wq0, Wk0, Wv0, Ws0, Wq1, Wk1, Wv1, Ws1, wthi);

    const int gm = (NN + 127) / 128;               // 391
    const int ga = (NN * 16) / 256;                // 3125 (exact)

    // layer 1 (single fused GEMM dispatch: q,k,v,s single-pass bf16)
    gemm_qkvs<<<dim3(gm, 4), 256, 0, stream>>>(x, wthi, bq0, bk0, bv0, bs0,
                                               qb, kb, vb, sbuf, NN);
    attn<<<ga, 256, 0, stream>>>(qb, kb, vb, sbuf, ea16, We0, row_ptr, csr_src,
                                 hbuf, Wout, bout, (float*)d_out, 0);
    // layer 2
    gemm_qkvs<<<dim3(gm, 4), 256, 0, stream>>>(hbuf, wthi + 4 * 16384, bq1, bk1, bv1, bs1,
                                               qb, kb, vb, sbuf, NN);
    attn<<<ga, 256, 0, stream>>>(qb, kb, vb, sbuf, ea16, We1, row_ptr, csr_src,
                                 hbuf, Wout, bout, (float*)d_out, 1);   // head fused
}